// Round 1
// baseline (982.795 us; speedup 1.0000x reference)
//
#include <hip/hip_runtime.h>
#include <hip/hip_bf16.h>
#include <cstdint>

// Problem constants (match reference)
constexpr int kNS = 4096;     // samples
constexpr int kNG = 20000;    // genes
constexpr int kE  = 131072;   // edges per relation
constexpr int kDIN = 256;
constexpr int kH  = 4;

__device__ __forceinline__ float elu_f(float v) { return v > 0.f ? v : expm1f(v); }

__device__ __forceinline__ void atomicMaxF(float* addr, float val) {
  if (val >= 0.f) atomicMax((int*)addr, __float_as_int(val));
  else            atomicMin((unsigned int*)addr, __float_as_uint(val));
}

// ---------------- fill ----------------
__global__ void fill_f32(float* __restrict__ p, float v, int n) {
  int i = blockIdx.x * blockDim.x + threadIdx.x;
  if (i < n) p[i] = v;
}

// ---------------- GEMM: C[M,N] = A[M,K] @ B[K,N] + bias[N] ----------------
// 64x64 tile, 256 threads, 4x4 per thread, BK=16. K multiple of 16, N multiple of 64.
__global__ __launch_bounds__(256) void gemm_bias(
    const float* __restrict__ A, const float* __restrict__ B,
    const float* __restrict__ bias, float* __restrict__ C,
    int M, int N, int K) {
  __shared__ float As[16][65];
  __shared__ float Bs[16][65];
  const int tid = threadIdx.x;
  const int brow = blockIdx.y * 64, bcol = blockIdx.x * 64;
  const int ty = tid >> 4, tx = tid & 15;
  // load maps
  const int ar = tid >> 2, ak = (tid & 3) * 4;   // A: row 0..63, k 0..15 (x4)
  const int bk = tid >> 4, bc = (tid & 15) * 4;  // B: k 0..15, col 0..63 (x4)
  float acc[4][4] = {};
  for (int k0 = 0; k0 < K; k0 += 16) {
    float4 av;
    if (brow + ar < M) av = *(const float4*)&A[(size_t)(brow + ar) * K + k0 + ak];
    else av = make_float4(0.f, 0.f, 0.f, 0.f);
    As[ak + 0][ar] = av.x; As[ak + 1][ar] = av.y;
    As[ak + 2][ar] = av.z; As[ak + 3][ar] = av.w;
    float4 bv = *(const float4*)&B[(size_t)(k0 + bk) * N + bcol + bc];
    Bs[bk][bc + 0] = bv.x; Bs[bk][bc + 1] = bv.y;
    Bs[bk][bc + 2] = bv.z; Bs[bk][bc + 3] = bv.w;
    __syncthreads();
#pragma unroll
    for (int kk = 0; kk < 16; ++kk) {
      float a0 = As[kk][ty * 4 + 0], a1 = As[kk][ty * 4 + 1];
      float a2 = As[kk][ty * 4 + 2], a3 = As[kk][ty * 4 + 3];
      float b0 = Bs[kk][tx * 4 + 0], b1 = Bs[kk][tx * 4 + 1];
      float b2 = Bs[kk][tx * 4 + 2], b3 = Bs[kk][tx * 4 + 3];
      acc[0][0] += a0 * b0; acc[0][1] += a0 * b1; acc[0][2] += a0 * b2; acc[0][3] += a0 * b3;
      acc[1][0] += a1 * b0; acc[1][1] += a1 * b1; acc[1][2] += a1 * b2; acc[1][3] += a1 * b3;
      acc[2][0] += a2 * b0; acc[2][1] += a2 * b1; acc[2][2] += a2 * b2; acc[2][3] += a2 * b3;
      acc[3][0] += a3 * b0; acc[3][1] += a3 * b1; acc[3][2] += a3 * b2; acc[3][3] += a3 * b3;
    }
    __syncthreads();
  }
#pragma unroll
  for (int i = 0; i < 4; ++i) {
    int row = brow + ty * 4 + i;
    if (row >= M) continue;
#pragma unroll
    for (int j = 0; j < 4; ++j) {
      int col = bcol + tx * 4 + j;
      C[(size_t)row * N + col] = acc[i][j] + bias[col];
    }
  }
}

// ---------------- edge alpha: wave per edge ----------------
template <int C>
__global__ __launch_bounds__(256) void edge_alpha(
    const float* __restrict__ xl, const float* __restrict__ xr,
    const float* __restrict__ att, const int* __restrict__ src,
    const int* __restrict__ dst, float* __restrict__ alpha,
    float* __restrict__ mmax, int E) {
  int e = blockIdx.x * 4 + (threadIdx.x >> 6);
  int lane = threadIdx.x & 63;
  if (e >= E) return;
  int s = src[e], d = dst[e];
  const float* pl = xl + (size_t)s * (4 * C);
  const float* pr = xr + (size_t)d * (4 * C);
  float p[4];
#pragma unroll
  for (int h = 0; h < 4; ++h) {
    float a = 0.f;
#pragma unroll
    for (int c = lane; c < C; c += 64) {
      float v = pl[h * C + c] + pr[h * C + c];
      v = v >= 0.f ? v : 0.2f * v;
      a += v * att[h * C + c];
    }
    p[h] = a;
  }
#pragma unroll
  for (int off = 32; off > 0; off >>= 1) {
#pragma unroll
    for (int h = 0; h < 4; ++h) p[h] += __shfl_xor(p[h], off);
  }
  if (lane == 0) {
#pragma unroll
    for (int h = 0; h < 4; ++h) {
      alpha[(size_t)e * 4 + h] = p[h];
      atomicMaxF(&mmax[d * 4 + h], p[h]);
    }
  }
}

// ---------------- exp + denominator ----------------
__global__ void edge_expsum(const int* __restrict__ dst, const float* __restrict__ mmax,
                            float* __restrict__ alpha, float* __restrict__ den, int E) {
  int i = blockIdx.x * blockDim.x + threadIdx.x;
  if (i >= E * 4) return;
  int e = i >> 2, h = i & 3;
  int d = dst[e];
  float ea = expf(alpha[i] - mmax[d * 4 + h]);
  alpha[i] = ea;
  atomicAdd(&den[d * 4 + h], ea);
}

// ---------------- weighted scatter: wave per edge ----------------
template <int C>
__global__ __launch_bounds__(256) void edge_scatter(
    const float* __restrict__ xl, const int* __restrict__ src,
    const int* __restrict__ dst, const float* __restrict__ ea,
    const float* __restrict__ den, float* __restrict__ acc, int E) {
  int e = blockIdx.x * 4 + (threadIdx.x >> 6);
  int lane = threadIdx.x & 63;
  if (e >= E) return;
  int s = src[e], d = dst[e];
  float a[4];
#pragma unroll
  for (int h = 0; h < 4; ++h) a[h] = ea[(size_t)e * 4 + h] / (den[d * 4 + h] + 1e-16f);
  const float* pl = xl + (size_t)s * (4 * C);
  float* pd = acc + (size_t)d * (4 * C);
#pragma unroll
  for (int c = lane; c < 4 * C; c += 64) {
    atomicAdd(&pd[c], a[c / C] * pl[c]);
  }
}

// ---------------- finalizers ----------------
__global__ void fin_gene(float* __restrict__ acc, const float* __restrict__ bias, int total) {
  int i = blockIdx.x * blockDim.x + threadIdx.x;
  if (i >= total) return;
  float v = acc[i] + bias[i & 255];
  acc[i] = elu_f(v);
}

__global__ void fin_sample(float* __restrict__ acc, const float* __restrict__ bias,
                           const float* __restrict__ sl1o, int rows) {
  int i = blockIdx.x * blockDim.x + threadIdx.x;
  if (i >= rows * 256) return;
  int r = i >> 8, c = i & 255;
  float v = acc[i] + bias[c] + sl1o[r * 64 + (c & 63)];
  acc[i] = elu_f(v);
}

__global__ void finalize3(const float* __restrict__ acc3, const float* __restrict__ bias3,
                          const float* __restrict__ sl3o, float* __restrict__ out, int rows) {
  int i = blockIdx.x * blockDim.x + threadIdx.x;
  if (i >= rows * 128) return;
  int r = i >> 7, c = i & 127;
  const float* pr = acc3 + (size_t)r * 512;
  float v = 0.25f * (pr[c] + pr[128 + c] + pr[256 + c] + pr[384 + c]);
  v += bias3[c] + sl3o[i];
  out[i] = elu_f(v);
}

extern "C" void kernel_launch(void* const* d_in, const int* in_sizes, int n_in,
                              void* d_out, int out_size, void* d_ws, size_t ws_size,
                              hipStream_t stream) {
  const float* x_sample = (const float*)d_in[0];
  const float* x_gene   = (const float*)d_in[1];
  const int* sg_src = (const int*)d_in[2];
  const int* sg_dst = (const int*)d_in[3];
  const int* gs_src = (const int*)d_in[4];
  const int* gs_dst = (const int*)d_in[5];
  const float* Wl1_sg = (const float*)d_in[6];
  const float* bl1_sg = (const float*)d_in[7];
  const float* Wr1_sg = (const float*)d_in[8];
  const float* br1_sg = (const float*)d_in[9];
  const float* att1_sg = (const float*)d_in[10];
  const float* bias1_sg = (const float*)d_in[11];
  const float* Wl1_gs = (const float*)d_in[12];
  const float* bl1_gs = (const float*)d_in[13];
  const float* Wr1_gs = (const float*)d_in[14];
  const float* br1_gs = (const float*)d_in[15];
  const float* att1_gs = (const float*)d_in[16];
  const float* bias1_gs = (const float*)d_in[17];
  const float* Wl3 = (const float*)d_in[18];
  const float* bl3 = (const float*)d_in[19];
  const float* Wr3 = (const float*)d_in[20];
  const float* br3 = (const float*)d_in[21];
  const float* att3 = (const float*)d_in[22];
  const float* bias3 = (const float*)d_in[23];
  const float* sl1_W = (const float*)d_in[24];
  const float* sl1_b = (const float*)d_in[25];
  const float* sl3_W = (const float*)d_in[26];
  const float* sl3_b = (const float*)d_in[27];

  float* ws = (float*)d_ws;
  size_t off = 0;
  auto alloc = [&](size_t n) { float* p = ws + off; off += n; return p; };
  float* xl_sg = alloc((size_t)kNS * 256);   // 1.05M
  float* xr_sg = alloc((size_t)kNG * 256);   // 5.12M
  float* xl_gs = alloc((size_t)kNG * 256);   // 5.12M  (contiguous with xr_sg)
  float* xr_gs = alloc((size_t)kNS * 256);
  float* acc_g = alloc((size_t)kNG * 256);   // becomes x1_gene
  float* acc_s = alloc((size_t)kNS * 256);   // becomes x1_sample
  float* sl1o  = alloc((size_t)kNS * 64);
  float* xr3   = alloc((size_t)kNS * 512);
  float* acc3  = alloc((size_t)kNS * 512);
  float* sl3o  = alloc((size_t)kNS * 128);
  float* alpha = alloc((size_t)kE * 4);
  float* mbuf  = alloc((size_t)kNG * 4);
  float* dbuf  = alloc((size_t)kNG * 4);
  // xl3 [NG,512] aliases xr_sg+xl_gs (both dead by the time layer-3 GEMM runs)
  float* xl3 = xr_sg;

  dim3 blk(256);
  auto gemm = [&](const float* A, const float* B, const float* bias, float* Cp, int M, int N) {
    dim3 grid(N / 64, (M + 63) / 64);
    hipLaunchKernelGGL(gemm_bias, grid, blk, 0, stream, A, B, bias, Cp, M, N, 256);
  };

  // layer-1 transforms
  gemm(x_sample, Wl1_sg, bl1_sg, xl_sg, kNS, 256);
  gemm(x_gene,   Wr1_sg, br1_sg, xr_sg, kNG, 256);
  gemm(x_gene,   Wl1_gs, bl1_gs, xl_gs, kNG, 256);
  gemm(x_sample, Wr1_gs, br1_gs, xr_gs, kNS, 256);
  gemm(x_sample, sl1_W,  sl1_b,  sl1o,  kNS, 64);

  // ---- stage 1: sg -> genes (C=64) ----
  hipMemsetAsync(acc_g, 0, (size_t)kNG * 256 * sizeof(float), stream);
  hipMemsetAsync(dbuf, 0, (size_t)kNG * 4 * sizeof(float), stream);
  fill_f32<<<(kNG * 4 + 255) / 256, 256, 0, stream>>>(mbuf, -1e30f, kNG * 4);
  edge_alpha<64><<<kE / 4, 256, 0, stream>>>(xl_sg, xr_sg, att1_sg, sg_src, sg_dst, alpha, mbuf, kE);
  edge_expsum<<<(kE * 4) / 256, 256, 0, stream>>>(sg_dst, mbuf, alpha, dbuf, kE);
  edge_scatter<64><<<kE / 4, 256, 0, stream>>>(xl_sg, sg_src, sg_dst, alpha, dbuf, acc_g, kE);
  fin_gene<<<((size_t)kNG * 256 + 255) / 256, 256, 0, stream>>>(acc_g, bias1_sg, kNG * 256);

  // ---- stage 2: gs -> samples (C=64) ----
  hipMemsetAsync(acc_s, 0, (size_t)kNS * 256 * sizeof(float), stream);
  hipMemsetAsync(dbuf, 0, (size_t)kNS * 4 * sizeof(float), stream);
  fill_f32<<<(kNS * 4 + 255) / 256, 256, 0, stream>>>(mbuf, -1e30f, kNS * 4);
  edge_alpha<64><<<kE / 4, 256, 0, stream>>>(xl_gs, xr_gs, att1_gs, gs_src, gs_dst, alpha, mbuf, kE);
  edge_expsum<<<(kE * 4) / 256, 256, 0, stream>>>(gs_dst, mbuf, alpha, dbuf, kE);
  edge_scatter<64><<<kE / 4, 256, 0, stream>>>(xl_gs, gs_src, gs_dst, alpha, dbuf, acc_s, kE);
  fin_sample<<<(kNS * 256 + 255) / 256, 256, 0, stream>>>(acc_s, bias1_gs, sl1o, kNS);

  // layer-3 transforms (acc_g = x1_gene, acc_s = x1_sample, both post-elu)
  gemm(acc_g, Wl3, bl3, xl3, kNG, 512);
  gemm(acc_s, Wr3, br3, xr3, kNS, 512);
  gemm(acc_s, sl3_W, sl3_b, sl3o, kNS, 128);

  // ---- stage 3: gs -> samples (C=128), head-mean ----
  hipMemsetAsync(acc3, 0, (size_t)kNS * 512 * sizeof(float), stream);
  hipMemsetAsync(dbuf, 0, (size_t)kNS * 4 * sizeof(float), stream);
  fill_f32<<<(kNS * 4 + 255) / 256, 256, 0, stream>>>(mbuf, -1e30f, kNS * 4);
  edge_alpha<128><<<kE / 4, 256, 0, stream>>>(xl3, xr3, att3, gs_src, gs_dst, alpha, mbuf, kE);
  edge_expsum<<<(kE * 4) / 256, 256, 0, stream>>>(gs_dst, mbuf, alpha, dbuf, kE);
  edge_scatter<128><<<kE / 4, 256, 0, stream>>>(xl3, gs_src, gs_dst, alpha, dbuf, acc3, kE);
  finalize3<<<(kNS * 128 + 255) / 256, 256, 0, stream>>>(acc3, bias3, sl3o, (float*)d_out, kNS);
}

// Round 2
// 763.006 us; speedup vs baseline: 1.2881x; 1.2881x over previous
//
#include <hip/hip_runtime.h>
#include <hip/hip_bf16.h>
#include <cstdint>

// Problem constants (match reference)
constexpr int kNS = 4096;     // samples
constexpr int kNG = 20000;    // genes
constexpr int kE  = 131072;   // edges per relation

__device__ __forceinline__ float elu_f(float v) { return v > 0.f ? v : expm1f(v); }

__device__ __forceinline__ void atomicMaxF(float* addr, float val) {
  if (val >= 0.f) atomicMax((int*)addr, __float_as_int(val));
  else            atomicMin((unsigned int*)addr, __float_as_uint(val));
}

// ---------------- fill ----------------
__global__ void fill_f32(float* __restrict__ p, float v, int n) {
  int i = blockIdx.x * blockDim.x + threadIdx.x;
  if (i < n) p[i] = v;
}

// ---------------- CSR build ----------------
__global__ void histo(const int* __restrict__ dst, int* __restrict__ deg, int E) {
  int e = blockIdx.x * blockDim.x + threadIdx.x;
  if (e < E) atomicAdd(&deg[dst[e]], 1);
}

// single-block exclusive scan of deg[0..n) -> row_ptr[0..n]
__global__ __launch_bounds__(256) void exclusive_scan(const int* __restrict__ deg,
                                                      int* __restrict__ row_ptr, int n) {
  __shared__ int partial[256];
  int tid = threadIdx.x;
  int chunk = (n + 255) / 256;
  int begin = tid * chunk;
  int finish = begin + chunk < n ? begin + chunk : n;
  int s = 0;
  for (int i = begin; i < finish; ++i) s += deg[i];
  partial[tid] = s;
  __syncthreads();
  if (tid == 0) {
    int run = 0;
    for (int i = 0; i < 256; ++i) { int t = partial[i]; partial[i] = run; run += t; }
  }
  __syncthreads();
  int run = partial[tid];
  for (int i = begin; i < finish; ++i) { row_ptr[i] = run; run += deg[i]; }
  if (tid == 255) row_ptr[n] = run;
}

__global__ void build_perm(const int* __restrict__ dst, const int* __restrict__ row_ptr,
                           int* __restrict__ cur, int* __restrict__ perm, int E) {
  int e = blockIdx.x * blockDim.x + threadIdx.x;
  if (e >= E) return;
  int d = dst[e];
  int pos = row_ptr[d] + atomicAdd(&cur[d], 1);
  perm[pos] = e;
}

// ---------------- GEMM: C[M,N] = A[M,K] @ B[K,N] + bias[N] ----------------
__global__ __launch_bounds__(256) void gemm_bias(
    const float* __restrict__ A, const float* __restrict__ B,
    const float* __restrict__ bias, float* __restrict__ C,
    int M, int N, int K) {
  __shared__ float As[16][65];
  __shared__ float Bs[16][65];
  const int tid = threadIdx.x;
  const int brow = blockIdx.y * 64, bcol = blockIdx.x * 64;
  const int ty = tid >> 4, tx = tid & 15;
  const int ar = tid >> 2, ak = (tid & 3) * 4;
  const int bk = tid >> 4, bc = (tid & 15) * 4;
  float acc[4][4] = {};
  for (int k0 = 0; k0 < K; k0 += 16) {
    float4 av;
    if (brow + ar < M) av = *(const float4*)&A[(size_t)(brow + ar) * K + k0 + ak];
    else av = make_float4(0.f, 0.f, 0.f, 0.f);
    As[ak + 0][ar] = av.x; As[ak + 1][ar] = av.y;
    As[ak + 2][ar] = av.z; As[ak + 3][ar] = av.w;
    float4 bv = *(const float4*)&B[(size_t)(k0 + bk) * N + bcol + bc];
    Bs[bk][bc + 0] = bv.x; Bs[bk][bc + 1] = bv.y;
    Bs[bk][bc + 2] = bv.z; Bs[bk][bc + 3] = bv.w;
    __syncthreads();
#pragma unroll
    for (int kk = 0; kk < 16; ++kk) {
      float a0 = As[kk][ty * 4 + 0], a1 = As[kk][ty * 4 + 1];
      float a2 = As[kk][ty * 4 + 2], a3 = As[kk][ty * 4 + 3];
      float b0 = Bs[kk][tx * 4 + 0], b1 = Bs[kk][tx * 4 + 1];
      float b2 = Bs[kk][tx * 4 + 2], b3 = Bs[kk][tx * 4 + 3];
      acc[0][0] += a0 * b0; acc[0][1] += a0 * b1; acc[0][2] += a0 * b2; acc[0][3] += a0 * b3;
      acc[1][0] += a1 * b0; acc[1][1] += a1 * b1; acc[1][2] += a1 * b2; acc[1][3] += a1 * b3;
      acc[2][0] += a2 * b0; acc[2][1] += a2 * b1; acc[2][2] += a2 * b2; acc[2][3] += a2 * b3;
      acc[3][0] += a3 * b0; acc[3][1] += a3 * b1; acc[3][2] += a3 * b2; acc[3][3] += a3 * b3;
    }
    __syncthreads();
  }
#pragma unroll
  for (int i = 0; i < 4; ++i) {
    int row = brow + ty * 4 + i;
    if (row >= M) continue;
#pragma unroll
    for (int j = 0; j < 4; ++j) {
      int col = bcol + tx * 4 + j;
      C[(size_t)row * N + col] = acc[i][j] + bias[col];
    }
  }
}

// ---------------- edge alpha: wave per edge ----------------
template <int C>
__global__ __launch_bounds__(256) void edge_alpha(
    const float* __restrict__ xl, const float* __restrict__ xr,
    const float* __restrict__ att, const int* __restrict__ src,
    const int* __restrict__ dst, float* __restrict__ alpha,
    float* __restrict__ mmax, int E) {
  int e = blockIdx.x * 4 + (threadIdx.x >> 6);
  int lane = threadIdx.x & 63;
  if (e >= E) return;
  int s = src[e], d = dst[e];
  const float* pl = xl + (size_t)s * (4 * C);
  const float* pr = xr + (size_t)d * (4 * C);
  float p[4];
#pragma unroll
  for (int h = 0; h < 4; ++h) {
    float a = 0.f;
#pragma unroll
    for (int c = lane; c < C; c += 64) {
      float v = pl[h * C + c] + pr[h * C + c];
      v = v >= 0.f ? v : 0.2f * v;
      a += v * att[h * C + c];
    }
    p[h] = a;
  }
#pragma unroll
  for (int off = 32; off > 0; off >>= 1) {
#pragma unroll
    for (int h = 0; h < 4; ++h) p[h] += __shfl_xor(p[h], off);
  }
  if (lane == 0) {
#pragma unroll
    for (int h = 0; h < 4; ++h) {
      alpha[(size_t)e * 4 + h] = p[h];
      atomicMaxF(&mmax[d * 4 + h], p[h]);
    }
  }
}

// ---------------- exp + denominator ----------------
__global__ void edge_expsum(const int* __restrict__ dst, const float* __restrict__ mmax,
                            float* __restrict__ alpha, float* __restrict__ den, int E) {
  int i = blockIdx.x * blockDim.x + threadIdx.x;
  if (i >= E * 4) return;
  int e = i >> 2, h = i & 3;
  int d = dst[e];
  float ea = expf(alpha[i] - mmax[d * 4 + h]);
  alpha[i] = ea;
  atomicAdd(&den[d * 4 + h], ea);
}

// ---------------- CSR gather aggregation: wave per dst node ----------------
template <int C>
__global__ __launch_bounds__(256) void node_gather(
    const float* __restrict__ xl, const int* __restrict__ src,
    const float* __restrict__ ea, const float* __restrict__ den,
    const int* __restrict__ row_ptr, const int* __restrict__ perm,
    float* __restrict__ out, int N) {
  int d = blockIdx.x * 4 + (threadIdx.x >> 6);
  int lane = threadIdx.x & 63;
  if (d >= N) return;
  constexpr int R = 4 * C / 64;  // regs per lane (4 for C=64, 8 for C=128)
  float acc[R] = {};
  float dinv[4];
#pragma unroll
  for (int h = 0; h < 4; ++h) dinv[h] = 1.f / (den[d * 4 + h] + 1e-16f);
  int start = row_ptr[d], end = row_ptr[d + 1];
  for (int i = start; i < end; ++i) {
    int e = perm[i];
    int s = src[e];
    float w[4];
#pragma unroll
    for (int h = 0; h < 4; ++h) w[h] = ea[(size_t)e * 4 + h] * dinv[h];
    const float* pl = xl + (size_t)s * (4 * C);
#pragma unroll
    for (int j = 0; j < R; ++j) {
      acc[j] += w[(j * 64) / C] * pl[lane + j * 64];
    }
  }
  float* po = out + (size_t)d * (4 * C);
#pragma unroll
  for (int j = 0; j < R; ++j) po[lane + j * 64] = acc[j];
}

// ---------------- finalizers ----------------
__global__ void fin_gene(float* __restrict__ acc, const float* __restrict__ bias, int total) {
  int i = blockIdx.x * blockDim.x + threadIdx.x;
  if (i >= total) return;
  float v = acc[i] + bias[i & 255];
  acc[i] = elu_f(v);
}

__global__ void fin_sample(float* __restrict__ acc, const float* __restrict__ bias,
                           const float* __restrict__ sl1o, int rows) {
  int i = blockIdx.x * blockDim.x + threadIdx.x;
  if (i >= rows * 256) return;
  int r = i >> 8, c = i & 255;
  float v = acc[i] + bias[c] + sl1o[r * 64 + (c & 63)];
  acc[i] = elu_f(v);
}

__global__ void finalize3(const float* __restrict__ acc3, const float* __restrict__ bias3,
                          const float* __restrict__ sl3o, float* __restrict__ out, int rows) {
  int i = blockIdx.x * blockDim.x + threadIdx.x;
  if (i >= rows * 128) return;
  int r = i >> 7, c = i & 127;
  const float* pr = acc3 + (size_t)r * 512;
  float v = 0.25f * (pr[c] + pr[128 + c] + pr[256 + c] + pr[384 + c]);
  v += bias3[c] + sl3o[i];
  out[i] = elu_f(v);
}

extern "C" void kernel_launch(void* const* d_in, const int* in_sizes, int n_in,
                              void* d_out, int out_size, void* d_ws, size_t ws_size,
                              hipStream_t stream) {
  const float* x_sample = (const float*)d_in[0];
  const float* x_gene   = (const float*)d_in[1];
  const int* sg_src = (const int*)d_in[2];
  const int* sg_dst = (const int*)d_in[3];
  const int* gs_src = (const int*)d_in[4];
  const int* gs_dst = (const int*)d_in[5];
  const float* Wl1_sg = (const float*)d_in[6];
  const float* bl1_sg = (const float*)d_in[7];
  const float* Wr1_sg = (const float*)d_in[8];
  const float* br1_sg = (const float*)d_in[9];
  const float* att1_sg = (const float*)d_in[10];
  const float* bias1_sg = (const float*)d_in[11];
  const float* Wl1_gs = (const float*)d_in[12];
  const float* bl1_gs = (const float*)d_in[13];
  const float* Wr1_gs = (const float*)d_in[14];
  const float* br1_gs = (const float*)d_in[15];
  const float* att1_gs = (const float*)d_in[16];
  const float* bias1_gs = (const float*)d_in[17];
  const float* Wl3 = (const float*)d_in[18];
  const float* bl3 = (const float*)d_in[19];
  const float* Wr3 = (const float*)d_in[20];
  const float* br3 = (const float*)d_in[21];
  const float* att3 = (const float*)d_in[22];
  const float* bias3 = (const float*)d_in[23];
  const float* sl1_W = (const float*)d_in[24];
  const float* sl1_b = (const float*)d_in[25];
  const float* sl3_W = (const float*)d_in[26];
  const float* sl3_b = (const float*)d_in[27];

  float* ws = (float*)d_ws;
  size_t off = 0;
  auto alloc = [&](size_t n) { float* p = ws + off; off += n; return p; };
  float* xl_sg = alloc((size_t)kNS * 256);
  float* xr_sg = alloc((size_t)kNG * 256);
  float* xl_gs = alloc((size_t)kNG * 256);
  float* xr_gs = alloc((size_t)kNS * 256);
  float* acc_g = alloc((size_t)kNG * 256);   // becomes x1_gene
  float* acc_s = alloc((size_t)kNS * 256);   // becomes x1_sample
  float* sl1o  = alloc((size_t)kNS * 64);
  float* xr3   = alloc((size_t)kNS * 512);
  float* acc3  = alloc((size_t)kNS * 512);
  float* sl3o  = alloc((size_t)kNS * 128);
  float* alpha = alloc((size_t)kE * 4);
  float* mbuf  = alloc((size_t)kNG * 4);
  float* dbuf  = alloc((size_t)kNG * 4);
  // CSR buffers (ints)
  int* deg_g   = (int*)alloc(kNG);
  int* rp_g    = (int*)alloc(kNG + 1);
  int* perm_g  = (int*)alloc(kE);
  int* deg_s   = (int*)alloc(kNS);
  int* rp_s    = (int*)alloc(kNS + 1);
  int* perm_s  = (int*)alloc(kE);
  // xl3 [NG,512] aliases xr_sg+xl_gs (both dead by the time layer-3 GEMM runs)
  float* xl3 = xr_sg;

  dim3 blk(256);
  auto gemm = [&](const float* A, const float* B, const float* bias, float* Cp, int M, int N) {
    dim3 grid(N / 64, (M + 63) / 64);
    hipLaunchKernelGGL(gemm_bias, grid, blk, 0, stream, A, B, bias, Cp, M, N, 256);
  };

  // ---- CSR build (deg buffers double as cursors after scan) ----
  hipMemsetAsync(deg_g, 0, kNG * sizeof(int), stream);
  hipMemsetAsync(deg_s, 0, kNS * sizeof(int), stream);
  histo<<<(kE + 255) / 256, 256, 0, stream>>>(sg_dst, deg_g, kE);
  histo<<<(kE + 255) / 256, 256, 0, stream>>>(gs_dst, deg_s, kE);
  exclusive_scan<<<1, 256, 0, stream>>>(deg_g, rp_g, kNG);
  exclusive_scan<<<1, 256, 0, stream>>>(deg_s, rp_s, kNS);
  hipMemsetAsync(deg_g, 0, kNG * sizeof(int), stream);
  hipMemsetAsync(deg_s, 0, kNS * sizeof(int), stream);
  build_perm<<<(kE + 255) / 256, 256, 0, stream>>>(sg_dst, rp_g, deg_g, perm_g, kE);
  build_perm<<<(kE + 255) / 256, 256, 0, stream>>>(gs_dst, rp_s, deg_s, perm_s, kE);

  // layer-1 transforms
  gemm(x_sample, Wl1_sg, bl1_sg, xl_sg, kNS, 256);
  gemm(x_gene,   Wr1_sg, br1_sg, xr_sg, kNG, 256);
  gemm(x_gene,   Wl1_gs, bl1_gs, xl_gs, kNG, 256);
  gemm(x_sample, Wr1_gs, br1_gs, xr_gs, kNS, 256);
  gemm(x_sample, sl1_W,  sl1_b,  sl1o,  kNS, 64);

  // ---- stage 1: sg -> genes (C=64) ----
  hipMemsetAsync(dbuf, 0, (size_t)kNG * 4 * sizeof(float), stream);
  fill_f32<<<(kNG * 4 + 255) / 256, 256, 0, stream>>>(mbuf, -1e30f, kNG * 4);
  edge_alpha<64><<<kE / 4, 256, 0, stream>>>(xl_sg, xr_sg, att1_sg, sg_src, sg_dst, alpha, mbuf, kE);
  edge_expsum<<<(kE * 4) / 256, 256, 0, stream>>>(sg_dst, mbuf, alpha, dbuf, kE);
  node_gather<64><<<(kNG + 3) / 4, 256, 0, stream>>>(xl_sg, sg_src, alpha, dbuf, rp_g, perm_g, acc_g, kNG);
  fin_gene<<<((size_t)kNG * 256 + 255) / 256, 256, 0, stream>>>(acc_g, bias1_sg, kNG * 256);

  // ---- stage 2: gs -> samples (C=64) ----
  hipMemsetAsync(dbuf, 0, (size_t)kNS * 4 * sizeof(float), stream);
  fill_f32<<<(kNS * 4 + 255) / 256, 256, 0, stream>>>(mbuf, -1e30f, kNS * 4);
  edge_alpha<64><<<kE / 4, 256, 0, stream>>>(xl_gs, xr_gs, att1_gs, gs_src, gs_dst, alpha, mbuf, kE);
  edge_expsum<<<(kE * 4) / 256, 256, 0, stream>>>(gs_dst, mbuf, alpha, dbuf, kE);
  node_gather<64><<<(kNS + 3) / 4, 256, 0, stream>>>(xl_gs, gs_src, alpha, dbuf, rp_s, perm_s, acc_s, kNS);
  fin_sample<<<(kNS * 256 + 255) / 256, 256, 0, stream>>>(acc_s, bias1_gs, sl1o, kNS);

  // layer-3 transforms (acc_g = x1_gene, acc_s = x1_sample, both post-elu)
  gemm(acc_g, Wl3, bl3, xl3, kNG, 512);
  gemm(acc_s, Wr3, br3, xr3, kNS, 512);
  gemm(acc_s, sl3_W, sl3_b, sl3o, kNS, 128);

  // ---- stage 3: gs -> samples (C=128), head-mean ----
  hipMemsetAsync(dbuf, 0, (size_t)kNS * 4 * sizeof(float), stream);
  fill_f32<<<(kNS * 4 + 255) / 256, 256, 0, stream>>>(mbuf, -1e30f, kNS * 4);
  edge_alpha<128><<<kE / 4, 256, 0, stream>>>(xl3, xr3, att3, gs_src, gs_dst, alpha, mbuf, kE);
  edge_expsum<<<(kE * 4) / 256, 256, 0, stream>>>(gs_dst, mbuf, alpha, dbuf, kE);
  node_gather<128><<<(kNS + 3) / 4, 256, 0, stream>>>(xl3, gs_src, alpha, dbuf, rp_s, perm_s, acc3, kNS);
  finalize3<<<(kNS * 128 + 255) / 256, 256, 0, stream>>>(acc3, bias3, sl3o, (float*)d_out, kNS);
}

// Round 3
// 535.304 us; speedup vs baseline: 1.8360x; 1.4254x over previous
//
#include <hip/hip_runtime.h>
#include <hip/hip_bf16.h>
#include <cstdint>

constexpr int kNS = 4096;
constexpr int kNG = 20000;
constexpr int kE  = 131072;

typedef __attribute__((ext_vector_type(8))) short short8;
typedef __attribute__((ext_vector_type(4))) float f32x4;

__device__ __forceinline__ float elu_f(float v) { return v > 0.f ? v : expm1f(v); }

__device__ __forceinline__ unsigned short f2bf(float f) {
  union { float f; unsigned u; } v; v.f = f;
  unsigned r = v.u + 0x7FFF + ((v.u >> 16) & 1);
  return (unsigned short)(r >> 16);
}

__device__ __forceinline__ void atomicMaxF(float* addr, float val) {
  if (val >= 0.f) atomicMax((int*)addr, __float_as_int(val));
  else            atomicMin((unsigned int*)addr, __float_as_uint(val));
}

// ---------------- fill / convert ----------------
__global__ void fill_f32(float* __restrict__ p, float v, int n) {
  int i = blockIdx.x * blockDim.x + threadIdx.x;
  if (i < n) p[i] = v;
}

__global__ void conv_bf16(const float* __restrict__ in, unsigned short* __restrict__ out, int n) {
  int i = (blockIdx.x * blockDim.x + threadIdx.x) * 4;
  if (i >= n) return;
  float4 v = *(const float4*)&in[i];
  ushort4 o;
  o.x = f2bf(v.x); o.y = f2bf(v.y); o.z = f2bf(v.z); o.w = f2bf(v.w);
  *(ushort4*)&out[i] = o;
}

// W [K,N] f32 -> Wt [N,K] bf16
__global__ void conv_wT(const float* __restrict__ W, unsigned short* __restrict__ Wt, int K, int N) {
  int i = blockIdx.x * blockDim.x + threadIdx.x;
  if (i >= K * N) return;
  int n = i / K, k = i - n * K;
  Wt[i] = f2bf(W[(size_t)k * N + n]);
}

// ---------------- CSR build ----------------
__global__ void histo(const int* __restrict__ dst, int* __restrict__ deg, int E) {
  int e = blockIdx.x * blockDim.x + threadIdx.x;
  if (e < E) atomicAdd(&deg[dst[e]], 1);
}

__global__ __launch_bounds__(256) void exclusive_scan(const int* __restrict__ deg,
                                                      int* __restrict__ row_ptr, int n) {
  __shared__ int partial[256];
  int tid = threadIdx.x;
  int chunk = (n + 255) / 256;
  int begin = tid * chunk;
  int finish = begin + chunk < n ? begin + chunk : n;
  int s = 0;
  for (int i = begin; i < finish; ++i) s += deg[i];
  partial[tid] = s;
  __syncthreads();
  if (tid == 0) {
    int run = 0;
    for (int i = 0; i < 256; ++i) { int t = partial[i]; partial[i] = run; run += t; }
  }
  __syncthreads();
  int run = partial[tid];
  for (int i = begin; i < finish; ++i) { row_ptr[i] = run; run += deg[i]; }
  if (tid == 255) row_ptr[n] = run;
}

__global__ void build_perm(const int* __restrict__ dst, const int* __restrict__ row_ptr,
                           int* __restrict__ cur, int* __restrict__ perm, int E) {
  int e = blockIdx.x * blockDim.x + threadIdx.x;
  if (e >= E) return;
  int d = dst[e];
  int pos = row_ptr[d] + atomicAdd(&cur[d], 1);
  perm[pos] = e;
}

// ---------------- MFMA GEMM: C[M,N] = A[M,K] @ Bt[N,K]^T + bias ----------------
// A [M,K] bf16 row-major, Bt [N,K] bf16 row-major (pre-transposed B).
// Tile 128x64, BK=32, 4 waves (2x2), each wave 64x32 via 4x2 16x16 fragments.
__global__ __launch_bounds__(256) void gemm_mfma(
    const unsigned short* __restrict__ A, const unsigned short* __restrict__ Bt,
    const float* __restrict__ bias, float* __restrict__ C, int M, int N, int K) {
  __shared__ alignas(16) unsigned short As[128 * 32];
  __shared__ alignas(16) unsigned short Bs[64 * 32];
  const int tid = threadIdx.x;
  const int wave = tid >> 6, lane = tid & 63;
  const int brow = blockIdx.y * 128, bcol = blockIdx.x * 64;
  const int wrow = (wave >> 1) * 64, wcol = (wave & 1) * 32;
  const int la = lane & 15, lk = (lane >> 4) * 8;
  f32x4 acc[4][2] = {};
  for (int k0 = 0; k0 < K; k0 += 32) {
    // stage A: 512 x 16B segments, linear LDS order == lane order
#pragma unroll
    for (int c = 0; c < 2; ++c) {
      int seg = wave * 128 + c * 64 + lane;
      int row = seg >> 2, ks = (seg & 3) * 8;
      int grow = brow + row; if (grow > M - 1) grow = M - 1;
      const unsigned short* g = A + (size_t)grow * K + k0 + ks;
      __builtin_amdgcn_global_load_lds(
          (const __attribute__((address_space(1))) unsigned*)g,
          (__attribute__((address_space(3))) unsigned*)&As[(wave * 128 + c * 64) * 8],
          16, 0, 0);
    }
    {  // stage Bt: 256 x 16B segments
      int seg = wave * 64 + lane;
      int row = seg >> 2, ks = (seg & 3) * 8;
      const unsigned short* g = Bt + (size_t)(bcol + row) * K + k0 + ks;
      __builtin_amdgcn_global_load_lds(
          (const __attribute__((address_space(1))) unsigned*)g,
          (__attribute__((address_space(3))) unsigned*)&Bs[(wave * 64) * 8],
          16, 0, 0);
    }
    __syncthreads();
    short8 bfr[2];
#pragma unroll
    for (int ni = 0; ni < 2; ++ni)
      bfr[ni] = *(const short8*)&Bs[(wcol + ni * 16 + la) * 32 + lk];
#pragma unroll
    for (int mi = 0; mi < 4; ++mi) {
      short8 af = *(const short8*)&As[(wrow + mi * 16 + la) * 32 + lk];
#pragma unroll
      for (int ni = 0; ni < 2; ++ni)
        acc[mi][ni] = __builtin_amdgcn_mfma_f32_16x16x32_bf16(af, bfr[ni], acc[mi][ni], 0, 0, 0);
    }
    __syncthreads();
  }
  const int r0 = (lane >> 4) * 4;
#pragma unroll
  for (int mi = 0; mi < 4; ++mi) {
#pragma unroll
    for (int r = 0; r < 4; ++r) {
      int row = brow + wrow + mi * 16 + r0 + r;
      if (row >= M) continue;
#pragma unroll
      for (int ni = 0; ni < 2; ++ni) {
        int col = bcol + wcol + ni * 16 + la;
        C[(size_t)row * N + col] = acc[mi][ni][r] + bias[col];
      }
    }
  }
}

// ---------------- edge alpha: wave per edge ----------------
template <int C>
__global__ __launch_bounds__(256) void edge_alpha(
    const float* __restrict__ xl, const float* __restrict__ xr,
    const float* __restrict__ att, const int* __restrict__ src,
    const int* __restrict__ dst, float* __restrict__ alpha,
    float* __restrict__ mmax, int E) {
  int e = blockIdx.x * 4 + (threadIdx.x >> 6);
  int lane = threadIdx.x & 63;
  if (e >= E) return;
  int s = src[e], d = dst[e];
  const float* pl = xl + (size_t)s * (4 * C);
  const float* pr = xr + (size_t)d * (4 * C);
  float p[4];
#pragma unroll
  for (int h = 0; h < 4; ++h) {
    float a = 0.f;
#pragma unroll
    for (int c = lane; c < C; c += 64) {
      float v = pl[h * C + c] + pr[h * C + c];
      v = v >= 0.f ? v : 0.2f * v;
      a += v * att[h * C + c];
    }
    p[h] = a;
  }
#pragma unroll
  for (int off = 32; off > 0; off >>= 1) {
#pragma unroll
    for (int h = 0; h < 4; ++h) p[h] += __shfl_xor(p[h], off);
  }
  if (lane == 0) {
#pragma unroll
    for (int h = 0; h < 4; ++h) {
      alpha[(size_t)e * 4 + h] = p[h];
      atomicMaxF(&mmax[d * 4 + h], p[h]);
    }
  }
}

// ---------------- exp + denominator ----------------
__global__ void edge_expsum(const int* __restrict__ dst, const float* __restrict__ mmax,
                            float* __restrict__ alpha, float* __restrict__ den, int E) {
  int i = blockIdx.x * blockDim.x + threadIdx.x;
  if (i >= E * 4) return;
  int e = i >> 2, h = i & 3;
  int d = dst[e];
  float ea = expf(alpha[i] - mmax[d * 4 + h]);
  alpha[i] = ea;
  atomicAdd(&den[d * 4 + h], ea);
}

// ---------------- CSR gather core ----------------
template <int C>
__device__ __forceinline__ void gather_acc(
    const float* __restrict__ xl, const int* __restrict__ src,
    const float* __restrict__ ea, const float* __restrict__ den,
    const int* __restrict__ row_ptr, const int* __restrict__ perm,
    int d, int lane, float* acc) {
  float dinv[4];
#pragma unroll
  for (int h = 0; h < 4; ++h) dinv[h] = 1.f / (den[d * 4 + h] + 1e-16f);
  int start = row_ptr[d], end = row_ptr[d + 1];
  for (int i = start; i < end; ++i) {
    int e = perm[i];
    int s = src[e];
    float w[4];
#pragma unroll
    for (int h = 0; h < 4; ++h) w[h] = ea[(size_t)e * 4 + h] * dinv[h];
    const float* pl = xl + (size_t)s * (4 * C);
#pragma unroll
    for (int j = 0; j < 4 * C / 64; ++j) acc[j] += w[(j * 64) / C] * pl[lane + j * 64];
  }
}

// gather + bias + elu -> bf16   (gene, C=64)
__global__ __launch_bounds__(256) void gather_fin_gene(
    const float* __restrict__ xl, const int* __restrict__ src,
    const float* __restrict__ ea, const float* __restrict__ den,
    const int* __restrict__ rp, const int* __restrict__ perm,
    const float* __restrict__ bias, unsigned short* __restrict__ out, int N) {
  int d = blockIdx.x * 4 + (threadIdx.x >> 6);
  int lane = threadIdx.x & 63;
  if (d >= N) return;
  float acc[4] = {};
  gather_acc<64>(xl, src, ea, den, rp, perm, d, lane, acc);
#pragma unroll
  for (int j = 0; j < 4; ++j) {
    int c = lane + j * 64;
    out[(size_t)d * 256 + c] = f2bf(elu_f(acc[j] + bias[c]));
  }
}

// gather + bias + self-loop + elu -> bf16   (sample, C=64)
__global__ __launch_bounds__(256) void gather_fin_sample(
    const float* __restrict__ xl, const int* __restrict__ src,
    const float* __restrict__ ea, const float* __restrict__ den,
    const int* __restrict__ rp, const int* __restrict__ perm,
    const float* __restrict__ bias, const float* __restrict__ sl1o,
    unsigned short* __restrict__ out, int N) {
  int d = blockIdx.x * 4 + (threadIdx.x >> 6);
  int lane = threadIdx.x & 63;
  if (d >= N) return;
  float acc[4] = {};
  gather_acc<64>(xl, src, ea, den, rp, perm, d, lane, acc);
  float sl = sl1o[(size_t)d * 64 + lane];
#pragma unroll
  for (int j = 0; j < 4; ++j) {
    int c = lane + j * 64;
    out[(size_t)d * 256 + c] = f2bf(elu_f(acc[j] + bias[c] + sl));
  }
}

// gather + head-mean + bias + self-loop + elu -> f32 output   (C=128)
__global__ __launch_bounds__(256) void gather_final(
    const float* __restrict__ xl, const int* __restrict__ src,
    const float* __restrict__ ea, const float* __restrict__ den,
    const int* __restrict__ rp, const int* __restrict__ perm,
    const float* __restrict__ bias3, const float* __restrict__ sl3o,
    float* __restrict__ out, int N) {
  int d = blockIdx.x * 4 + (threadIdx.x >> 6);
  int lane = threadIdx.x & 63;
  if (d >= N) return;
  float acc[8] = {};
  gather_acc<128>(xl, src, ea, den, rp, perm, d, lane, acc);
#pragma unroll
  for (int jj = 0; jj < 2; ++jj) {
    int cc = lane + jj * 64;
    float s = acc[jj] + acc[jj + 2] + acc[jj + 4] + acc[jj + 6];
    float v = 0.25f * s + bias3[cc] + sl3o[(size_t)d * 128 + cc];
    out[(size_t)d * 128 + cc] = elu_f(v);
  }
}

extern "C" void kernel_launch(void* const* d_in, const int* in_sizes, int n_in,
                              void* d_out, int out_size, void* d_ws, size_t ws_size,
                              hipStream_t stream) {
  const float* x_sample = (const float*)d_in[0];
  const float* x_gene   = (const float*)d_in[1];
  const int* sg_src = (const int*)d_in[2];
  const int* sg_dst = (const int*)d_in[3];
  const int* gs_src = (const int*)d_in[4];
  const int* gs_dst = (const int*)d_in[5];
  const float* Wl1_sg = (const float*)d_in[6];
  const float* bl1_sg = (const float*)d_in[7];
  const float* Wr1_sg = (const float*)d_in[8];
  const float* br1_sg = (const float*)d_in[9];
  const float* att1_sg = (const float*)d_in[10];
  const float* bias1_sg = (const float*)d_in[11];
  const float* Wl1_gs = (const float*)d_in[12];
  const float* bl1_gs = (const float*)d_in[13];
  const float* Wr1_gs = (const float*)d_in[14];
  const float* br1_gs = (const float*)d_in[15];
  const float* att1_gs = (const float*)d_in[16];
  const float* bias1_gs = (const float*)d_in[17];
  const float* Wl3 = (const float*)d_in[18];
  const float* bl3 = (const float*)d_in[19];
  const float* Wr3 = (const float*)d_in[20];
  const float* br3 = (const float*)d_in[21];
  const float* att3 = (const float*)d_in[22];
  const float* bias3 = (const float*)d_in[23];
  const float* sl1_W = (const float*)d_in[24];
  const float* sl1_b = (const float*)d_in[25];
  const float* sl3_W = (const float*)d_in[26];
  const float* sl3_b = (const float*)d_in[27];

  float* ws = (float*)d_ws;
  size_t off = 0;
  auto alloc = [&](size_t n) { float* p = ws + off; off += n; return p; };
  float* xl_sg = alloc((size_t)kNS * 256);
  float* xr_sg = alloc((size_t)kNG * 256);
  float* xl_gs = alloc((size_t)kNG * 256);
  float* xr_gs = alloc((size_t)kNS * 256);
  float* sl1o  = alloc((size_t)kNS * 64);
  float* xr3   = alloc((size_t)kNS * 512);
  float* sl3o  = alloc((size_t)kNS * 128);
  float* alpha = alloc((size_t)kE * 4);
  float* mbuf  = alloc((size_t)kNG * 4);
  float* dbuf  = alloc((size_t)kNG * 4);
  int* deg_g   = (int*)alloc(kNG);
  int* rp_g    = (int*)alloc(kNG + 1);
  int* perm_g  = (int*)alloc(kE);
  int* deg_s   = (int*)alloc(kNS);
  int* rp_s    = (int*)alloc(kNS + 1);
  int* perm_s  = (int*)alloc(kE);
  // bf16 buffers (alloc unit = float = 2 bf16)
  unsigned short* xs_bf  = (unsigned short*)alloc((size_t)kNS * 256 / 2);
  unsigned short* xg_bf  = (unsigned short*)alloc((size_t)kNG * 256 / 2);
  unsigned short* xg1_bf = (unsigned short*)alloc((size_t)kNG * 256 / 2);
  unsigned short* xs1_bf = (unsigned short*)alloc((size_t)kNS * 256 / 2);
  unsigned short* WtL1sg = (unsigned short*)alloc(256 * 256 / 2);
  unsigned short* WtR1sg = (unsigned short*)alloc(256 * 256 / 2);
  unsigned short* WtL1gs = (unsigned short*)alloc(256 * 256 / 2);
  unsigned short* WtR1gs = (unsigned short*)alloc(256 * 256 / 2);
  unsigned short* WtL3   = (unsigned short*)alloc(256 * 512 / 2);
  unsigned short* WtR3   = (unsigned short*)alloc(256 * 512 / 2);
  unsigned short* Wtsl1  = (unsigned short*)alloc(256 * 64 / 2);
  unsigned short* Wtsl3  = (unsigned short*)alloc(256 * 128 / 2);
  // xl3 [NG,512] f32 aliases xr_sg+xl_gs (dead after stage 1/2)
  float* xl3 = xr_sg;

  auto gemm = [&](const unsigned short* A, const unsigned short* Bt, const float* bias,
                  float* Cp, int M, int N) {
    dim3 grid(N / 64, (M + 127) / 128);
    hipLaunchKernelGGL(gemm_mfma, grid, dim3(256), 0, stream, A, Bt, bias, Cp, M, N, 256);
  };
  auto wT = [&](const float* W, unsigned short* Wt, int N) {
    conv_wT<<<(256 * N + 255) / 256, 256, 0, stream>>>(W, Wt, 256, N);
  };

  // ---- conversions ----
  conv_bf16<<<(kNS * 256 / 4 + 255) / 256, 256, 0, stream>>>(x_sample, xs_bf, kNS * 256);
  conv_bf16<<<(kNG * 256 / 4 + 255) / 256, 256, 0, stream>>>(x_gene, xg_bf, kNG * 256);
  wT(Wl1_sg, WtL1sg, 256); wT(Wr1_sg, WtR1sg, 256);
  wT(Wl1_gs, WtL1gs, 256); wT(Wr1_gs, WtR1gs, 256);
  wT(Wl3, WtL3, 512); wT(Wr3, WtR3, 512);
  wT(sl1_W, Wtsl1, 64); wT(sl3_W, Wtsl3, 128);

  // ---- CSR build ----
  hipMemsetAsync(deg_g, 0, kNG * sizeof(int), stream);
  hipMemsetAsync(deg_s, 0, kNS * sizeof(int), stream);
  histo<<<(kE + 255) / 256, 256, 0, stream>>>(sg_dst, deg_g, kE);
  histo<<<(kE + 255) / 256, 256, 0, stream>>>(gs_dst, deg_s, kE);
  exclusive_scan<<<1, 256, 0, stream>>>(deg_g, rp_g, kNG);
  exclusive_scan<<<1, 256, 0, stream>>>(deg_s, rp_s, kNS);
  hipMemsetAsync(deg_g, 0, kNG * sizeof(int), stream);
  hipMemsetAsync(deg_s, 0, kNS * sizeof(int), stream);
  build_perm<<<(kE + 255) / 256, 256, 0, stream>>>(sg_dst, rp_g, deg_g, perm_g, kE);
  build_perm<<<(kE + 255) / 256, 256, 0, stream>>>(gs_dst, rp_s, deg_s, perm_s, kE);

  // ---- layer-1 transforms (bf16 MFMA) ----
  gemm(xs_bf, WtL1sg, bl1_sg, xl_sg, kNS, 256);
  gemm(xg_bf, WtR1sg, br1_sg, xr_sg, kNG, 256);
  gemm(xg_bf, WtL1gs, bl1_gs, xl_gs, kNG, 256);
  gemm(xs_bf, WtR1gs, br1_gs, xr_gs, kNS, 256);
  gemm(xs_bf, Wtsl1, sl1_b, sl1o, kNS, 64);

  // ---- stage 1: sg -> genes (C=64) ----
  hipMemsetAsync(dbuf, 0, (size_t)kNG * 4 * sizeof(float), stream);
  fill_f32<<<(kNG * 4 + 255) / 256, 256, 0, stream>>>(mbuf, -1e30f, kNG * 4);
  edge_alpha<64><<<kE / 4, 256, 0, stream>>>(xl_sg, xr_sg, att1_sg, sg_src, sg_dst, alpha, mbuf, kE);
  edge_expsum<<<(kE * 4) / 256, 256, 0, stream>>>(sg_dst, mbuf, alpha, dbuf, kE);
  gather_fin_gene<<<(kNG + 3) / 4, 256, 0, stream>>>(xl_sg, sg_src, alpha, dbuf, rp_g, perm_g,
                                                     bias1_sg, xg1_bf, kNG);

  // ---- stage 2: gs -> samples (C=64) ----
  hipMemsetAsync(dbuf, 0, (size_t)kNS * 4 * sizeof(float), stream);
  fill_f32<<<(kNS * 4 + 255) / 256, 256, 0, stream>>>(mbuf, -1e30f, kNS * 4);
  edge_alpha<64><<<kE / 4, 256, 0, stream>>>(xl_gs, xr_gs, att1_gs, gs_src, gs_dst, alpha, mbuf, kE);
  edge_expsum<<<(kE * 4) / 256, 256, 0, stream>>>(gs_dst, mbuf, alpha, dbuf, kE);
  gather_fin_sample<<<(kNS + 3) / 4, 256, 0, stream>>>(xl_gs, gs_src, alpha, dbuf, rp_s, perm_s,
                                                       bias1_gs, sl1o, xs1_bf, kNS);

  // ---- layer-3 transforms ----
  gemm(xg1_bf, WtL3, bl3, xl3, kNG, 512);
  gemm(xs1_bf, WtR3, br3, xr3, kNS, 512);
  gemm(xs1_bf, Wtsl3, sl3_b, sl3o, kNS, 128);

  // ---- stage 3: gs -> samples (C=128), head-mean ----
  hipMemsetAsync(dbuf, 0, (size_t)kNS * 4 * sizeof(float), stream);
  fill_f32<<<(kNS * 4 + 255) / 256, 256, 0, stream>>>(mbuf, -1e30f, kNS * 4);
  edge_alpha<128><<<kE / 4, 256, 0, stream>>>(xl3, xr3, att3, gs_src, gs_dst, alpha, mbuf, kE);
  edge_expsum<<<(kE * 4) / 256, 256, 0, stream>>>(gs_dst, mbuf, alpha, dbuf, kE);
  gather_final<<<(kNS + 3) / 4, 256, 0, stream>>>(xl3, gs_src, alpha, dbuf, rp_s, perm_s,
                                                  bias3, sl3o, (float*)d_out, kNS);
}

// Round 4
// 321.592 us; speedup vs baseline: 3.0560x; 1.6645x over previous
//
#include <hip/hip_runtime.h>
#include <hip/hip_bf16.h>
#include <cstdint>

constexpr int kNS = 4096;
constexpr int kNG = 20000;
constexpr int kE  = 131072;

typedef __attribute__((ext_vector_type(8))) short short8;
typedef __attribute__((ext_vector_type(4))) float f32x4;

__device__ __forceinline__ float elu_f(float v) { return v > 0.f ? v : expm1f(v); }

__device__ __forceinline__ unsigned short f2bf(float f) {
  union { float f; unsigned u; } v; v.f = f;
  unsigned r = v.u + 0x7FFF + ((v.u >> 16) & 1);
  return (unsigned short)(r >> 16);
}

__device__ __forceinline__ float bf2f(unsigned short u) {
  union { unsigned u; float f; } v; v.u = ((unsigned)u) << 16; return v.f;
}

// ---------------- convert ----------------
__global__ void conv_bf16(const float* __restrict__ in, unsigned short* __restrict__ out, int n) {
  int i = (blockIdx.x * blockDim.x + threadIdx.x) * 4;
  if (i >= n) return;
  float4 v = *(const float4*)&in[i];
  ushort4 o;
  o.x = f2bf(v.x); o.y = f2bf(v.y); o.z = f2bf(v.z); o.w = f2bf(v.w);
  *(ushort4*)&out[i] = o;
}

// W [K,N] f32 -> Wt [N,K] bf16
__global__ void conv_wT(const float* __restrict__ W, unsigned short* __restrict__ Wt, int K, int N) {
  int i = blockIdx.x * blockDim.x + threadIdx.x;
  if (i >= K * N) return;
  int n = i / K, k = i - n * K;
  Wt[i] = f2bf(W[(size_t)k * N + n]);
}

// ---------------- CSR build ----------------
__global__ void histo(const int* __restrict__ dst, int* __restrict__ deg, int E) {
  int e = blockIdx.x * blockDim.x + threadIdx.x;
  if (e < E) atomicAdd(&deg[dst[e]], 1);
}

__global__ __launch_bounds__(256) void exclusive_scan(const int* __restrict__ deg,
                                                      int* __restrict__ row_ptr, int n) {
  __shared__ int partial[256];
  int tid = threadIdx.x;
  int chunk = (n + 255) / 256;
  int begin = tid * chunk;
  int finish = begin + chunk < n ? begin + chunk : n;
  int s = 0;
  for (int i = begin; i < finish; ++i) s += deg[i];
  partial[tid] = s;
  __syncthreads();
  if (tid == 0) {
    int run = 0;
    for (int i = 0; i < 256; ++i) { int t = partial[i]; partial[i] = run; run += t; }
  }
  __syncthreads();
  int run = partial[tid];
  for (int i = begin; i < finish; ++i) { row_ptr[i] = run; run += deg[i]; }
  if (tid == 255) row_ptr[n] = run;
}

// store src id directly in CSR slot (removes one indirection in the hot loop)
__global__ void build_perm_src(const int* __restrict__ dst, const int* __restrict__ src,
                               const int* __restrict__ row_ptr, int* __restrict__ cur,
                               int* __restrict__ psrc, int E) {
  int e = blockIdx.x * blockDim.x + threadIdx.x;
  if (e >= E) return;
  int d = dst[e];
  int pos = row_ptr[d] + atomicAdd(&cur[d], 1);
  psrc[pos] = src[e];
}

// ---------------- MFMA GEMM: C[M,N] = A[M,K] @ Bt[N,K]^T + bias ----------------
// A [M,K] bf16 row-major, Bt [N,K] bf16 row-major. Tile 128x64, BK=32, 4 waves.
template <int BF16OUT>
__global__ __launch_bounds__(256) void gemm_mfma(
    const unsigned short* __restrict__ A, const unsigned short* __restrict__ Bt,
    const float* __restrict__ bias, float* __restrict__ Cf,
    unsigned short* __restrict__ Cb, int M, int N, int K) {
  __shared__ alignas(16) unsigned short As[128 * 32];
  __shared__ alignas(16) unsigned short Bs[64 * 32];
  const int tid = threadIdx.x;
  const int wave = tid >> 6, lane = tid & 63;
  const int brow = blockIdx.y * 128, bcol = blockIdx.x * 64;
  const int wrow = (wave >> 1) * 64, wcol = (wave & 1) * 32;
  const int la = lane & 15, lk = (lane >> 4) * 8;
  f32x4 acc[4][2] = {};
  for (int k0 = 0; k0 < K; k0 += 32) {
#pragma unroll
    for (int c = 0; c < 2; ++c) {
      int seg = wave * 128 + c * 64 + lane;
      int row = seg >> 2, ks = (seg & 3) * 8;
      int grow = brow + row; if (grow > M - 1) grow = M - 1;
      const unsigned short* g = A + (size_t)grow * K + k0 + ks;
      __builtin_amdgcn_global_load_lds(
          (const __attribute__((address_space(1))) unsigned*)g,
          (__attribute__((address_space(3))) unsigned*)&As[(wave * 128 + c * 64) * 8],
          16, 0, 0);
    }
    {
      int seg = wave * 64 + lane;
      int row = seg >> 2, ks = (seg & 3) * 8;
      const unsigned short* g = Bt + (size_t)(bcol + row) * K + k0 + ks;
      __builtin_amdgcn_global_load_lds(
          (const __attribute__((address_space(1))) unsigned*)g,
          (__attribute__((address_space(3))) unsigned*)&Bs[(wave * 64) * 8],
          16, 0, 0);
    }
    __syncthreads();
    short8 bfr[2];
#pragma unroll
    for (int ni = 0; ni < 2; ++ni)
      bfr[ni] = *(const short8*)&Bs[(wcol + ni * 16 + la) * 32 + lk];
#pragma unroll
    for (int mi = 0; mi < 4; ++mi) {
      short8 af = *(const short8*)&As[(wrow + mi * 16 + la) * 32 + lk];
#pragma unroll
      for (int ni = 0; ni < 2; ++ni)
        acc[mi][ni] = __builtin_amdgcn_mfma_f32_16x16x32_bf16(af, bfr[ni], acc[mi][ni], 0, 0, 0);
    }
    __syncthreads();
  }
  const int r0 = (lane >> 4) * 4;
#pragma unroll
  for (int mi = 0; mi < 4; ++mi) {
#pragma unroll
    for (int r = 0; r < 4; ++r) {
      int row = brow + wrow + mi * 16 + r0 + r;
      if (row >= M) continue;
#pragma unroll
      for (int ni = 0; ni < 2; ++ni) {
        int col = bcol + wcol + ni * 16 + la;
        float v = acc[mi][ni][r] + bias[col];
        if (BF16OUT) Cb[(size_t)row * N + col] = f2bf(v);
        else Cf[(size_t)row * N + col] = v;
      }
    }
  }
}

// ---------------- fused GATv2: alpha + online softmax + aggregate, wave/dst ----------------
// MODE 0: gene out (bias, elu) -> bf16 [N,256]
// MODE 1: sample out (bias, self-loop tile, elu) -> bf16 [N,256]
// MODE 2: final (head-mean, bias3, self-loop, elu) -> f32 [N,128]
template <int C, int MODE>
__global__ __launch_bounds__(256) void fused_gat(
    const unsigned short* __restrict__ xl,  // [*, 4C] bf16
    const float* __restrict__ xr,           // [N, 4C] f32
    const float* __restrict__ att,          // [4C]
    const int* __restrict__ psrc, const int* __restrict__ rp,
    const float* __restrict__ bias, const float* __restrict__ sl,
    void* __restrict__ outv, int N) {
  constexpr int D = 4 * C;
  constexpr int R = D / 64;  // 4 (C=64) or 8 (C=128); lane's channels all in head lane>>4
  int d = blockIdx.x * 4 + (threadIdx.x >> 6);
  int lane = threadIdx.x & 63;
  if (d >= N) return;
  float xrr[R], atr[R];
#pragma unroll
  for (int j = 0; j < R; ++j) {
    xrr[j] = xr[(size_t)d * D + lane * R + j];
    atr[j] = att[lane * R + j];
  }
  float m = -3.0e38f, l = 0.f, acc[R] = {};
  int i0 = rp[d], i1 = rp[d + 1];
  for (int i = i0; i < i1; ++i) {
    int s = psrc[i];
    float xf[R];
    if (R == 4) {
      ushort4 xv = *(const ushort4*)&xl[(size_t)s * D + lane * 4];
      xf[0] = bf2f(xv.x); xf[1] = bf2f(xv.y); xf[2] = bf2f(xv.z); xf[3] = bf2f(xv.w);
    } else {
      short8 xv = *(const short8*)&xl[(size_t)s * D + lane * 8];
#pragma unroll
      for (int j = 0; j < R; ++j) xf[j] = bf2f((unsigned short)xv[j]);
    }
    float dot = 0.f;
#pragma unroll
    for (int j = 0; j < R; ++j) {
      float v = xf[j] + xrr[j];
      v = v >= 0.f ? v : 0.2f * v;
      dot += v * atr[j];
    }
    dot += __shfl_xor(dot, 1); dot += __shfl_xor(dot, 2);
    dot += __shfl_xor(dot, 4); dot += __shfl_xor(dot, 8);
    float mn = fmaxf(m, dot);
    float sc = __expf(m - mn);
    float w = __expf(dot - mn);
    l = l * sc + w;
#pragma unroll
    for (int j = 0; j < R; ++j) acc[j] = acc[j] * sc + w * xf[j];
    m = mn;
  }
  float dinv = 1.f / (l + 1e-16f);
  if (MODE == 0) {
    unsigned short* out = (unsigned short*)outv;
#pragma unroll
    for (int j = 0; j < R; ++j) {
      int c = lane * R + j;
      out[(size_t)d * D + c] = f2bf(elu_f(acc[j] * dinv + bias[c]));
    }
  } else if (MODE == 1) {
    unsigned short* out = (unsigned short*)outv;
#pragma unroll
    for (int j = 0; j < R; ++j) {
      int c = lane * R + j;
      out[(size_t)d * D + c] = f2bf(elu_f(acc[j] * dinv + bias[c] + sl[(size_t)d * 64 + (c & 63)]));
    }
  } else {
    float* out = (float*)outv;
    float r[R];
#pragma unroll
    for (int j = 0; j < R; ++j) {
      r[j] = acc[j] * dinv;
      r[j] += __shfl_xor(r[j], 16);
      r[j] += __shfl_xor(r[j], 32);
    }
    if (lane < 16) {
#pragma unroll
      for (int j = 0; j < R; ++j) {
        int c = lane * R + j;  // 0..127
        out[(size_t)d * 128 + c] = elu_f(0.25f * r[j] + bias[c] + sl[(size_t)d * 128 + c]);
      }
    }
  }
}

extern "C" void kernel_launch(void* const* d_in, const int* in_sizes, int n_in,
                              void* d_out, int out_size, void* d_ws, size_t ws_size,
                              hipStream_t stream) {
  const float* x_sample = (const float*)d_in[0];
  const float* x_gene   = (const float*)d_in[1];
  const int* sg_src = (const int*)d_in[2];
  const int* sg_dst = (const int*)d_in[3];
  const int* gs_src = (const int*)d_in[4];
  const int* gs_dst = (const int*)d_in[5];
  const float* Wl1_sg = (const float*)d_in[6];
  const float* bl1_sg = (const float*)d_in[7];
  const float* Wr1_sg = (const float*)d_in[8];
  const float* br1_sg = (const float*)d_in[9];
  const float* att1_sg = (const float*)d_in[10];
  const float* bias1_sg = (const float*)d_in[11];
  const float* Wl1_gs = (const float*)d_in[12];
  const float* bl1_gs = (const float*)d_in[13];
  const float* Wr1_gs = (const float*)d_in[14];
  const float* br1_gs = (const float*)d_in[15];
  const float* att1_gs = (const float*)d_in[16];
  const float* bias1_gs = (const float*)d_in[17];
  const float* Wl3 = (const float*)d_in[18];
  const float* bl3 = (const float*)d_in[19];
  const float* Wr3 = (const float*)d_in[20];
  const float* br3 = (const float*)d_in[21];
  const float* att3 = (const float*)d_in[22];
  const float* bias3 = (const float*)d_in[23];
  const float* sl1_W = (const float*)d_in[24];
  const float* sl1_b = (const float*)d_in[25];
  const float* sl3_W = (const float*)d_in[26];
  const float* sl3_b = (const float*)d_in[27];

  float* ws = (float*)d_ws;
  size_t off = 0;
  auto alloc = [&](size_t n) { float* p = ws + off; off += n; return p; };
  float* xr_sg = alloc((size_t)kNG * 256);   // f32, dead after stage 1 -> aliased by xl3
  float* xr_gs = alloc((size_t)kNS * 256);
  float* xr3   = alloc((size_t)kNS * 512);
  float* sl1o  = alloc((size_t)kNS * 64);
  float* sl3o  = alloc((size_t)kNS * 128);
  unsigned short* xl_sg  = (unsigned short*)alloc((size_t)kNS * 256 / 2);
  unsigned short* xl_gs  = (unsigned short*)alloc((size_t)kNG * 256 / 2);
  unsigned short* xs_bf  = (unsigned short*)alloc((size_t)kNS * 256 / 2);
  unsigned short* xg_bf  = (unsigned short*)alloc((size_t)kNG * 256 / 2);
  unsigned short* xg1_bf = (unsigned short*)alloc((size_t)kNG * 256 / 2);
  unsigned short* xs1_bf = (unsigned short*)alloc((size_t)kNS * 256 / 2);
  unsigned short* WtL1sg = (unsigned short*)alloc(256 * 256 / 2);
  unsigned short* WtR1sg = (unsigned short*)alloc(256 * 256 / 2);
  unsigned short* WtL1gs = (unsigned short*)alloc(256 * 256 / 2);
  unsigned short* WtR1gs = (unsigned short*)alloc(256 * 256 / 2);
  unsigned short* WtL3   = (unsigned short*)alloc(256 * 512 / 2);
  unsigned short* WtR3   = (unsigned short*)alloc(256 * 512 / 2);
  unsigned short* Wtsl1  = (unsigned short*)alloc(256 * 64 / 2);
  unsigned short* Wtsl3  = (unsigned short*)alloc(256 * 128 / 2);
  int* deg_g  = (int*)alloc(kNG);
  int* rp_g   = (int*)alloc(kNG + 1);
  int* psrc_g = (int*)alloc(kE);
  int* deg_s  = (int*)alloc(kNS);
  int* rp_s   = (int*)alloc(kNS + 1);
  int* psrc_s = (int*)alloc(kE);
  // xl3 bf16 [NG,512] aliases xr_sg f32 [NG,256] (same byte size; xr_sg dead after stage 1)
  unsigned short* xl3 = (unsigned short*)xr_sg;

  auto gemm_f32 = [&](const unsigned short* A, const unsigned short* Bt, const float* bias,
                      float* Cp, int M, int N) {
    dim3 grid(N / 64, (M + 127) / 128);
    gemm_mfma<0><<<grid, 256, 0, stream>>>(A, Bt, bias, Cp, nullptr, M, N, 256);
  };
  auto gemm_bf = [&](const unsigned short* A, const unsigned short* Bt, const float* bias,
                     unsigned short* Cp, int M, int N) {
    dim3 grid(N / 64, (M + 127) / 128);
    gemm_mfma<1><<<grid, 256, 0, stream>>>(A, Bt, bias, nullptr, Cp, M, N, 256);
  };
  auto wT = [&](const float* W, unsigned short* Wt, int N) {
    conv_wT<<<(256 * N + 255) / 256, 256, 0, stream>>>(W, Wt, 256, N);
  };

  // ---- conversions ----
  conv_bf16<<<(kNS * 256 / 4 + 255) / 256, 256, 0, stream>>>(x_sample, xs_bf, kNS * 256);
  conv_bf16<<<(kNG * 256 / 4 + 255) / 256, 256, 0, stream>>>(x_gene, xg_bf, kNG * 256);
  wT(Wl1_sg, WtL1sg, 256); wT(Wr1_sg, WtR1sg, 256);
  wT(Wl1_gs, WtL1gs, 256); wT(Wr1_gs, WtR1gs, 256);
  wT(Wl3, WtL3, 512); wT(Wr3, WtR3, 512);
  wT(sl1_W, Wtsl1, 64); wT(sl3_W, Wtsl3, 128);

  // ---- CSR build ----
  hipMemsetAsync(deg_g, 0, kNG * sizeof(int), stream);
  hipMemsetAsync(deg_s, 0, kNS * sizeof(int), stream);
  histo<<<(kE + 255) / 256, 256, 0, stream>>>(sg_dst, deg_g, kE);
  histo<<<(kE + 255) / 256, 256, 0, stream>>>(gs_dst, deg_s, kE);
  exclusive_scan<<<1, 256, 0, stream>>>(deg_g, rp_g, kNG);
  exclusive_scan<<<1, 256, 0, stream>>>(deg_s, rp_s, kNS);
  hipMemsetAsync(deg_g, 0, kNG * sizeof(int), stream);
  hipMemsetAsync(deg_s, 0, kNS * sizeof(int), stream);
  build_perm_src<<<(kE + 255) / 256, 256, 0, stream>>>(sg_dst, sg_src, rp_g, deg_g, psrc_g, kE);
  build_perm_src<<<(kE + 255) / 256, 256, 0, stream>>>(gs_dst, gs_src, rp_s, deg_s, psrc_s, kE);

  // ---- layer-1 transforms ----
  gemm_bf (xs_bf, WtL1sg, bl1_sg, xl_sg, kNS, 256);
  gemm_f32(xg_bf, WtR1sg, br1_sg, xr_sg, kNG, 256);
  gemm_bf (xg_bf, WtL1gs, bl1_gs, xl_gs, kNG, 256);
  gemm_f32(xs_bf, WtR1gs, br1_gs, xr_gs, kNS, 256);
  gemm_f32(xs_bf, Wtsl1, sl1_b, sl1o, kNS, 64);

  // ---- stage 1: sg -> genes (C=64), fused ----
  fused_gat<64, 0><<<(kNG + 3) / 4, 256, 0, stream>>>(
      xl_sg, xr_sg, att1_sg, psrc_g, rp_g, bias1_sg, nullptr, xg1_bf, kNG);

  // ---- stage 2: gs -> samples (C=64), fused ----
  fused_gat<64, 1><<<(kNS + 3) / 4, 256, 0, stream>>>(
      xl_gs, xr_gs, att1_gs, psrc_s, rp_s, bias1_gs, sl1o, xs1_bf, kNS);

  // ---- layer-3 transforms ----
  gemm_bf (xg1_bf, WtL3, bl3, xl3, kNG, 512);
  gemm_f32(xs1_bf, WtR3, br3, xr3, kNS, 512);
  gemm_f32(xs1_bf, Wtsl3, sl3_b, sl3o, kNS, 128);

  // ---- stage 3: gs -> samples (C=128), fused, head-mean ----
  fused_gat<128, 2><<<(kNS + 3) / 4, 256, 0, stream>>>(
      xl3, xr3, att3, psrc_s, rp_s, bias3, sl3o, d_out, kNS);
}

// Round 5
// 235.768 us; speedup vs baseline: 4.1685x; 1.3640x over previous
//
#include <hip/hip_runtime.h>
#include <hip/hip_bf16.h>
#include <cstdint>

constexpr int kNS = 4096;
constexpr int kNG = 20000;
constexpr int kE  = 131072;

typedef __attribute__((ext_vector_type(8))) short short8;
typedef __attribute__((ext_vector_type(4))) float f32x4;

__device__ __forceinline__ float elu_f(float v) { return v > 0.f ? v : expm1f(v); }

__device__ __forceinline__ unsigned short f2bf(float f) {
  union { float f; unsigned u; } v; v.f = f;
  unsigned r = v.u + 0x7FFF + ((v.u >> 16) & 1);
  return (unsigned short)(r >> 16);
}

__device__ __forceinline__ float bf2f(unsigned short u) {
  union { unsigned u; float f; } v; v.u = ((unsigned)u) << 16; return v.f;
}

// ================= prep: all conversions/transposes/bias concat in ONE kernel ===========
// block map: [0,1024) xs conv | [1024,6024) xg conv | 2240 W-transpose blocks | 7 bias blocks
__global__ __launch_bounds__(256) void prep(
    const float* __restrict__ xs, const float* __restrict__ xg,
    const float* __restrict__ Wl1_sg, const float* __restrict__ Wr1_gs,
    const float* __restrict__ sl1_W, const float* __restrict__ Wr1_sg,
    const float* __restrict__ Wl1_gs, const float* __restrict__ Wl3,
    const float* __restrict__ Wr3, const float* __restrict__ sl3_W,
    const float* __restrict__ bl1_sg, const float* __restrict__ br1_gs,
    const float* __restrict__ sl1_b, const float* __restrict__ br1_sg,
    const float* __restrict__ bl1_gs, const float* __restrict__ br3,
    const float* __restrict__ sl3_b,
    unsigned short* __restrict__ xs_bf, unsigned short* __restrict__ xg_bf,
    unsigned short* __restrict__ Wt1, unsigned short* __restrict__ Wt2,
    unsigned short* __restrict__ Wt3, unsigned short* __restrict__ Wt4,
    float* __restrict__ bc1, float* __restrict__ bc2, float* __restrict__ bc4) {
  int bid = blockIdx.x, tid = threadIdx.x;
  if (bid < 1024) {
    int i = (bid * 256 + tid) * 4;
    float4 v = *(const float4*)&xs[i];
    ushort4 o = {f2bf(v.x), f2bf(v.y), f2bf(v.z), f2bf(v.w)};
    *(ushort4*)&xs_bf[i] = o;
    return;
  }
  bid -= 1024;
  if (bid < 5000) {
    int i = (bid * 256 + tid) * 4;
    float4 v = *(const float4*)&xg[i];
    ushort4 o = {f2bf(v.x), f2bf(v.y), f2bf(v.z), f2bf(v.w)};
    *(ushort4*)&xg_bf[i] = o;
    return;
  }
  bid -= 5000;
  // W [256,N] f32 -> Wt [N,256] bf16 segments
  auto wseg = [&](const float* W, unsigned short* Wt, int N) {
    int i = bid * 256 + tid;
    int n = i >> 8, k = i & 255;
    Wt[i] = f2bf(W[(size_t)k * N + n]);
  };
  if (bid < 256) { wseg(Wl1_sg, Wt1, 256); return; } bid -= 256;
  if (bid < 256) { wseg(Wr1_gs, Wt1 + 256 * 256, 256); return; } bid -= 256;
  if (bid < 64)  { wseg(sl1_W,  Wt1 + 512 * 256, 64);  return; } bid -= 64;
  if (bid < 256) { wseg(Wr1_sg, Wt2, 256); return; } bid -= 256;
  if (bid < 256) { wseg(Wl1_gs, Wt2 + 256 * 256, 256); return; } bid -= 256;
  if (bid < 512) { wseg(Wl3,    Wt3, 512); return; } bid -= 512;
  if (bid < 512) { wseg(Wr3,    Wt4, 512); return; } bid -= 512;
  if (bid < 128) { wseg(sl3_W,  Wt4 + 512 * 256, 128); return; } bid -= 128;
  int j = bid * 256 + tid;
  if (j < 256) bc1[j] = bl1_sg[j];
  else if (j < 512) bc1[j] = br1_gs[j - 256];
  else if (j < 576) bc1[j] = sl1_b[j - 512];
  else if (j < 832) bc2[j - 576] = br1_sg[j - 576];
  else if (j < 1088) bc2[j - 576] = bl1_gs[j - 832];
  else if (j < 1600) bc4[j - 1088] = br3[j - 1088];
  else if (j < 1728) bc4[j - 1088] = sl3_b[j - 1600];
}

// ================= CSR build (both relations per kernel) =================
__global__ void histo_dual(const int* __restrict__ sg_dst, const int* __restrict__ gs_dst,
                           int* __restrict__ deg_g, int* __restrict__ deg_s) {
  int i = blockIdx.x * 256 + threadIdx.x;
  if (i < kE) atomicAdd(&deg_g[sg_dst[i]], 1);
  else atomicAdd(&deg_s[gs_dst[i - kE]], 1);
}

__global__ __launch_bounds__(256) void scan_dual(int* __restrict__ deg_g, int* __restrict__ rp_g,
                                                 int ng, int* __restrict__ deg_s,
                                                 int* __restrict__ rp_s, int ns) {
  int* deg = blockIdx.x == 0 ? deg_g : deg_s;
  int* rp  = blockIdx.x == 0 ? rp_g  : rp_s;
  int n    = blockIdx.x == 0 ? ng    : ns;
  __shared__ int partial[256];
  int tid = threadIdx.x;
  int chunk = (n + 255) / 256;
  int b0 = tid * chunk;
  int b1 = b0 + chunk < n ? b0 + chunk : n;
  int s = 0;
  for (int i = b0; i < b1; ++i) s += deg[i];
  partial[tid] = s;
  __syncthreads();
  if (tid == 0) {
    int run = 0;
    for (int i = 0; i < 256; ++i) { int t = partial[i]; partial[i] = run; run += t; }
  }
  __syncthreads();
  int run = partial[tid];
  for (int i = b0; i < b1; ++i) { rp[i] = run; run += deg[i]; deg[i] = 0; }
  if (b0 <= n && b1 == n) rp[n] = run;
}

__global__ void build_dual(const int* __restrict__ sg_dst, const int* __restrict__ sg_src,
                           const int* __restrict__ rp_g, int* __restrict__ cur_g,
                           int* __restrict__ ps_g,
                           const int* __restrict__ gs_dst, const int* __restrict__ gs_src,
                           const int* __restrict__ rp_s, int* __restrict__ cur_s,
                           int* __restrict__ ps_s) {
  int i = blockIdx.x * 256 + threadIdx.x;
  if (i < kE) {
    int d = sg_dst[i];
    ps_g[rp_g[d] + atomicAdd(&cur_g[d], 1)] = sg_src[i];
  } else {
    i -= kE;
    int d = gs_dst[i];
    ps_s[rp_s[d] + atomicAdd(&cur_s[d], 1)] = gs_src[i];
  }
}

// ================= MFMA GEMM: C[M,N] = A[M,K=256] @ Bt[N,K]^T + bias -> bf16 ==========
__global__ __launch_bounds__(256) void gemm_mfma(
    const unsigned short* __restrict__ A, const unsigned short* __restrict__ Bt,
    const float* __restrict__ bias, unsigned short* __restrict__ Cb, int M, int N) {
  __shared__ alignas(16) unsigned short As[128 * 32];
  __shared__ alignas(16) unsigned short Bs[64 * 32];
  const int tid = threadIdx.x;
  const int wave = tid >> 6, lane = tid & 63;
  const int brow = blockIdx.y * 128, bcol = blockIdx.x * 64;
  const int wrow = (wave >> 1) * 64, wcol = (wave & 1) * 32;
  const int la = lane & 15, lk = (lane >> 4) * 8;
  f32x4 acc[4][2] = {};
  for (int k0 = 0; k0 < 256; k0 += 32) {
#pragma unroll
    for (int c = 0; c < 2; ++c) {
      int seg = wave * 128 + c * 64 + lane;
      int row = seg >> 2, ks = (seg & 3) * 8;
      int grow = brow + row; if (grow > M - 1) grow = M - 1;
      const unsigned short* g = A + (size_t)grow * 256 + k0 + ks;
      __builtin_amdgcn_global_load_lds(
          (const __attribute__((address_space(1))) unsigned*)g,
          (__attribute__((address_space(3))) unsigned*)&As[(wave * 128 + c * 64) * 8],
          16, 0, 0);
    }
    {
      int seg = wave * 64 + lane;
      int row = seg >> 2, ks = (seg & 3) * 8;
      const unsigned short* g = Bt + (size_t)(bcol + row) * 256 + k0 + ks;
      __builtin_amdgcn_global_load_lds(
          (const __attribute__((address_space(1))) unsigned*)g,
          (__attribute__((address_space(3))) unsigned*)&Bs[(wave * 64) * 8],
          16, 0, 0);
    }
    __syncthreads();
    short8 bfr[2];
#pragma unroll
    for (int ni = 0; ni < 2; ++ni)
      bfr[ni] = *(const short8*)&Bs[(wcol + ni * 16 + la) * 32 + lk];
#pragma unroll
    for (int mi = 0; mi < 4; ++mi) {
      short8 af = *(const short8*)&As[(wrow + mi * 16 + la) * 32 + lk];
#pragma unroll
      for (int ni = 0; ni < 2; ++ni)
        acc[mi][ni] = __builtin_amdgcn_mfma_f32_16x16x32_bf16(af, bfr[ni], acc[mi][ni], 0, 0, 0);
    }
    __syncthreads();
  }
  const int r0 = (lane >> 4) * 4;
#pragma unroll
  for (int mi = 0; mi < 4; ++mi) {
#pragma unroll
    for (int r = 0; r < 4; ++r) {
      int row = brow + wrow + mi * 16 + r0 + r;
      if (row >= M) continue;
#pragma unroll
      for (int ni = 0; ni < 2; ++ni) {
        int col = bcol + wcol + ni * 16 + la;
        Cb[(size_t)row * N + col] = f2bf(acc[mi][ni][r] + bias[col]);
      }
    }
  }
}

// ================= fused GATv2, 4-edge batched online softmax, wave/dst ================
template <int R>
__device__ __forceinline__ void load_xf(const unsigned short* p, float* xf) {
  if constexpr (R == 4) {
    ushort4 v = *(const ushort4*)p;
    xf[0] = bf2f(v.x); xf[1] = bf2f(v.y); xf[2] = bf2f(v.z); xf[3] = bf2f(v.w);
  } else {
    short8 v = *(const short8*)p;
#pragma unroll
    for (int j = 0; j < 8; ++j) xf[j] = bf2f((unsigned short)v[j]);
  }
}

// MODE 0: bias+elu -> bf16 [N,256]; MODE 1: +self-loop -> bf16 [N,256];
// MODE 2: head-mean+bias3+self-loop+elu -> f32 [N,128]
template <int C, int MODE>
__global__ __launch_bounds__(256) void fused_gat(
    const unsigned short* __restrict__ xl, int ldl,
    const unsigned short* __restrict__ xr, int ldr,
    const float* __restrict__ att,
    const int* __restrict__ psrc, const int* __restrict__ rp,
    const float* __restrict__ bias,
    const unsigned short* __restrict__ sl, int ldsl,
    void* __restrict__ outv, int N) {
  constexpr int D = 4 * C;
  constexpr int R = D / 64;
  int d = blockIdx.x * 4 + (threadIdx.x >> 6);
  int lane = threadIdx.x & 63;
  if (d >= N) return;
  float xrr[R], atr[R];
  {
    float t[R];
    load_xf<R>(&xr[(size_t)d * ldr + lane * R], t);
#pragma unroll
    for (int j = 0; j < R; ++j) { xrr[j] = t[j]; atr[j] = att[lane * R + j]; }
  }
  float m = -3.0e38f, l = 0.f, acc[R] = {};
  int i0 = rp[d], i1 = rp[d + 1];
  for (int i = i0; i < i1; i += 4) {
    int s0 = psrc[i];
    int s1 = (i + 1 < i1) ? psrc[i + 1] : s0;
    int s2 = (i + 2 < i1) ? psrc[i + 2] : s0;
    int s3 = (i + 3 < i1) ? psrc[i + 3] : s0;
    float xf[4][R];
    load_xf<R>(&xl[(size_t)s0 * ldl + lane * R], xf[0]);
    load_xf<R>(&xl[(size_t)s1 * ldl + lane * R], xf[1]);
    load_xf<R>(&xl[(size_t)s2 * ldl + lane * R], xf[2]);
    load_xf<R>(&xl[(size_t)s3 * ldl + lane * R], xf[3]);
    float dt[4];
#pragma unroll
    for (int b = 0; b < 4; ++b) {
      float a = 0.f;
#pragma unroll
      for (int j = 0; j < R; ++j) {
        float v = xf[b][j] + xrr[j];
        v = v >= 0.f ? v : 0.2f * v;
        a = fmaf(v, atr[j], a);
      }
      dt[b] = a;
    }
#pragma unroll
    for (int b = 0; b < 4; ++b) {
      dt[b] += __shfl_xor(dt[b], 1);
      dt[b] += __shfl_xor(dt[b], 2);
      dt[b] += __shfl_xor(dt[b], 4);
      dt[b] += __shfl_xor(dt[b], 8);
    }
    if (i + 1 >= i1) dt[1] = -3.0e38f;
    if (i + 2 >= i1) dt[2] = -3.0e38f;
    if (i + 3 >= i1) dt[3] = -3.0e38f;
    float bm = fmaxf(fmaxf(dt[0], dt[1]), fmaxf(dt[2], dt[3]));
    float mn = fmaxf(m, bm);
    float sc = __expf(m - mn);
    float w0 = __expf(dt[0] - mn), w1 = __expf(dt[1] - mn);
    float w2 = __expf(dt[2] - mn), w3 = __expf(dt[3] - mn);
    l = l * sc + ((w0 + w1) + (w2 + w3));
#pragma unroll
    for (int j = 0; j < R; ++j)
      acc[j] = acc[j] * sc + w0 * xf[0][j] + w1 * xf[1][j] + w2 * xf[2][j] + w3 * xf[3][j];
    m = mn;
  }
  float dinv = 1.f / (l + 1e-16f);
  if (MODE == 0) {
    unsigned short* out = (unsigned short*)outv;
    ushort4 o;
    o.x = f2bf(elu_f(acc[0] * dinv + bias[lane * 4 + 0]));
    o.y = f2bf(elu_f(acc[1] * dinv + bias[lane * 4 + 1]));
    o.z = f2bf(elu_f(acc[2] * dinv + bias[lane * 4 + 2]));
    o.w = f2bf(elu_f(acc[3] * dinv + bias[lane * 4 + 3]));
    *(ushort4*)&out[(size_t)d * 256 + lane * 4] = o;
  } else if (MODE == 1) {
    unsigned short* out = (unsigned short*)outv;
    ushort4 o;
#pragma unroll
    for (int j = 0; j < 4; ++j) {
      int c = lane * 4 + j;
      float v = acc[j] * dinv + bias[c] + bf2f(sl[(size_t)d * ldsl + (c & 63)]);
      ((unsigned short*)&o)[j] = f2bf(elu_f(v));
    }
    *(ushort4*)&out[(size_t)d * 256 + lane * 4] = o;
  } else {
    float* out = (float*)outv;
    float r[R];
#pragma unroll
    for (int j = 0; j < R; ++j) {
      r[j] = acc[j] * dinv;
      r[j] += __shfl_xor(r[j], 16);
      r[j] += __shfl_xor(r[j], 32);
    }
    if (lane < 16) {
#pragma unroll
      for (int j = 0; j < R; ++j) {
        int c = lane * R + j;  // 0..127
        out[(size_t)d * 128 + c] =
            elu_f(0.25f * r[j] + bias[c] + bf2f(sl[(size_t)d * ldsl + c]));
      }
    }
  }
}

extern "C" void kernel_launch(void* const* d_in, const int* in_sizes, int n_in,
                              void* d_out, int out_size, void* d_ws, size_t ws_size,
                              hipStream_t stream) {
  const float* x_sample = (const float*)d_in[0];
  const float* x_gene   = (const float*)d_in[1];
  const int* sg_src = (const int*)d_in[2];
  const int* sg_dst = (const int*)d_in[3];
  const int* gs_src = (const int*)d_in[4];
  const int* gs_dst = (const int*)d_in[5];
  const float* Wl1_sg = (const float*)d_in[6];
  const float* bl1_sg = (const float*)d_in[7];
  const float* Wr1_sg = (const float*)d_in[8];
  const float* br1_sg = (const float*)d_in[9];
  const float* att1_sg = (const float*)d_in[10];
  const float* bias1_sg = (const float*)d_in[11];
  const float* Wl1_gs = (const float*)d_in[12];
  const float* bl1_gs = (const float*)d_in[13];
  const float* Wr1_gs = (const float*)d_in[14];
  const float* br1_gs = (const float*)d_in[15];
  const float* att1_gs = (const float*)d_in[16];
  const float* bias1_gs = (const float*)d_in[17];
  const float* Wl3 = (const float*)d_in[18];
  const float* bl3 = (const float*)d_in[19];
  const float* Wr3 = (const float*)d_in[20];
  const float* br3 = (const float*)d_in[21];
  const float* att3 = (const float*)d_in[22];
  const float* bias3 = (const float*)d_in[23];
  const float* sl1_W = (const float*)d_in[24];
  const float* sl1_b = (const float*)d_in[25];
  const float* sl3_W = (const float*)d_in[26];
  const float* sl3_b = (const float*)d_in[27];

  float* ws = (float*)d_ws;
  size_t off = 0;
  auto alloc = [&](size_t n) { float* p = ws + off; off += n; return p; };
  float* bc1 = alloc(576);
  float* bc2 = alloc(512);
  float* bc4 = alloc(640);
  unsigned short* cat1 = (unsigned short*)alloc((size_t)kNS * 576 / 2);  // xl_sg|xr_gs|sl1o
  unsigned short* cat2 = (unsigned short*)alloc((size_t)kNG * 512 / 2);  // xr_sg|xl_gs
  unsigned short* xl3  = (unsigned short*)alloc((size_t)kNG * 512 / 2);
  unsigned short* cat4 = (unsigned short*)alloc((size_t)kNS * 640 / 2);  // xr3|sl3o
  unsigned short* xs_bf  = (unsigned short*)alloc((size_t)kNS * 256 / 2);
  unsigned short* xg_bf  = (unsigned short*)alloc((size_t)kNG * 256 / 2);
  unsigned short* xg1_bf = (unsigned short*)alloc((size_t)kNG * 256 / 2);
  unsigned short* xs1_bf = (unsigned short*)alloc((size_t)kNS * 256 / 2);
  unsigned short* Wt1 = (unsigned short*)alloc(576 * 256 / 2);
  unsigned short* Wt2 = (unsigned short*)alloc(512 * 256 / 2);
  unsigned short* Wt3 = (unsigned short*)alloc(512 * 256 / 2);
  unsigned short* Wt4 = (unsigned short*)alloc(640 * 256 / 2);
  int* deg_g  = (int*)alloc(kNG);       // contiguous with deg_s for single memset
  int* deg_s  = (int*)alloc(kNS);
  int* rp_g   = (int*)alloc(kNG + 1);
  int* rp_s   = (int*)alloc(kNS + 1);
  int* psrc_g = (int*)alloc(kE);
  int* psrc_s = (int*)alloc(kE);

  hipMemsetAsync(deg_g, 0, (kNG + kNS) * sizeof(int), stream);

  prep<<<8271, 256, 0, stream>>>(
      x_sample, x_gene, Wl1_sg, Wr1_gs, sl1_W, Wr1_sg, Wl1_gs, Wl3, Wr3, sl3_W,
      bl1_sg, br1_gs, sl1_b, br1_sg, bl1_gs, br3, sl3_b,
      xs_bf, xg_bf, Wt1, Wt2, Wt3, Wt4, bc1, bc2, bc4);

  histo_dual<<<1024, 256, 0, stream>>>(sg_dst, gs_dst, deg_g, deg_s);
  scan_dual<<<2, 256, 0, stream>>>(deg_g, rp_g, kNG, deg_s, rp_s, kNS);
  build_dual<<<1024, 256, 0, stream>>>(sg_dst, sg_src, rp_g, deg_g, psrc_g,
                                       gs_dst, gs_src, rp_s, deg_s, psrc_s);

  auto gemm = [&](const unsigned short* A, const unsigned short* Bt, const float* bias,
                  unsigned short* Cp, int M, int N) {
    dim3 grid(N / 64, (M + 127) / 128);
    gemm_mfma<<<grid, 256, 0, stream>>>(A, Bt, bias, Cp, M, N);
  };

  // layer-1: 2 fat GEMMs
  gemm(xs_bf, Wt1, bc1, cat1, kNS, 576);   // [xl_sg | xr_gs | sl1o]
  gemm(xg_bf, Wt2, bc2, cat2, kNG, 512);   // [xr_sg | xl_gs]

  // stage 1: sg -> genes (C=64)
  fused_gat<64, 0><<<(kNG + 3) / 4, 256, 0, stream>>>(
      cat1, 576, cat2, 512, att1_sg, psrc_g, rp_g, bias1_sg, nullptr, 0, xg1_bf, kNG);

  // stage 2: gs -> samples (C=64)
  fused_gat<64, 1><<<(kNS + 3) / 4, 256, 0, stream>>>(
      cat2 + 256, 512, cat1 + 256, 576, att1_gs, psrc_s, rp_s, bias1_gs,
      cat1 + 512, 576, xs1_bf, kNS);

  // layer-3: 2 GEMMs
  gemm(xg1_bf, Wt3, bl3, xl3, kNG, 512);
  gemm(xs1_bf, Wt4, bc4, cat4, kNS, 640);  // [xr3 | sl3o]

  // stage 3: gs -> samples (C=128), head-mean
  fused_gat<128, 2><<<(kNS + 3) / 4, 256, 0, stream>>>(
      xl3, 512, cat4, 640, att3, psrc_s, rp_s, bias3, cat4 + 512, 640, d_out, kNS);
}

// Round 6
// 193.954 us; speedup vs baseline: 5.0672x; 1.2156x over previous
//
#include <hip/hip_runtime.h>
#include <hip/hip_bf16.h>
#include <cstdint>

constexpr int kNS = 4096;
constexpr int kNG = 20000;
constexpr int kE  = 131072;
constexpr int kNCAT = kNG + kNS;          // 24096
constexpr int kNB = (kNCAT + 255) / 256;  // 95 scan blocks

typedef __attribute__((ext_vector_type(8))) short short8;
typedef __attribute__((ext_vector_type(4))) float f32x4;

__device__ __forceinline__ float elu_f(float v) { return v > 0.f ? v : expm1f(v); }

__device__ __forceinline__ unsigned short f2bf(float f) {
  union { float f; unsigned u; } v; v.f = f;
  unsigned r = v.u + 0x7FFF + ((v.u >> 16) & 1);
  return (unsigned short)(r >> 16);
}

__device__ __forceinline__ float bf2f(unsigned short u) {
  union { unsigned u; float f; } v; v.u = ((unsigned)u) << 16; return v.f;
}

// ================= prep: conversions/transposes/bias concat + edge histogram ===========
// blocks: [0,1024) xs | [1024,6024) xg | [6024,8264) W-transpose | [8264,8271) bias
//         [8271,9295) histogram (deg pre-zeroed by memset)
__global__ __launch_bounds__(256) void prep(
    const float* __restrict__ xs, const float* __restrict__ xg,
    const float* __restrict__ Wl1_sg, const float* __restrict__ Wr1_gs,
    const float* __restrict__ sl1_W, const float* __restrict__ Wr1_sg,
    const float* __restrict__ Wl1_gs, const float* __restrict__ Wl3,
    const float* __restrict__ Wr3, const float* __restrict__ sl3_W,
    const float* __restrict__ bl1_sg, const float* __restrict__ br1_gs,
    const float* __restrict__ sl1_b, const float* __restrict__ br1_sg,
    const float* __restrict__ bl1_gs, const float* __restrict__ br3,
    const float* __restrict__ sl3_b,
    const int* __restrict__ sg_dst, const int* __restrict__ gs_dst,
    int* __restrict__ deg_g, int* __restrict__ deg_s,
    unsigned short* __restrict__ xs_bf, unsigned short* __restrict__ xg_bf,
    unsigned short* __restrict__ Wt1, unsigned short* __restrict__ Wt2,
    unsigned short* __restrict__ Wt3, unsigned short* __restrict__ Wt4,
    float* __restrict__ bc1, float* __restrict__ bc2, float* __restrict__ bc4) {
  int bid = blockIdx.x, tid = threadIdx.x;
  if (bid < 1024) {
    int i = (bid * 256 + tid) * 4;
    float4 v = *(const float4*)&xs[i];
    ushort4 o = {f2bf(v.x), f2bf(v.y), f2bf(v.z), f2bf(v.w)};
    *(ushort4*)&xs_bf[i] = o;
    return;
  }
  bid -= 1024;
  if (bid < 5000) {
    int i = (bid * 256 + tid) * 4;
    float4 v = *(const float4*)&xg[i];
    ushort4 o = {f2bf(v.x), f2bf(v.y), f2bf(v.z), f2bf(v.w)};
    *(ushort4*)&xg_bf[i] = o;
    return;
  }
  bid -= 5000;
  auto wseg = [&](const float* W, unsigned short* Wt, int N) {
    int i = bid * 256 + tid;
    int n = i >> 8, k = i & 255;
    Wt[i] = f2bf(W[(size_t)k * N + n]);
  };
  if (bid < 256) { wseg(Wl1_sg, Wt1, 256); return; } bid -= 256;
  if (bid < 256) { wseg(Wr1_gs, Wt1 + 256 * 256, 256); return; } bid -= 256;
  if (bid < 64)  { wseg(sl1_W,  Wt1 + 512 * 256, 64);  return; } bid -= 64;
  if (bid < 256) { wseg(Wr1_sg, Wt2, 256); return; } bid -= 256;
  if (bid < 256) { wseg(Wl1_gs, Wt2 + 256 * 256, 256); return; } bid -= 256;
  if (bid < 512) { wseg(Wl3,    Wt3, 512); return; } bid -= 512;
  if (bid < 512) { wseg(Wr3,    Wt4, 512); return; } bid -= 512;
  if (bid < 128) { wseg(sl3_W,  Wt4 + 512 * 256, 128); return; } bid -= 128;
  if (bid < 7) {
    int j = bid * 256 + tid;
    if (j < 256) bc1[j] = bl1_sg[j];
    else if (j < 512) bc1[j] = br1_gs[j - 256];
    else if (j < 576) bc1[j] = sl1_b[j - 512];
    else if (j < 832) bc2[j - 576] = br1_sg[j - 576];
    else if (j < 1088) bc2[j - 576] = bl1_gs[j - 832];
    else if (j < 1600) bc4[j - 1088] = br3[j - 1088];
    else if (j < 1728) bc4[j - 1088] = sl3_b[j - 1600];
    return;
  }
  bid -= 7;
  // histogram: 1024 blocks over 2*kE edges
  int i = bid * 256 + tid;
  if (i < kE) atomicAdd(&deg_g[sg_dst[i]], 1);
  else atomicAdd(&deg_s[gs_dst[i - kE]], 1);
}

// ================= parallel CSR scan (3 phases over concatenated deg) =================
__global__ __launch_bounds__(256) void scan_blocksum(const int* __restrict__ deg,
                                                     int* __restrict__ part) {
  int i = blockIdx.x * 256 + threadIdx.x;
  int v = i < kNCAT ? deg[i] : 0;
  v += __shfl_xor(v, 1); v += __shfl_xor(v, 2); v += __shfl_xor(v, 4);
  v += __shfl_xor(v, 8); v += __shfl_xor(v, 16); v += __shfl_xor(v, 32);
  __shared__ int ssum[4];
  if ((threadIdx.x & 63) == 0) ssum[threadIdx.x >> 6] = v;
  __syncthreads();
  if (threadIdx.x == 0) part[blockIdx.x] = ssum[0] + ssum[1] + ssum[2] + ssum[3];
}

__global__ __launch_bounds__(128) void scan_part(int* __restrict__ part, int n) {
  __shared__ int s[128];
  int t = threadIdx.x;
  int v = t < n ? part[t] : 0;
  s[t] = v;
  __syncthreads();
  for (int ofs = 1; ofs < 128; ofs <<= 1) {
    int add = t >= ofs ? s[t - ofs] : 0;
    __syncthreads();
    s[t] += add;
    __syncthreads();
  }
  if (t < n) part[t] = s[t] - v;
}

__global__ __launch_bounds__(256) void scan_write(int* __restrict__ deg,
                                                  const int* __restrict__ part,
                                                  int* __restrict__ rp_g,
                                                  int* __restrict__ rp_s) {
  int b = blockIdx.x, t = threadIdx.x;
  int i = b * 256 + t;
  int v = i < kNCAT ? deg[i] : 0;
  __shared__ int s[256];
  s[t] = v;
  __syncthreads();
  for (int ofs = 1; ofs < 256; ofs <<= 1) {
    int add = t >= ofs ? s[t - ofs] : 0;
    __syncthreads();
    s[t] += add;
    __syncthreads();
  }
  int ex = part[b] + s[t] - v;
  if (i < kNG) { rp_g[i] = ex; deg[i] = 0; }
  else if (i < kNCAT) { rp_s[i - kNG] = ex - kE; deg[i] = 0; }
  if (b == 0 && t == 0) { rp_g[kNG] = kE; rp_s[kNS] = kE; }
}

__global__ void build_dual(const int* __restrict__ sg_dst, const int* __restrict__ sg_src,
                           const int* __restrict__ rp_g, int* __restrict__ cur_g,
                           int* __restrict__ ps_g,
                           const int* __restrict__ gs_dst, const int* __restrict__ gs_src,
                           const int* __restrict__ rp_s, int* __restrict__ cur_s,
                           int* __restrict__ ps_s) {
  int i = blockIdx.x * 256 + threadIdx.x;
  if (i < kE) {
    int d = sg_dst[i];
    ps_g[rp_g[d] + atomicAdd(&cur_g[d], 1)] = sg_src[i];
  } else {
    i -= kE;
    int d = gs_dst[i];
    ps_s[rp_s[d] + atomicAdd(&cur_s[d], 1)] = gs_src[i];
  }
}

// ================= MFMA GEMM: C[M,N] = A[M,K=256] @ Bt[N,K]^T + bias -> bf16 ==========
__global__ __launch_bounds__(256) void gemm_mfma(
    const unsigned short* __restrict__ A, const unsigned short* __restrict__ Bt,
    const float* __restrict__ bias, unsigned short* __restrict__ Cb, int M, int N) {
  __shared__ alignas(16) unsigned short As[128 * 32];
  __shared__ alignas(16) unsigned short Bs[64 * 32];
  const int tid = threadIdx.x;
  const int wave = tid >> 6, lane = tid & 63;
  const int brow = blockIdx.y * 128, bcol = blockIdx.x * 64;
  const int wrow = (wave >> 1) * 64, wcol = (wave & 1) * 32;
  const int la = lane & 15, lk = (lane >> 4) * 8;
  f32x4 acc[4][2] = {};
  for (int k0 = 0; k0 < 256; k0 += 32) {
#pragma unroll
    for (int c = 0; c < 2; ++c) {
      int seg = wave * 128 + c * 64 + lane;
      int row = seg >> 2, ks = (seg & 3) * 8;
      int grow = brow + row; if (grow > M - 1) grow = M - 1;
      const unsigned short* g = A + (size_t)grow * 256 + k0 + ks;
      __builtin_amdgcn_global_load_lds(
          (const __attribute__((address_space(1))) unsigned*)g,
          (__attribute__((address_space(3))) unsigned*)&As[(wave * 128 + c * 64) * 8],
          16, 0, 0);
    }
    {
      int seg = wave * 64 + lane;
      int row = seg >> 2, ks = (seg & 3) * 8;
      const unsigned short* g = Bt + (size_t)(bcol + row) * 256 + k0 + ks;
      __builtin_amdgcn_global_load_lds(
          (const __attribute__((address_space(1))) unsigned*)g,
          (__attribute__((address_space(3))) unsigned*)&Bs[(wave * 64) * 8],
          16, 0, 0);
    }
    __syncthreads();
    short8 bfr[2];
#pragma unroll
    for (int ni = 0; ni < 2; ++ni)
      bfr[ni] = *(const short8*)&Bs[(wcol + ni * 16 + la) * 32 + lk];
#pragma unroll
    for (int mi = 0; mi < 4; ++mi) {
      short8 af = *(const short8*)&As[(wrow + mi * 16 + la) * 32 + lk];
#pragma unroll
      for (int ni = 0; ni < 2; ++ni)
        acc[mi][ni] = __builtin_amdgcn_mfma_f32_16x16x32_bf16(af, bfr[ni], acc[mi][ni], 0, 0, 0);
    }
    __syncthreads();
  }
  const int r0 = (lane >> 4) * 4;
#pragma unroll
  for (int mi = 0; mi < 4; ++mi) {
#pragma unroll
    for (int r = 0; r < 4; ++r) {
      int row = brow + wrow + mi * 16 + r0 + r;
      if (row >= M) continue;
#pragma unroll
      for (int ni = 0; ni < 2; ++ni) {
        int col = bcol + wcol + ni * 16 + la;
        Cb[(size_t)row * N + col] = f2bf(acc[mi][ni][r] + bias[col]);
      }
    }
  }
}

// ================= fused GATv2, 4-edge batched online softmax, wave/dst ================
template <int R>
__device__ __forceinline__ void load_xf(const unsigned short* p, float* xf) {
  if constexpr (R == 4) {
    ushort4 v = *(const ushort4*)p;
    xf[0] = bf2f(v.x); xf[1] = bf2f(v.y); xf[2] = bf2f(v.z); xf[3] = bf2f(v.w);
  } else {
    short8 v = *(const short8*)p;
#pragma unroll
    for (int j = 0; j < 8; ++j) xf[j] = bf2f((unsigned short)v[j]);
  }
}

template <int C, int MODE>
__global__ __launch_bounds__(256) void fused_gat(
    const unsigned short* __restrict__ xl, int ldl,
    const unsigned short* __restrict__ xr, int ldr,
    const float* __restrict__ att,
    const int* __restrict__ psrc, const int* __restrict__ rp,
    const float* __restrict__ bias,
    const unsigned short* __restrict__ sl, int ldsl,
    void* __restrict__ outv, int N) {
  constexpr int D = 4 * C;
  constexpr int R = D / 64;
  int d = blockIdx.x * 4 + (threadIdx.x >> 6);
  int lane = threadIdx.x & 63;
  if (d >= N) return;
  float xrr[R], atr[R];
  {
    float t[R];
    load_xf<R>(&xr[(size_t)d * ldr + lane * R], t);
#pragma unroll
    for (int j = 0; j < R; ++j) { xrr[j] = t[j]; atr[j] = att[lane * R + j]; }
  }
  float m = -3.0e38f, l = 0.f, acc[R] = {};
  int i0 = rp[d], i1 = rp[d + 1];
  for (int i = i0; i < i1; i += 4) {
    int s0 = psrc[i];
    int s1 = (i + 1 < i1) ? psrc[i + 1] : s0;
    int s2 = (i + 2 < i1) ? psrc[i + 2] : s0;
    int s3 = (i + 3 < i1) ? psrc[i + 3] : s0;
    float xf[4][R];
    load_xf<R>(&xl[(size_t)s0 * ldl + lane * R], xf[0]);
    load_xf<R>(&xl[(size_t)s1 * ldl + lane * R], xf[1]);
    load_xf<R>(&xl[(size_t)s2 * ldl + lane * R], xf[2]);
    load_xf<R>(&xl[(size_t)s3 * ldl + lane * R], xf[3]);
    float dt[4];
#pragma unroll
    for (int b = 0; b < 4; ++b) {
      float a = 0.f;
#pragma unroll
      for (int j = 0; j < R; ++j) {
        float v = xf[b][j] + xrr[j];
        v = v >= 0.f ? v : 0.2f * v;
        a = fmaf(v, atr[j], a);
      }
      dt[b] = a;
    }
#pragma unroll
    for (int b = 0; b < 4; ++b) {
      dt[b] += __shfl_xor(dt[b], 1);
      dt[b] += __shfl_xor(dt[b], 2);
      dt[b] += __shfl_xor(dt[b], 4);
      dt[b] += __shfl_xor(dt[b], 8);
    }
    if (i + 1 >= i1) dt[1] = -3.0e38f;
    if (i + 2 >= i1) dt[2] = -3.0e38f;
    if (i + 3 >= i1) dt[3] = -3.0e38f;
    float bm = fmaxf(fmaxf(dt[0], dt[1]), fmaxf(dt[2], dt[3]));
    float mn = fmaxf(m, bm);
    float sc = __expf(m - mn);
    float w0 = __expf(dt[0] - mn), w1 = __expf(dt[1] - mn);
    float w2 = __expf(dt[2] - mn), w3 = __expf(dt[3] - mn);
    l = l * sc + ((w0 + w1) + (w2 + w3));
#pragma unroll
    for (int j = 0; j < R; ++j)
      acc[j] = acc[j] * sc + w0 * xf[0][j] + w1 * xf[1][j] + w2 * xf[2][j] + w3 * xf[3][j];
    m = mn;
  }
  float dinv = 1.f / (l + 1e-16f);
  if (MODE == 0) {
    unsigned short* out = (unsigned short*)outv;
    ushort4 o;
    o.x = f2bf(elu_f(acc[0] * dinv + bias[lane * 4 + 0]));
    o.y = f2bf(elu_f(acc[1] * dinv + bias[lane * 4 + 1]));
    o.z = f2bf(elu_f(acc[2] * dinv + bias[lane * 4 + 2]));
    o.w = f2bf(elu_f(acc[3] * dinv + bias[lane * 4 + 3]));
    *(ushort4*)&out[(size_t)d * 256 + lane * 4] = o;
  } else if (MODE == 1) {
    unsigned short* out = (unsigned short*)outv;
    ushort4 o;
#pragma unroll
    for (int j = 0; j < 4; ++j) {
      int c = lane * 4 + j;
      float v = acc[j] * dinv + bias[c] + bf2f(sl[(size_t)d * ldsl + (c & 63)]);
      ((unsigned short*)&o)[j] = f2bf(elu_f(v));
    }
    *(ushort4*)&out[(size_t)d * 256 + lane * 4] = o;
  } else {
    float* out = (float*)outv;
    float r[R];
#pragma unroll
    for (int j = 0; j < R; ++j) {
      r[j] = acc[j] * dinv;
      r[j] += __shfl_xor(r[j], 16);
      r[j] += __shfl_xor(r[j], 32);
    }
    if (lane < 16) {
#pragma unroll
      for (int j = 0; j < R; ++j) {
        int c = lane * R + j;
        out[(size_t)d * 128 + c] =
            elu_f(0.25f * r[j] + bias[c] + bf2f(sl[(size_t)d * ldsl + c]));
      }
    }
  }
}

extern "C" void kernel_launch(void* const* d_in, const int* in_sizes, int n_in,
                              void* d_out, int out_size, void* d_ws, size_t ws_size,
                              hipStream_t stream) {
  const float* x_sample = (const float*)d_in[0];
  const float* x_gene   = (const float*)d_in[1];
  const int* sg_src = (const int*)d_in[2];
  const int* sg_dst = (const int*)d_in[3];
  const int* gs_src = (const int*)d_in[4];
  const int* gs_dst = (const int*)d_in[5];
  const float* Wl1_sg = (const float*)d_in[6];
  const float* bl1_sg = (const float*)d_in[7];
  const float* Wr1_sg = (const float*)d_in[8];
  const float* br1_sg = (const float*)d_in[9];
  const float* att1_sg = (const float*)d_in[10];
  const float* bias1_sg = (const float*)d_in[11];
  const float* Wl1_gs = (const float*)d_in[12];
  const float* bl1_gs = (const float*)d_in[13];
  const float* Wr1_gs = (const float*)d_in[14];
  const float* br1_gs = (const float*)d_in[15];
  const float* att1_gs = (const float*)d_in[16];
  const float* bias1_gs = (const float*)d_in[17];
  const float* Wl3 = (const float*)d_in[18];
  const float* bl3 = (const float*)d_in[19];
  const float* Wr3 = (const float*)d_in[20];
  const float* br3 = (const float*)d_in[21];
  const float* att3 = (const float*)d_in[22];
  const float* bias3 = (const float*)d_in[23];
  const float* sl1_W = (const float*)d_in[24];
  const float* sl1_b = (const float*)d_in[25];
  const float* sl3_W = (const float*)d_in[26];
  const float* sl3_b = (const float*)d_in[27];

  float* ws = (float*)d_ws;
  size_t off = 0;
  auto alloc = [&](size_t n) { float* p = ws + off; off += n; return p; };
  float* bc1 = alloc(576);
  float* bc2 = alloc(512);
  float* bc4 = alloc(640);
  unsigned short* cat1 = (unsigned short*)alloc((size_t)kNS * 576 / 2);  // xl_sg|xr_gs|sl1o
  unsigned short* cat2 = (unsigned short*)alloc((size_t)kNG * 512 / 2);  // xr_sg|xl_gs
  unsigned short* xl3  = (unsigned short*)alloc((size_t)kNG * 512 / 2);
  unsigned short* cat4 = (unsigned short*)alloc((size_t)kNS * 640 / 2);  // xr3|sl3o
  unsigned short* xs_bf  = (unsigned short*)alloc((size_t)kNS * 256 / 2);
  unsigned short* xg_bf  = (unsigned short*)alloc((size_t)kNG * 256 / 2);
  unsigned short* xg1_bf = (unsigned short*)alloc((size_t)kNG * 256 / 2);
  unsigned short* xs1_bf = (unsigned short*)alloc((size_t)kNS * 256 / 2);
  unsigned short* Wt1 = (unsigned short*)alloc(576 * 256 / 2);
  unsigned short* Wt2 = (unsigned short*)alloc(512 * 256 / 2);
  unsigned short* Wt3 = (unsigned short*)alloc(512 * 256 / 2);
  unsigned short* Wt4 = (unsigned short*)alloc(640 * 256 / 2);
  int* deg_g  = (int*)alloc(kNG);   // contiguous with deg_s (concatenated scan relies on it)
  int* deg_s  = (int*)alloc(kNS);
  int* rp_g   = (int*)alloc(kNG + 1);
  int* rp_s   = (int*)alloc(kNS + 1);
  int* psrc_g = (int*)alloc(kE);
  int* psrc_s = (int*)alloc(kE);
  int* part   = (int*)alloc(128);

  hipMemsetAsync(deg_g, 0, (kNG + kNS) * sizeof(int), stream);

  prep<<<9295, 256, 0, stream>>>(
      x_sample, x_gene, Wl1_sg, Wr1_gs, sl1_W, Wr1_sg, Wl1_gs, Wl3, Wr3, sl3_W,
      bl1_sg, br1_gs, sl1_b, br1_sg, bl1_gs, br3, sl3_b,
      sg_dst, gs_dst, deg_g, deg_s,
      xs_bf, xg_bf, Wt1, Wt2, Wt3, Wt4, bc1, bc2, bc4);

  scan_blocksum<<<kNB, 256, 0, stream>>>(deg_g, part);
  scan_part<<<1, 128, 0, stream>>>(part, kNB);
  scan_write<<<kNB, 256, 0, stream>>>(deg_g, part, rp_g, rp_s);
  build_dual<<<1024, 256, 0, stream>>>(sg_dst, sg_src, rp_g, deg_g, psrc_g,
                                       gs_dst, gs_src, rp_s, deg_s, psrc_s);

  auto gemm = [&](const unsigned short* A, const unsigned short* Bt, const float* bias,
                  unsigned short* Cp, int M, int N) {
    dim3 grid(N / 64, (M + 127) / 128);
    gemm_mfma<<<grid, 256, 0, stream>>>(A, Bt, bias, Cp, M, N);
  };

  // layer-1: 2 fat GEMMs
  gemm(xs_bf, Wt1, bc1, cat1, kNS, 576);   // [xl_sg | xr_gs | sl1o]
  gemm(xg_bf, Wt2, bc2, cat2, kNG, 512);   // [xr_sg | xl_gs]

  // stage 1: sg -> genes (C=64)
  fused_gat<64, 0><<<(kNG + 3) / 4, 256, 0, stream>>>(
      cat1, 576, cat2, 512, att1_sg, psrc_g, rp_g, bias1_sg, nullptr, 0, xg1_bf, kNG);

  // stage 2: gs -> samples (C=64)
  fused_gat<64, 1><<<(kNS + 3) / 4, 256, 0, stream>>>(
      cat2 + 256, 512, cat1 + 256, 576, att1_gs, psrc_s, rp_s, bias1_gs,
      cat1 + 512, 576, xs1_bf, kNS);

  // layer-3: 2 GEMMs
  gemm(xg1_bf, Wt3, bl3, xl3, kNG, 512);
  gemm(xs1_bf, Wt4, bc4, cat4, kNS, 640);  // [xr3 | sl3o]

  // stage 3: gs -> samples (C=128), head-mean
  fused_gat<128, 2><<<(kNS + 3) / 4, 256, 0, stream>>>(
      xl3, 512, cat4, 640, att3, psrc_s, rp_s, bias3, cat4 + 512, 640, d_out, kNS);
}

// Round 7
// 185.703 us; speedup vs baseline: 5.2923x; 1.0444x over previous
//
#include <hip/hip_runtime.h>
#include <hip/hip_bf16.h>
#include <cstdint>

constexpr int kNS = 4096;
constexpr int kNG = 20000;
constexpr int kE  = 131072;
constexpr int kNCAT = kNG + kNS;          // 24096
constexpr int kNB = (kNCAT + 255) / 256;  // 95 scan blocks

typedef __attribute__((ext_vector_type(8))) short short8;
typedef __attribute__((ext_vector_type(4))) float f32x4;

__device__ __forceinline__ float elu_f(float v) { return v > 0.f ? v : expm1f(v); }

__device__ __forceinline__ unsigned short f2bf(float f) {
  union { float f; unsigned u; } v; v.f = f;
  unsigned r = v.u + 0x7FFF + ((v.u >> 16) & 1);
  return (unsigned short)(r >> 16);
}

__device__ __forceinline__ float bf2f(unsigned short u) {
  union { unsigned u; float f; } v; v.u = ((unsigned)u) << 16; return v.f;
}

// ================= prep: conversions/transposes/bias concat + edge histogram ===========
__global__ __launch_bounds__(256) void prep(
    const float* __restrict__ xs, const float* __restrict__ xg,
    const float* __restrict__ Wl1_sg, const float* __restrict__ Wr1_gs,
    const float* __restrict__ sl1_W, const float* __restrict__ Wr1_sg,
    const float* __restrict__ Wl1_gs, const float* __restrict__ Wl3,
    const float* __restrict__ Wr3, const float* __restrict__ sl3_W,
    const float* __restrict__ bl1_sg, const float* __restrict__ br1_gs,
    const float* __restrict__ sl1_b, const float* __restrict__ br1_sg,
    const float* __restrict__ bl1_gs, const float* __restrict__ br3,
    const float* __restrict__ sl3_b,
    const int* __restrict__ sg_dst, const int* __restrict__ gs_dst,
    int* __restrict__ deg_g, int* __restrict__ deg_s,
    unsigned short* __restrict__ xs_bf, unsigned short* __restrict__ xg_bf,
    unsigned short* __restrict__ Wt1, unsigned short* __restrict__ Wt2,
    unsigned short* __restrict__ Wt3, unsigned short* __restrict__ Wt4,
    float* __restrict__ bc1, float* __restrict__ bc2, float* __restrict__ bc4) {
  int bid = blockIdx.x, tid = threadIdx.x;
  if (bid < 1024) {
    int i = (bid * 256 + tid) * 4;
    float4 v = *(const float4*)&xs[i];
    ushort4 o = {f2bf(v.x), f2bf(v.y), f2bf(v.z), f2bf(v.w)};
    *(ushort4*)&xs_bf[i] = o;
    return;
  }
  bid -= 1024;
  if (bid < 5000) {
    int i = (bid * 256 + tid) * 4;
    float4 v = *(const float4*)&xg[i];
    ushort4 o = {f2bf(v.x), f2bf(v.y), f2bf(v.z), f2bf(v.w)};
    *(ushort4*)&xg_bf[i] = o;
    return;
  }
  bid -= 5000;
  auto wseg = [&](const float* W, unsigned short* Wt, int N) {
    int i = bid * 256 + tid;
    int n = i >> 8, k = i & 255;
    Wt[i] = f2bf(W[(size_t)k * N + n]);
  };
  if (bid < 256) { wseg(Wl1_sg, Wt1, 256); return; } bid -= 256;
  if (bid < 256) { wseg(Wr1_gs, Wt1 + 256 * 256, 256); return; } bid -= 256;
  if (bid < 64)  { wseg(sl1_W,  Wt1 + 512 * 256, 64);  return; } bid -= 64;
  if (bid < 256) { wseg(Wr1_sg, Wt2, 256); return; } bid -= 256;
  if (bid < 256) { wseg(Wl1_gs, Wt2 + 256 * 256, 256); return; } bid -= 256;
  if (bid < 512) { wseg(Wl3,    Wt3, 512); return; } bid -= 512;
  if (bid < 512) { wseg(Wr3,    Wt4, 512); return; } bid -= 512;
  if (bid < 128) { wseg(sl3_W,  Wt4 + 512 * 256, 128); return; } bid -= 128;
  if (bid < 7) {
    int j = bid * 256 + tid;
    if (j < 256) bc1[j] = bl1_sg[j];
    else if (j < 512) bc1[j] = br1_gs[j - 256];
    else if (j < 576) bc1[j] = sl1_b[j - 512];
    else if (j < 832) bc2[j - 576] = br1_sg[j - 576];
    else if (j < 1088) bc2[j - 576] = bl1_gs[j - 832];
    else if (j < 1600) bc4[j - 1088] = br3[j - 1088];
    else if (j < 1728) bc4[j - 1088] = sl3_b[j - 1600];
    return;
  }
  bid -= 7;
  int i = bid * 256 + tid;
  if (i < kE) atomicAdd(&deg_g[sg_dst[i]], 1);
  else atomicAdd(&deg_s[gs_dst[i - kE]], 1);
}

// ================= parallel CSR scan =================
__global__ __launch_bounds__(256) void scan_blocksum(const int* __restrict__ deg,
                                                     int* __restrict__ part) {
  int i = blockIdx.x * 256 + threadIdx.x;
  int v = i < kNCAT ? deg[i] : 0;
  v += __shfl_xor(v, 1); v += __shfl_xor(v, 2); v += __shfl_xor(v, 4);
  v += __shfl_xor(v, 8); v += __shfl_xor(v, 16); v += __shfl_xor(v, 32);
  __shared__ int ssum[4];
  if ((threadIdx.x & 63) == 0) ssum[threadIdx.x >> 6] = v;
  __syncthreads();
  if (threadIdx.x == 0) part[blockIdx.x] = ssum[0] + ssum[1] + ssum[2] + ssum[3];
}

__global__ __launch_bounds__(128) void scan_part(int* __restrict__ part, int n) {
  __shared__ int s[128];
  int t = threadIdx.x;
  int v = t < n ? part[t] : 0;
  s[t] = v;
  __syncthreads();
  for (int ofs = 1; ofs < 128; ofs <<= 1) {
    int add = t >= ofs ? s[t - ofs] : 0;
    __syncthreads();
    s[t] += add;
    __syncthreads();
  }
  if (t < n) part[t] = s[t] - v;
}

__global__ __launch_bounds__(256) void scan_write(int* __restrict__ deg,
                                                  const int* __restrict__ part,
                                                  int* __restrict__ rp_g,
                                                  int* __restrict__ rp_s) {
  int b = blockIdx.x, t = threadIdx.x;
  int i = b * 256 + t;
  int v = i < kNCAT ? deg[i] : 0;
  __shared__ int s[256];
  s[t] = v;
  __syncthreads();
  for (int ofs = 1; ofs < 256; ofs <<= 1) {
    int add = t >= ofs ? s[t - ofs] : 0;
    __syncthreads();
    s[t] += add;
    __syncthreads();
  }
  int ex = part[b] + s[t] - v;
  if (i < kNG) { rp_g[i] = ex; deg[i] = 0; }
  else if (i < kNCAT) { rp_s[i - kNG] = ex - kE; deg[i] = 0; }
  if (b == 0 && t == 0) { rp_g[kNG] = kE; rp_s[kNS] = kE; }
}

__global__ void build_dual(const int* __restrict__ sg_dst, const int* __restrict__ sg_src,
                           const int* __restrict__ rp_g, int* __restrict__ cur_g,
                           int* __restrict__ ps_g,
                           const int* __restrict__ gs_dst, const int* __restrict__ gs_src,
                           const int* __restrict__ rp_s, int* __restrict__ cur_s,
                           int* __restrict__ ps_s) {
  int i = blockIdx.x * 256 + threadIdx.x;
  if (i < kE) {
    int d = sg_dst[i];
    ps_g[rp_g[d] + atomicAdd(&cur_g[d], 1)] = sg_src[i];
  } else {
    i -= kE;
    int d = gs_dst[i];
    ps_s[rp_s[d] + atomicAdd(&cur_s[d], 1)] = gs_src[i];
  }
}

// ================= MFMA GEMM body (128x64 tile, BK=32, K=256) =================
__device__ __forceinline__ void gemm_body(
    const unsigned short* __restrict__ A, const unsigned short* __restrict__ Bt,
    const float* __restrict__ bias, unsigned short* __restrict__ Cb,
    int M, int N, int bx, int by) {
  __shared__ alignas(16) unsigned short As[128 * 32];
  __shared__ alignas(16) unsigned short Bs[64 * 32];
  const int tid = threadIdx.x;
  const int wave = tid >> 6, lane = tid & 63;
  const int brow = by * 128, bcol = bx * 64;
  const int wrow = (wave >> 1) * 64, wcol = (wave & 1) * 32;
  const int la = lane & 15, lk = (lane >> 4) * 8;
  f32x4 acc[4][2] = {};
  for (int k0 = 0; k0 < 256; k0 += 32) {
#pragma unroll
    for (int c = 0; c < 2; ++c) {
      int seg = wave * 128 + c * 64 + lane;
      int row = seg >> 2, ks = (seg & 3) * 8;
      int grow = brow + row; if (grow > M - 1) grow = M - 1;
      const unsigned short* g = A + (size_t)grow * 256 + k0 + ks;
      __builtin_amdgcn_global_load_lds(
          (const __attribute__((address_space(1))) unsigned*)g,
          (__attribute__((address_space(3))) unsigned*)&As[(wave * 128 + c * 64) * 8],
          16, 0, 0);
    }
    {
      int seg = wave * 64 + lane;
      int row = seg >> 2, ks = (seg & 3) * 8;
      const unsigned short* g = Bt + (size_t)(bcol + row) * 256 + k0 + ks;
      __builtin_amdgcn_global_load_lds(
          (const __attribute__((address_space(1))) unsigned*)g,
          (__attribute__((address_space(3))) unsigned*)&Bs[(wave * 64) * 8],
          16, 0, 0);
    }
    __syncthreads();
    short8 bfr[2];
#pragma unroll
    for (int ni = 0; ni < 2; ++ni)
      bfr[ni] = *(const short8*)&Bs[(wcol + ni * 16 + la) * 32 + lk];
#pragma unroll
    for (int mi = 0; mi < 4; ++mi) {
      short8 af = *(const short8*)&As[(wrow + mi * 16 + la) * 32 + lk];
#pragma unroll
      for (int ni = 0; ni < 2; ++ni)
        acc[mi][ni] = __builtin_amdgcn_mfma_f32_16x16x32_bf16(af, bfr[ni], acc[mi][ni], 0, 0, 0);
    }
    __syncthreads();
  }
  const int r0 = (lane >> 4) * 4;
#pragma unroll
  for (int mi = 0; mi < 4; ++mi) {
#pragma unroll
    for (int r = 0; r < 4; ++r) {
      int row = brow + wrow + mi * 16 + r0 + r;
      if (row >= M) continue;
#pragma unroll
      for (int ni = 0; ni < 2; ++ni) {
        int col = bcol + wcol + ni * 16 + la;
        Cb[(size_t)row * N + col] = f2bf(acc[mi][ni][r] + bias[col]);
      }
    }
  }
}

// two independent GEMMs in one dispatch
__global__ __launch_bounds__(256) void gemm_dual(
    const unsigned short* __restrict__ A0, const unsigned short* __restrict__ B0,
    const float* __restrict__ b0, unsigned short* __restrict__ C0, int M0, int N0, int nb0,
    const unsigned short* __restrict__ A1, const unsigned short* __restrict__ B1,
    const float* __restrict__ b1, unsigned short* __restrict__ C1, int M1, int N1) {
  int flat = blockIdx.x;
  if (flat < nb0) {
    int nbx = N0 / 64;
    gemm_body(A0, B0, b0, C0, M0, N0, flat % nbx, flat / nbx);
  } else {
    flat -= nb0;
    int nbx = N1 / 64;
    gemm_body(A1, B1, b1, C1, M1, N1, flat % nbx, flat / nbx);
  }
}

// ================= fused GATv2, C=64: half-wave per edge, 8 in flight ================
// lane = 32*sub + cl; lane's channels = cl*8..cl*8+7 (head = cl>>3).
// halves process disjoint edge chunks of the SAME dst; merged via shfl_xor 32.
__device__ __forceinline__ void gat64_body(
    const unsigned short* __restrict__ xl, int ldl,
    const unsigned short* __restrict__ xr, int ldr,
    const float* __restrict__ att,
    const int* __restrict__ psrc, const int* __restrict__ rp,
    const float* __restrict__ bias,
    const unsigned short* __restrict__ sl, int ldsl, bool addSL,
    unsigned short* __restrict__ out, int N, int rbid) {
  int lane = threadIdx.x & 63;
  int sub = lane >> 5, cl = lane & 31;
  int d = rbid * 4 + (threadIdx.x >> 6);
  if (d >= N) return;
  float xrr[8], atr[8];
  {
    short8 xv = *(const short8*)&xr[(size_t)d * ldr + cl * 8];
#pragma unroll
    for (int j = 0; j < 8; ++j) {
      xrr[j] = bf2f((unsigned short)xv[j]);
      atr[j] = att[cl * 8 + j];
    }
  }
  float m = -3.0e38f, l = 0.f, acc[8] = {};
  int i0 = rp[d], i1 = rp[d + 1];
  for (int i = i0 + sub * 4; i < i1; i += 8) {
    int ia = i + 1 < i1 ? i + 1 : i;
    int ib = i + 2 < i1 ? i + 2 : i;
    int ic = i + 3 < i1 ? i + 3 : i;
    int s0 = psrc[i], s1 = psrc[ia], s2 = psrc[ib], s3 = psrc[ic];
    short8 x0 = *(const short8*)&xl[(size_t)s0 * ldl + cl * 8];
    short8 x1 = *(const short8*)&xl[(size_t)s1 * ldl + cl * 8];
    short8 x2 = *(const short8*)&xl[(size_t)s2 * ldl + cl * 8];
    short8 x3 = *(const short8*)&xl[(size_t)s3 * ldl + cl * 8];
    float xf[4][8];
#pragma unroll
    for (int j = 0; j < 8; ++j) {
      xf[0][j] = bf2f((unsigned short)x0[j]);
      xf[1][j] = bf2f((unsigned short)x1[j]);
      xf[2][j] = bf2f((unsigned short)x2[j]);
      xf[3][j] = bf2f((unsigned short)x3[j]);
    }
    float dt[4];
#pragma unroll
    for (int b = 0; b < 4; ++b) {
      float a = 0.f;
#pragma unroll
      for (int j = 0; j < 8; ++j) {
        float v = xf[b][j] + xrr[j];
        v = v >= 0.f ? v : 0.2f * v;
        a = fmaf(v, atr[j], a);
      }
      dt[b] = a;
    }
#pragma unroll
    for (int b = 0; b < 4; ++b) {
      dt[b] += __shfl_xor(dt[b], 1);
      dt[b] += __shfl_xor(dt[b], 2);
      dt[b] += __shfl_xor(dt[b], 4);
    }
    if (i + 1 >= i1) dt[1] = -3.0e38f;
    if (i + 2 >= i1) dt[2] = -3.0e38f;
    if (i + 3 >= i1) dt[3] = -3.0e38f;
    float bm = fmaxf(fmaxf(dt[0], dt[1]), fmaxf(dt[2], dt[3]));
    float mn = fmaxf(m, bm);
    float sc = __expf(m - mn);
    float w0 = __expf(dt[0] - mn), w1 = __expf(dt[1] - mn);
    float w2 = __expf(dt[2] - mn), w3 = __expf(dt[3] - mn);
    l = l * sc + ((w0 + w1) + (w2 + w3));
#pragma unroll
    for (int j = 0; j < 8; ++j)
      acc[j] = acc[j] * sc + w0 * xf[0][j] + w1 * xf[1][j] + w2 * xf[2][j] + w3 * xf[3][j];
    m = mn;
  }
  // merge the two halves (disjoint edge sets, same channels)
  {
    float mo = __shfl_xor(m, 32), lo = __shfl_xor(l, 32);
    float mm = fmaxf(m, mo);
    float se = __expf(m - mm), so = __expf(mo - mm);
    l = l * se + lo * so;
#pragma unroll
    for (int j = 0; j < 8; ++j) {
      float ao = __shfl_xor(acc[j], 32);
      acc[j] = acc[j] * se + ao * so;
    }
    m = mm;
  }
  if (sub == 0) {
    float dinv = 1.f / (l + 1e-16f);
    short8 o;
#pragma unroll
    for (int j = 0; j < 8; ++j) {
      int c = cl * 8 + j;
      float v = acc[j] * dinv + bias[c];
      if (addSL) v += bf2f(sl[(size_t)d * ldsl + (c & 63)]);
      o[j] = (short)f2bf(elu_f(v));
    }
    *(short8*)&out[(size_t)d * 256 + cl * 8] = o;
  }
}

// both C=64 stages in one dispatch
__global__ __launch_bounds__(256) void gat12(
    const unsigned short* __restrict__ xlA, int ldlA,
    const unsigned short* __restrict__ xrA, int ldrA,
    const float* __restrict__ attA, const int* __restrict__ psA,
    const int* __restrict__ rpA, const float* __restrict__ biasA,
    unsigned short* __restrict__ outA, int NA, int nbA,
    const unsigned short* __restrict__ xlB, int ldlB,
    const unsigned short* __restrict__ xrB, int ldrB,
    const float* __restrict__ attB, const int* __restrict__ psB,
    const int* __restrict__ rpB, const float* __restrict__ biasB,
    const unsigned short* __restrict__ slB, int ldslB,
    unsigned short* __restrict__ outB, int NB) {
  int bid = blockIdx.x;
  if (bid < nbA)
    gat64_body(xlA, ldlA, xrA, ldrA, attA, psA, rpA, biasA, nullptr, 0, false, outA, NA, bid);
  else
    gat64_body(xlB, ldlB, xrB, ldrB, attB, psB, rpB, biasB, slB, ldslB, true, outB, NB, bid - nbA);
}

// ================= stage-3 GAT, C=128: 2 waves per dst, LDS merge, head-mean ==========
__global__ __launch_bounds__(256) void gat3(
    const unsigned short* __restrict__ xl,   // [NG,512]
    const unsigned short* __restrict__ xr,   // cat4 [NS,640], cols 0..511
    const float* __restrict__ att,
    const int* __restrict__ psrc, const int* __restrict__ rp,
    const float* __restrict__ bias,
    const unsigned short* __restrict__ sl,   // cat4 cols 512..639
    float* __restrict__ out) {
  __shared__ float sm_acc[2][64][8];
  __shared__ float sm_ml[2][64][2];
  int w = threadIdx.x >> 6, lane = threadIdx.x & 63;
  int p = w >> 1, wp = w & 1;
  int d = blockIdx.x * 2 + p;
  float xrr[8], atr[8];
  {
    short8 xv = *(const short8*)&xr[(size_t)d * 640 + lane * 8];
#pragma unroll
    for (int j = 0; j < 8; ++j) {
      xrr[j] = bf2f((unsigned short)xv[j]);
      atr[j] = att[lane * 8 + j];
    }
  }
  float m = -3.0e38f, l = 0.f, acc[8] = {};
  int i0 = rp[d], i1 = rp[d + 1];
  for (int i = i0 + wp * 4; i < i1; i += 8) {
    int ia = i + 1 < i1 ? i + 1 : i;
    int ib = i + 2 < i1 ? i + 2 : i;
    int ic = i + 3 < i1 ? i + 3 : i;
    int s0 = psrc[i], s1 = psrc[ia], s2 = psrc[ib], s3 = psrc[ic];
    short8 x0 = *(const short8*)&xl[(size_t)s0 * 512 + lane * 8];
    short8 x1 = *(const short8*)&xl[(size_t)s1 * 512 + lane * 8];
    short8 x2 = *(const short8*)&xl[(size_t)s2 * 512 + lane * 8];
    short8 x3 = *(const short8*)&xl[(size_t)s3 * 512 + lane * 8];
    float xf[4][8];
#pragma unroll
    for (int j = 0; j < 8; ++j) {
      xf[0][j] = bf2f((unsigned short)x0[j]);
      xf[1][j] = bf2f((unsigned short)x1[j]);
      xf[2][j] = bf2f((unsigned short)x2[j]);
      xf[3][j] = bf2f((unsigned short)x3[j]);
    }
    float dt[4];
#pragma unroll
    for (int b = 0; b < 4; ++b) {
      float a = 0.f;
#pragma unroll
      for (int j = 0; j < 8; ++j) {
        float v = xf[b][j] + xrr[j];
        v = v >= 0.f ? v : 0.2f * v;
        a = fmaf(v, atr[j], a);
      }
      dt[b] = a;
    }
#pragma unroll
    for (int b = 0; b < 4; ++b) {
      dt[b] += __shfl_xor(dt[b], 1);
      dt[b] += __shfl_xor(dt[b], 2);
      dt[b] += __shfl_xor(dt[b], 4);
      dt[b] += __shfl_xor(dt[b], 8);
    }
    if (i + 1 >= i1) dt[1] = -3.0e38f;
    if (i + 2 >= i1) dt[2] = -3.0e38f;
    if (i + 3 >= i1) dt[3] = -3.0e38f;
    float bm = fmaxf(fmaxf(dt[0], dt[1]), fmaxf(dt[2], dt[3]));
    float mn = fmaxf(m, bm);
    float sc = __expf(m - mn);
    float w0 = __expf(dt[0] - mn), w1 = __expf(dt[1] - mn);
    float w2 = __expf(dt[2] - mn), w3 = __expf(dt[3] - mn);
    l = l * sc + ((w0 + w1) + (w2 + w3));
#pragma unroll
    for (int j = 0; j < 8; ++j)
      acc[j] = acc[j] * sc + w0 * xf[0][j] + w1 * xf[1][j] + w2 * xf[2][j] + w3 * xf[3][j];
    m = mn;
  }
  if (wp == 1) {
#pragma unroll
    for (int j = 0; j < 8; ++j) sm_acc[p][lane][j] = acc[j];
    sm_ml[p][lane][0] = m;
    sm_ml[p][lane][1] = l;
  }
  __syncthreads();
  if (wp == 0) {
    float mo = sm_ml[p][lane][0], lo = sm_ml[p][lane][1];
    float mm = fmaxf(m, mo);
    float se = __expf(m - mm), so = __expf(mo - mm);
    l = l * se + lo * so;
#pragma unroll
    for (int j = 0; j < 8; ++j) acc[j] = acc[j] * se + sm_acc[p][lane][j] * so;
    float dinv = 1.f / (l + 1e-16f);
    float r[8];
#pragma unroll
    for (int j = 0; j < 8; ++j) {
      r[j] = acc[j] * dinv;
      r[j] += __shfl_xor(r[j], 16);
      r[j] += __shfl_xor(r[j], 32);
    }
    if (lane < 16) {
#pragma unroll
      for (int j = 0; j < 8; ++j) {
        int c = lane * 8 + j;
        out[(size_t)d * 128 + c] =
            elu_f(0.25f * r[j] + bias[c] + bf2f(sl[(size_t)d * 640 + c]));
      }
    }
  }
}

extern "C" void kernel_launch(void* const* d_in, const int* in_sizes, int n_in,
                              void* d_out, int out_size, void* d_ws, size_t ws_size,
                              hipStream_t stream) {
  const float* x_sample = (const float*)d_in[0];
  const float* x_gene   = (const float*)d_in[1];
  const int* sg_src = (const int*)d_in[2];
  const int* sg_dst = (const int*)d_in[3];
  const int* gs_src = (const int*)d_in[4];
  const int* gs_dst = (const int*)d_in[5];
  const float* Wl1_sg = (const float*)d_in[6];
  const float* bl1_sg = (const float*)d_in[7];
  const float* Wr1_sg = (const float*)d_in[8];
  const float* br1_sg = (const float*)d_in[9];
  const float* att1_sg = (const float*)d_in[10];
  const float* bias1_sg = (const float*)d_in[11];
  const float* Wl1_gs = (const float*)d_in[12];
  const float* bl1_gs = (const float*)d_in[13];
  const float* Wr1_gs = (const float*)d_in[14];
  const float* br1_gs = (const float*)d_in[15];
  const float* att1_gs = (const float*)d_in[16];
  const float* bias1_gs = (const float*)d_in[17];
  const float* Wl3 = (const float*)d_in[18];
  const float* bl3 = (const float*)d_in[19];
  const float* Wr3 = (const float*)d_in[20];
  const float* br3 = (const float*)d_in[21];
  const float* att3 = (const float*)d_in[22];
  const float* bias3 = (const float*)d_in[23];
  const float* sl1_W = (const float*)d_in[24];
  const float* sl1_b = (const float*)d_in[25];
  const float* sl3_W = (const float*)d_in[26];
  const float* sl3_b = (const float*)d_in[27];

  float* ws = (float*)d_ws;
  size_t off = 0;
  auto alloc = [&](size_t n) { float* p = ws + off; off += n; return p; };
  float* bc1 = alloc(576);
  float* bc2 = alloc(512);
  float* bc4 = alloc(640);
  unsigned short* cat1 = (unsigned short*)alloc((size_t)kNS * 576 / 2);  // xl_sg|xr_gs|sl1o
  unsigned short* cat2 = (unsigned short*)alloc((size_t)kNG * 512 / 2);  // xr_sg|xl_gs
  unsigned short* xl3  = (unsigned short*)alloc((size_t)kNG * 512 / 2);
  unsigned short* cat4 = (unsigned short*)alloc((size_t)kNS * 640 / 2);  // xr3|sl3o
  unsigned short* xs_bf  = (unsigned short*)alloc((size_t)kNS * 256 / 2);
  unsigned short* xg_bf  = (unsigned short*)alloc((size_t)kNG * 256 / 2);
  unsigned short* xg1_bf = (unsigned short*)alloc((size_t)kNG * 256 / 2);
  unsigned short* xs1_bf = (unsigned short*)alloc((size_t)kNS * 256 / 2);
  unsigned short* Wt1 = (unsigned short*)alloc(576 * 256 / 2);
  unsigned short* Wt2 = (unsigned short*)alloc(512 * 256 / 2);
  unsigned short* Wt3 = (unsigned short*)alloc(512 * 256 / 2);
  unsigned short* Wt4 = (unsigned short*)alloc(640 * 256 / 2);
  int* deg_g  = (int*)alloc(kNG);
  int* deg_s  = (int*)alloc(kNS);
  int* rp_g   = (int*)alloc(kNG + 1);
  int* rp_s   = (int*)alloc(kNS + 1);
  int* psrc_g = (int*)alloc(kE);
  int* psrc_s = (int*)alloc(kE);
  int* part   = (int*)alloc(128);

  hipMemsetAsync(deg_g, 0, (kNG + kNS) * sizeof(int), stream);

  prep<<<9295, 256, 0, stream>>>(
      x_sample, x_gene, Wl1_sg, Wr1_gs, sl1_W, Wr1_sg, Wl1_gs, Wl3, Wr3, sl3_W,
      bl1_sg, br1_gs, sl1_b, br1_sg, bl1_gs, br3, sl3_b,
      sg_dst, gs_dst, deg_g, deg_s,
      xs_bf, xg_bf, Wt1, Wt2, Wt3, Wt4, bc1, bc2, bc4);

  scan_blocksum<<<kNB, 256, 0, stream>>>(deg_g, part);
  scan_part<<<1, 128, 0, stream>>>(part, kNB);
  scan_write<<<kNB, 256, 0, stream>>>(deg_g, part, rp_g, rp_s);
  build_dual<<<1024, 256, 0, stream>>>(sg_dst, sg_src, rp_g, deg_g, psrc_g,
                                       gs_dst, gs_src, rp_s, deg_s, psrc_s);

  // layer-1: both GEMMs fused (288 + 1256 blocks)
  gemm_dual<<<288 + 1256, 256, 0, stream>>>(
      xs_bf, Wt1, bc1, cat1, kNS, 576, 288,
      xg_bf, Wt2, bc2, cat2, kNG, 512);

  // stages 1+2 fused (5000 + 1024 blocks)
  gat12<<<5000 + 1024, 256, 0, stream>>>(
      cat1, 576, cat2, 512, att1_sg, psrc_g, rp_g, bias1_sg, xg1_bf, kNG, 5000,
      cat2 + 256, 512, cat1 + 256, 576, att1_gs, psrc_s, rp_s, bias1_gs,
      cat1 + 512, 576, xs1_bf, kNS);

  // layer-3: both GEMMs fused (1256 + 320 blocks)
  gemm_dual<<<1256 + 320, 256, 0, stream>>>(
      xg1_bf, Wt3, bl3, xl3, kNG, 512, 1256,
      xs1_bf, Wt4, bc4, cat4, kNS, 640);

  // stage 3: 2 waves per dst (2048 blocks)
  gat3<<<kNS / 2, 256, 0, stream>>>(
      xl3, cat4, att3, psrc_s, rp_s, bias3, cat4 + 512, (float*)d_out);
}

// Round 8
// 158.279 us; speedup vs baseline: 6.2093x; 1.1733x over previous
//
#include <hip/hip_runtime.h>
#include <hip/hip_bf16.h>
#include <cstdint>

constexpr int kNS = 4096;
constexpr int kNG = 20000;
constexpr int kE  = 131072;
constexpr int kNCAT = kNG + kNS;          // 24096
constexpr int kNB = (kNCAT + 255) / 256;  // 95 scan blocks
constexpr float kL2E = 1.4426950408889634f;

typedef __attribute__((ext_vector_type(8))) short short8;
typedef __attribute__((ext_vector_type(4))) float f32x4;
typedef __attribute__((ext_vector_type(2))) float f32x2;

__device__ __forceinline__ float elu_f(float v) { return v > 0.f ? v : expm1f(v); }

__device__ __forceinline__ unsigned short f2bf(float f) {
  union { float f; unsigned u; } v; v.f = f;
  unsigned r = v.u + 0x7FFF + ((v.u >> 16) & 1);
  return (unsigned short)(r >> 16);
}

__device__ __forceinline__ float bf2f(unsigned short u) {
  union { unsigned u; float f; } v; v.u = ((unsigned)u) << 16; return v.f;
}

// unpack 2 bf16 (packed in a dword) -> f32x2 {lo, hi}
__device__ __forceinline__ f32x2 bfp2(unsigned u) {
  union { unsigned u; float f; } lo, hi;
  lo.u = u << 16; hi.u = u & 0xffff0000u;
  return (f32x2){lo.f, hi.f};
}

// ================= prep: conversions/transposes/bias concat + edge histogram ===========
__global__ __launch_bounds__(256) void prep(
    const float* __restrict__ xs, const float* __restrict__ xg,
    const float* __restrict__ Wl1_sg, const float* __restrict__ Wr1_gs,
    const float* __restrict__ sl1_W, const float* __restrict__ Wr1_sg,
    const float* __restrict__ Wl1_gs, const float* __restrict__ Wl3,
    const float* __restrict__ Wr3, const float* __restrict__ sl3_W,
    const float* __restrict__ bl1_sg, const float* __restrict__ br1_gs,
    const float* __restrict__ sl1_b, const float* __restrict__ br1_sg,
    const float* __restrict__ bl1_gs, const float* __restrict__ br3,
    const float* __restrict__ sl3_b,
    const int* __restrict__ sg_dst, const int* __restrict__ gs_dst,
    int* __restrict__ deg_g, int* __restrict__ deg_s,
    unsigned short* __restrict__ xs_bf, unsigned short* __restrict__ xg_bf,
    unsigned short* __restrict__ Wt1, unsigned short* __restrict__ Wt2,
    unsigned short* __restrict__ Wt3, unsigned short* __restrict__ Wt4,
    float* __restrict__ bc1, float* __restrict__ bc2, float* __restrict__ bc4) {
  int bid = blockIdx.x, tid = threadIdx.x;
  if (bid < 1024) {
    int i = (bid * 256 + tid) * 4;
    float4 v = *(const float4*)&xs[i];
    ushort4 o = {f2bf(v.x), f2bf(v.y), f2bf(v.z), f2bf(v.w)};
    *(ushort4*)&xs_bf[i] = o;
    return;
  }
  bid -= 1024;
  if (bid < 5000) {
    int i = (bid * 256 + tid) * 4;
    float4 v = *(const float4*)&xg[i];
    ushort4 o = {f2bf(v.x), f2bf(v.y), f2bf(v.z), f2bf(v.w)};
    *(ushort4*)&xg_bf[i] = o;
    return;
  }
  bid -= 5000;
  auto wseg = [&](const float* W, unsigned short* Wt, int N) {
    int i = bid * 256 + tid;
    int n = i >> 8, k = i & 255;
    Wt[i] = f2bf(W[(size_t)k * N + n]);
  };
  if (bid < 256) { wseg(Wl1_sg, Wt1, 256); return; } bid -= 256;
  if (bid < 256) { wseg(Wr1_gs, Wt1 + 256 * 256, 256); return; } bid -= 256;
  if (bid < 64)  { wseg(sl1_W,  Wt1 + 512 * 256, 64);  return; } bid -= 64;
  if (bid < 256) { wseg(Wr1_sg, Wt2, 256); return; } bid -= 256;
  if (bid < 256) { wseg(Wl1_gs, Wt2 + 256 * 256, 256); return; } bid -= 256;
  if (bid < 512) { wseg(Wl3,    Wt3, 512); return; } bid -= 512;
  if (bid < 512) { wseg(Wr3,    Wt4, 512); return; } bid -= 512;
  if (bid < 128) { wseg(sl3_W,  Wt4 + 512 * 256, 128); return; } bid -= 128;
  if (bid < 7) {
    int j = bid * 256 + tid;
    if (j < 256) bc1[j] = bl1_sg[j];
    else if (j < 512) bc1[j] = br1_gs[j - 256];
    else if (j < 576) bc1[j] = sl1_b[j - 512];
    else if (j < 832) bc2[j - 576] = br1_sg[j - 576];
    else if (j < 1088) bc2[j - 576] = bl1_gs[j - 832];
    else if (j < 1600) bc4[j - 1088] = br3[j - 1088];
    else if (j < 1728) bc4[j - 1088] = sl3_b[j - 1600];
    return;
  }
  bid -= 7;
  int i = bid * 256 + tid;
  if (i < kE) atomicAdd(&deg_g[sg_dst[i]], 1);
  else atomicAdd(&deg_s[gs_dst[i - kE]], 1);
}

// ================= single-dispatch scan with decoupled lookback =================
// 95 blocks, all co-resident. pflag pre-zeroed by host memset. Publisher is
// thread 255 (never spins: b <= 94 < 255) -> deadlock-free.
__global__ __launch_bounds__(256) void scan_fused(
    int* __restrict__ deg, int* __restrict__ rp_g, int* __restrict__ rp_s,
    int* __restrict__ pval, int* __restrict__ pflag) {
  int b = blockIdx.x, t = threadIdx.x;
  int i = b * 256 + t;
  int v = i < kNCAT ? deg[i] : 0;
  __shared__ int s[256];
  s[t] = v;
  __syncthreads();
  for (int ofs = 1; ofs < 256; ofs <<= 1) {
    int add = t >= ofs ? s[t - ofs] : 0;
    __syncthreads();
    s[t] += add;
    __syncthreads();
  }
  if (t == 255) {
    atomicExch(&pval[b], s[255]);   // device-scope store of block total
    __threadfence();
    atomicExch(&pflag[b], 1);       // release
  }
  int pre = 0;
  if (t < b) {
    while (atomicAdd(&pflag[t], 0) == 0) {}
    pre = atomicAdd(&pval[t], 0);
  }
  pre += __shfl_xor(pre, 1);  pre += __shfl_xor(pre, 2);
  pre += __shfl_xor(pre, 4);  pre += __shfl_xor(pre, 8);
  pre += __shfl_xor(pre, 16); pre += __shfl_xor(pre, 32);
  __shared__ int ws4[4];
  if ((t & 63) == 0) ws4[t >> 6] = pre;
  __syncthreads();
  int prefix = ws4[0] + ws4[1] + ws4[2] + ws4[3];
  int ex = prefix + s[t] - v;   // exclusive scan value
  if (i < kNG) { rp_g[i] = ex; deg[i] = 0; }
  else if (i < kNCAT) { rp_s[i - kNG] = ex - kE; deg[i] = 0; }
  if (b == 0 && t == 0) { rp_g[kNG] = kE; rp_s[kNS] = kE; }
}

// ================= MFMA GEMM body (128x64 tile, BK=32, K=256) =================
__device__ __forceinline__ void gemm_body(
    const unsigned short* __restrict__ A, const unsigned short* __restrict__ Bt,
    const float* __restrict__ bias, unsigned short* __restrict__ Cb,
    int M, int N, int bx, int by) {
  __shared__ alignas(16) unsigned short As[128 * 32];
  __shared__ alignas(16) unsigned short Bs[64 * 32];
  const int tid = threadIdx.x;
  const int wave = tid >> 6, lane = tid & 63;
  const int brow = by * 128, bcol = bx * 64;
  const int wrow = (wave >> 1) * 64, wcol = (wave & 1) * 32;
  const int la = lane & 15, lk = (lane >> 4) * 8;
  f32x4 acc[4][2] = {};
  for (int k0 = 0; k0 < 256; k0 += 32) {
#pragma unroll
    for (int c = 0; c < 2; ++c) {
      int seg = wave * 128 + c * 64 + lane;
      int row = seg >> 2, ks = (seg & 3) * 8;
      int grow = brow + row; if (grow > M - 1) grow = M - 1;
      const unsigned short* g = A + (size_t)grow * 256 + k0 + ks;
      __builtin_amdgcn_global_load_lds(
          (const __attribute__((address_space(1))) unsigned*)g,
          (__attribute__((address_space(3))) unsigned*)&As[(wave * 128 + c * 64) * 8],
          16, 0, 0);
    }
    {
      int seg = wave * 64 + lane;
      int row = seg >> 2, ks = (seg & 3) * 8;
      const unsigned short* g = Bt + (size_t)(bcol + row) * 256 + k0 + ks;
      __builtin_amdgcn_global_load_lds(
          (const __attribute__((address_space(1))) unsigned*)g,
          (__attribute__((address_space(3))) unsigned*)&Bs[(wave * 64) * 8],
          16, 0, 0);
    }
    __syncthreads();
    short8 bfr[2];
#pragma unroll
    for (int ni = 0; ni < 2; ++ni)
      bfr[ni] = *(const short8*)&Bs[(wcol + ni * 16 + la) * 32 + lk];
#pragma unroll
    for (int mi = 0; mi < 4; ++mi) {
      short8 af = *(const short8*)&As[(wrow + mi * 16 + la) * 32 + lk];
#pragma unroll
      for (int ni = 0; ni < 2; ++ni)
        acc[mi][ni] = __builtin_amdgcn_mfma_f32_16x16x32_bf16(af, bfr[ni], acc[mi][ni], 0, 0, 0);
    }
    __syncthreads();
  }
  const int r0 = (lane >> 4) * 4;
#pragma unroll
  for (int mi = 0; mi < 4; ++mi) {
#pragma unroll
    for (int r = 0; r < 4; ++r) {
      int row = brow + wrow + mi * 16 + r0 + r;
      if (row >= M) continue;
#pragma unroll
      for (int ni = 0; ni < 2; ++ni) {
        int col = bcol + wcol + ni * 16 + la;
        Cb[(size_t)row * N + col] = f2bf(acc[mi][ni][r] + bias[col]);
      }
    }
  }
}

// two GEMMs + (optionally) CSR perm-build in one dispatch
__global__ __launch_bounds__(256) void gemm_build(
    const unsigned short* __restrict__ A0, const unsigned short* __restrict__ B0,
    const float* __restrict__ b0, unsigned short* __restrict__ C0, int M0, int N0, int nb0,
    const unsigned short* __restrict__ A1, const unsigned short* __restrict__ B1,
    const float* __restrict__ b1, unsigned short* __restrict__ C1, int M1, int N1, int nb1,
    const int* __restrict__ sgd, const int* __restrict__ sgs,
    const int* __restrict__ rpg, int* __restrict__ curg, int* __restrict__ psg,
    const int* __restrict__ gsd, const int* __restrict__ gss,
    const int* __restrict__ rps, int* __restrict__ curs, int* __restrict__ pss) {
  int flat = blockIdx.x;
  if (flat < nb0) {
    int nbx = N0 / 64;
    gemm_body(A0, B0, b0, C0, M0, N0, flat % nbx, flat / nbx);
    return;
  }
  flat -= nb0;
  if (flat < nb1) {
    int nbx = N1 / 64;
    gemm_body(A1, B1, b1, C1, M1, N1, flat % nbx, flat / nbx);
    return;
  }
  flat -= nb1;
  int i = flat * 256 + threadIdx.x;
  if (i < kE) {
    int d = sgd[i];
    psg[rpg[d] + atomicAdd(&curg[d], 1)] = sgs[i];
  } else {
    i -= kE;
    int d = gsd[i];
    pss[rps[d] + atomicAdd(&curs[d], 1)] = gss[i];
  }
}

// ================= fused GATv2, C=64, no-max softmax, pk f32 math ================
// lane = 32*half-part + cl; lane's channels = cl*8..cl*8+7 (head = cl>>3, 8-lane logit reduce).
// SPLIT: two halves share one dst (disjoint edge chunks, add-merge).
// !SPLIT: each half owns its own dst (stage 1, low degree).
template <bool SPLIT, bool ADDSL>
__device__ __forceinline__ void gat64_body(
    const unsigned short* __restrict__ xl, int ldl,
    const unsigned short* __restrict__ xr, int ldr,
    const float* __restrict__ att,
    const int* __restrict__ psrc, const int* __restrict__ rp,
    const float* __restrict__ bias,
    const unsigned short* __restrict__ sl, int ldsl,
    unsigned short* __restrict__ out, int N, int rbid) {
  int tid = threadIdx.x;
  int cl = tid & 31;
  int d, sub;
  if (SPLIT) { d = rbid * 4 + (tid >> 6); sub = (tid >> 5) & 1; }
  else       { d = rbid * 8 + (tid >> 5); sub = 0; }
  if (d >= N) return;
  f32x2 xr2[4], at2[4];
  {
    const uint4 xu = *(const uint4*)&xr[(size_t)d * ldr + cl * 8];
    xr2[0] = bfp2(xu.x); xr2[1] = bfp2(xu.y); xr2[2] = bfp2(xu.z); xr2[3] = bfp2(xu.w);
    float4 a0 = *(const float4*)&att[cl * 8];
    float4 a1 = *(const float4*)&att[cl * 8 + 4];
    at2[0] = (f32x2){a0.x, a0.y} * kL2E; at2[1] = (f32x2){a0.z, a0.w} * kL2E;
    at2[2] = (f32x2){a1.x, a1.y} * kL2E; at2[3] = (f32x2){a1.z, a1.w} * kL2E;
  }
  float l = 0.f;
  f32x2 acc2[4] = {};
  int i0 = rp[d], i1 = rp[d + 1];
  for (int i = SPLIT ? i0 + sub * 4 : i0; i < i1; i += SPLIT ? 8 : 4) {
    int ia = i + 1 < i1 ? i + 1 : i;
    int ib = i + 2 < i1 ? i + 2 : i;
    int ic = i + 3 < i1 ? i + 3 : i;
    int s0 = psrc[i], s1 = psrc[ia], s2 = psrc[ib], s3 = psrc[ic];
    uint4 xu0 = *(const uint4*)&xl[(size_t)s0 * ldl + cl * 8];
    uint4 xu1 = *(const uint4*)&xl[(size_t)s1 * ldl + cl * 8];
    uint4 xu2 = *(const uint4*)&xl[(size_t)s2 * ldl + cl * 8];
    uint4 xu3 = *(const uint4*)&xl[(size_t)s3 * ldl + cl * 8];
    f32x2 xf[4][4];
    xf[0][0] = bfp2(xu0.x); xf[0][1] = bfp2(xu0.y); xf[0][2] = bfp2(xu0.z); xf[0][3] = bfp2(xu0.w);
    xf[1][0] = bfp2(xu1.x); xf[1][1] = bfp2(xu1.y); xf[1][2] = bfp2(xu1.z); xf[1][3] = bfp2(xu1.w);
    xf[2][0] = bfp2(xu2.x); xf[2][1] = bfp2(xu2.y); xf[2][2] = bfp2(xu2.z); xf[2][3] = bfp2(xu2.w);
    xf[3][0] = bfp2(xu3.x); xf[3][1] = bfp2(xu3.y); xf[3][2] = bfp2(xu3.z); xf[3][3] = bfp2(xu3.w);
    float dt[4];
#pragma unroll
    for (int b = 0; b < 4; ++b) {
      f32x2 d2 = {0.f, 0.f};
#pragma unroll
      for (int p = 0; p < 4; ++p) {
        f32x2 v = xf[b][p] + xr2[p];
        f32x2 lk = __builtin_elementwise_max(v, v * 0.2f);
        d2 = __builtin_elementwise_fma(lk, at2[p], d2);
      }
      float dd = d2.x + d2.y;
      dd += __shfl_xor(dd, 1);
      dd += __shfl_xor(dd, 2);
      dd += __shfl_xor(dd, 4);   // 8-lane head reduce
      dt[b] = dd;
    }
    float w0 = exp2f(dt[0]);
    float w1 = (i + 1 < i1) ? exp2f(dt[1]) : 0.f;
    float w2 = (i + 2 < i1) ? exp2f(dt[2]) : 0.f;
    float w3 = (i + 3 < i1) ? exp2f(dt[3]) : 0.f;
    l += (w0 + w1) + (w2 + w3);
#pragma unroll
    for (int p = 0; p < 4; ++p) {
      acc2[p] = __builtin_elementwise_fma(xf[0][p], (f32x2){w0, w0}, acc2[p]);
      acc2[p] = __builtin_elementwise_fma(xf[1][p], (f32x2){w1, w1}, acc2[p]);
      acc2[p] = __builtin_elementwise_fma(xf[2][p], (f32x2){w2, w2}, acc2[p]);
      acc2[p] = __builtin_elementwise_fma(xf[3][p], (f32x2){w3, w3}, acc2[p]);
    }
  }
  if (SPLIT) {  // add-merge the two halves (no-max softmax -> plain sums)
    l += __shfl_xor(l, 32);
#pragma unroll
    for (int p = 0; p < 4; ++p) {
      acc2[p].x += __shfl_xor(acc2[p].x, 32);
      acc2[p].y += __shfl_xor(acc2[p].y, 32);
    }
    if (sub != 0) return;
  }
  float dinv = 1.f / (l + 1e-16f);
  short8 o;
#pragma unroll
  for (int p = 0; p < 4; ++p) {
    int c = cl * 8 + p * 2;
    float v0 = acc2[p].x * dinv + bias[c];
    float v1 = acc2[p].y * dinv + bias[c + 1];
    if (ADDSL) {
      v0 += bf2f(sl[(size_t)d * ldsl + (c & 63)]);
      v1 += bf2f(sl[(size_t)d * ldsl + ((c + 1) & 63)]);
    }
    o[p * 2]     = (short)f2bf(elu_f(v0));
    o[p * 2 + 1] = (short)f2bf(elu_f(v1));
  }
  *(short8*)&out[(size_t)d * 256 + cl * 8] = o;
}

// stage1 (dst per half-wave) + stage2 (split, +SL) in one dispatch
__global__ __launch_bounds__(256) void gat12(
    const unsigned short* __restrict__ xlA, int ldlA,
    const unsigned short* __restrict__ xrA, int ldrA,
    const float* __restrict__ attA, const int* __restrict__ psA,
    const int* __restrict__ rpA, const float* __restrict__ biasA,
    unsigned short* __restrict__ outA, int NA, int nbA,
    const unsigned short* __restrict__ xlB, int ldlB,
    const unsigned short* __restrict__ xrB, int ldrB,
    const float* __restrict__ attB, const int* __restrict__ psB,
    const int* __restrict__ rpB, const float* __restrict__ biasB,
    const unsigned short* __restrict__ slB, int ldslB,
    unsigned short* __restrict__ outB, int NB) {
  int bid = blockIdx.x;
  if (bid < nbA)
    gat64_body<false, false>(xlA, ldlA, xrA, ldrA, attA, psA, rpA, biasA,
                             nullptr, 0, outA, NA, bid);
  else
    gat64_body<true, true>(xlB, ldlB, xrB, ldrB, attB, psB, rpB, biasB,
                           slB, ldslB, outB, NB, bid - nbA);
}

// ================= stage-3 GAT, C=128: 2 waves/dst, LDS add-merge, head-mean ==========
__global__ __launch_bounds__(256) void gat3(
    const unsigned short* __restrict__ xl,   // [NG,512]
    const unsigned short* __restrict__ xr,   // cat4 [NS,640], cols 0..511
    const float* __restrict__ att,
    const int* __restrict__ psrc, const int* __restrict__ rp,
    const float* __restrict__ bias,
    const unsigned short* __restrict__ sl,   // cat4 cols 512..639
    float* __restrict__ out) {
  __shared__ float sm_acc[2][64][8];
  __shared__ float sm_l[2][64];
  int w = threadIdx.x >> 6, lane = threadIdx.x & 63;
  int p = w >> 1, wp = w & 1;
  int d = blockIdx.x * 2 + p;
  f32x2 xr2[4], at2[4];
  {
    const uint4 xu = *(const uint4*)&xr[(size_t)d * 640 + lane * 8];
    xr2[0] = bfp2(xu.x); xr2[1] = bfp2(xu.y); xr2[2] = bfp2(xu.z); xr2[3] = bfp2(xu.w);
    float4 a0 = *(const float4*)&att[lane * 8];
    float4 a1 = *(const float4*)&att[lane * 8 + 4];
    at2[0] = (f32x2){a0.x, a0.y} * kL2E; at2[1] = (f32x2){a0.z, a0.w} * kL2E;
    at2[2] = (f32x2){a1.x, a1.y} * kL2E; at2[3] = (f32x2){a1.z, a1.w} * kL2E;
  }
  float l = 0.f;
  f32x2 acc2[4] = {};
  int i0 = rp[d], i1 = rp[d + 1];
  for (int i = i0 + wp * 4; i < i1; i += 8) {
    int ia = i + 1 < i1 ? i + 1 : i;
    int ib = i + 2 < i1 ? i + 2 : i;
    int ic = i + 3 < i1 ? i + 3 : i;
    int s0 = psrc[i], s1 = psrc[ia], s2 = psrc[ib], s3 = psrc[ic];
    uint4 xu0 = *(const uint4*)&xl[(size_t)s0 * 512 + lane * 8];
    uint4 xu1 = *(const uint4*)&xl[(size_t)s1 * 512 + lane * 8];
    uint4 xu2 = *(const uint4*)&xl[(size_t)s2 * 512 + lane * 8];
    uint4 xu3 = *(const uint4*)&xl[(size_t)s3 * 512 + lane * 8];
    f32x2 xf[4][4];
    xf[0][0] = bfp2(xu0.x); xf[0][1] = bfp2(xu0.y); xf[0][2] = bfp2(xu0.z); xf[0][3] = bfp2(xu0.w);
    xf[1][0] = bfp2(xu1.x); xf[1][1] = bfp2(xu1.y); xf[1][2] = bfp2(xu1.z); xf[1][3] = bfp2(xu1.w);
    xf[2][0] = bfp2(xu2.x); xf[2][1] = bfp2(xu2.y); xf[2][2] = bfp2(xu2.z); xf[2][3] = bfp2(xu2.w);
    xf[3][0] = bfp2(xu3.x); xf[3][1] = bfp2(xu3.y); xf[3][2] = bfp2(xu3.z); xf[3][3] = bfp2(xu3.w);
    float dt[4];
#pragma unroll
    for (int b = 0; b < 4; ++b) {
      f32x2 d2 = {0.f, 0.f};
#pragma unroll
      for (int q = 0; q < 4; ++q) {
        f32x2 v = xf[b][q] + xr2[q];
        f32x2 lk = __builtin_elementwise_max(v, v * 0.2f);
        d2 = __builtin_elementwise_fma(lk, at2[q], d2);
      }
      float dd = d2.x + d2.y;
      dd += __shfl_xor(dd, 1);
      dd += __shfl_xor(dd, 2);
      dd += __shfl_xor(dd, 4);
      dd += __shfl_xor(dd, 8);   // 16-lane head reduce (C=128)
      dt[b] = dd;
    }
    float w0 = exp2f(dt[0]);
    float w1 = (i + 1 < i1) ? exp2f(dt[1]) : 0.f;
    float w2 = (i + 2 < i1) ? exp2f(dt[2]) : 0.f;
    float w3 = (i + 3 < i1) ? exp2f(dt[3]) : 0.f;
    l += (w0 + w1) + (w2 + w3);
#pragma unroll
    for (int q = 0; q < 4; ++q) {
      acc2[q] = __builtin_elementwise_fma(xf[0][q], (f32x2){w0, w0}, acc2[q]);
      acc2[q] = __builtin_elementwise_fma(xf[1][q], (f32x2){w1, w1}, acc2[q]);
      acc2[q] = __builtin_elementwise_fma(xf[2][q], (f32x2){w2, w2}, acc2[q]);
      acc2[q] = __builtin_elementwise_fma(xf[3][q], (f32x2){w3, w3}, acc2[q]);
    }
  }
  if (wp == 1) {
#pragma unroll
    for (int q = 0; q < 4; ++q) {
      sm_acc[p][lane][q * 2]     = acc2[q].x;
      sm_acc[p][lane][q * 2 + 1] = acc2[q].y;
    }
    sm_l[p][lane] = l;
  }
  __syncthreads();
  if (wp == 0) {
    l += sm_l[p][lane];
    float dinv = 1.f / (l + 1e-16f);
    float r[8];
#pragma unroll
    for (int q = 0; q < 4; ++q) {
      r[q * 2]     = (acc2[q].x + sm_acc[p][lane][q * 2]) * dinv;
      r[q * 2 + 1] = (acc2[q].y + sm_acc[p][lane][q * 2 + 1]) * dinv;
    }
#pragma unroll
    for (int j = 0; j < 8; ++j) {
      r[j] += __shfl_xor(r[j], 16);
      r[j] += __shfl_xor(r[j], 32);
    }
    if (lane < 16) {
#pragma unroll
      for (int j = 0; j < 8; ++j) {
        int c = lane * 8 + j;
        out[(size_t)d * 128 + c] =
            elu_f(0.25f * r[j] + bias[c] + bf2f(sl[(size_t)d * 640 + c]));
      }
    }
  }
}

extern "C" void kernel_launch(void* const* d_in, const int* in_sizes, int n_in,
                              void* d_out, int out_size, void* d_ws, size_t ws_size,
                              hipStream_t stream) {
  const float* x_sample = (const float*)d_in[0];
  const float* x_gene   = (const float*)d_in[1];
  const int* sg_src = (const int*)d_in[2];
  const int* sg_dst = (const int*)d_in[3];
  const int* gs_src = (const int*)d_in[4];
  const int* gs_dst = (const int*)d_in[5];
  const float* Wl1_sg = (const float*)d_in[6];
  const float* bl1_sg = (const float*)d_in[7];
  const float* Wr1_sg = (const float*)d_in[8];
  const float* br1_sg = (const float*)d_in[9];
  const float* att1_sg = (const float*)d_in[10];
  const float* bias1_sg = (const float*)d_in[11];
  const float* Wl1_gs = (const float*)d_in[12];
  const float* bl1_gs = (const float*)d_in[13];
  const float* Wr1_gs = (const float*)d_in[14];
  const float* br1_gs = (const float*)d_in[15];
  const float* att1_gs = (const float*)d_in[16];
  const float* bias1_gs = (const float*)d_in[17];
  const float* Wl3 = (const float*)d_in[18];
  const float* bl3 = (const float*)d_in[19];
  const float* Wr3 = (const float*)d_in[20];
  const float* br3 = (const float*)d_in[21];
  const float* att3 = (const float*)d_in[22];
  const float* bias3 = (const float*)d_in[23];
  const float* sl1_W = (const float*)d_in[24];
  const float* sl1_b = (const float*)d_in[25];
  const float* sl3_W = (const float*)d_in[26];
  const float* sl3_b = (const float*)d_in[27];

  float* ws = (float*)d_ws;
  size_t off = 0;
  auto alloc = [&](size_t n) { float* p = ws + off; off += n; return p; };
  float* bc1 = alloc(576);
  float* bc2 = alloc(512);
  float* bc4 = alloc(640);
  unsigned short* cat1 = (unsigned short*)alloc((size_t)kNS * 576 / 2);  // xl_sg|xr_gs|sl1o
  unsigned short* cat2 = (unsigned short*)alloc((size_t)kNG * 512 / 2);  // xr_sg|xl_gs
  unsigned short* xl3  = (unsigned short*)alloc((size_t)kNG * 512 / 2);
  unsigned short* cat4 = (unsigned short*)alloc((size_t)kNS * 640 / 2);  // xr3|sl3o
  unsigned short* xs_bf  = (unsigned short*)alloc((size_t)kNS * 256 / 2);
  unsigned short* xg_bf  = (unsigned short*)alloc((size_t)kNG * 256 / 2);
  unsigned short* xg1_bf = (unsigned short*)alloc((size_t)kNG * 256 / 2);
  unsigned short* xs1_bf = (unsigned short*)alloc((size_t)kNS * 256 / 2);
  unsigned short* Wt1 = (unsigned short*)alloc(576 * 256 / 2);
  unsigned short* Wt2 = (unsigned short*)alloc(512 * 256 / 2);
  unsigned short* Wt3 = (unsigned short*)alloc(512 * 256 / 2);
  unsigned short* Wt4 = (unsigned short*)alloc(640 * 256 / 2);
  int* deg_g  = (int*)alloc(kNG);   // deg_g|deg_s|pval|pflag contiguous for one memset
  int* deg_s  = (int*)alloc(kNS);
  int* pval   = (int*)alloc(128);
  int* pflag  = (int*)alloc(128);
  int* rp_g   = (int*)alloc(kNG + 1);
  int* rp_s   = (int*)alloc(kNS + 1);
  int* psrc_g = (int*)alloc(kE);
  int* psrc_s = (int*)alloc(kE);

  hipMemsetAsync(deg_g, 0, (kNCAT + 256) * sizeof(int), stream);

  prep<<<9295, 256, 0, stream>>>(
      x_sample, x_gene, Wl1_sg, Wr1_gs, sl1_W, Wr1_sg, Wl1_gs, Wl3, Wr3, sl3_W,
      bl1_sg, br1_gs, sl1_b, br1_sg, bl1_gs, br3, sl3_b,
      sg_dst, gs_dst, deg_g, deg_s,
      xs_bf, xg_bf, Wt1, Wt2, Wt3, Wt4, bc1, bc2, bc4);

  scan_fused<<<kNB, 256, 0, stream>>>(deg_g, rp_g, rp_s, pval, pflag);

  // layer-1 GEMMs + CSR perm build in one dispatch (independent work)
  gemm_build<<<288 + 1256 + 1024, 256, 0, stream>>>(
      xs_bf, Wt1, bc1, cat1, kNS, 576, 288,
      xg_bf, Wt2, bc2, cat2, kNG, 512, 1256,
      sg_dst, sg_src, rp_g, deg_g, psrc_g,
      gs_dst, gs_src, rp_s, deg_s, psrc_s);

  // stage 1 (2500 blocks, dst-per-half) + stage 2 (1024 blocks, split)
  gat12<<<2500 + 1024, 256, 0, stream>>>(
      cat1, 576, cat2, 512, att1_sg, psrc_g, rp_g, bias1_sg, xg1_bf, kNG, 2500,
      cat2 + 256, 512, cat1 + 256, 576, att1_gs, psrc_s, rp_s, bias1_gs,
      cat1 + 512, 576, xs1_bf, kNS);

  // layer-3 GEMMs (no build blocks)
  gemm_build<<<1256 + 320, 256, 0, stream>>>(
      xg1_bf, Wt3, bl3, xl3, kNG, 512, 1256,
      xs1_bf, Wt4, bc4, cat4, kNS, 640, 320,
      sg_dst, sg_src, rp_g, deg_g, psrc_g,
      gs_dst, gs_src, rp_s, deg_s, psrc_s);

  // stage 3: 2 waves per dst (2048 blocks)
  gat3<<<kNS / 2, 256, 0, stream>>>(
      xl3, cat4, att3, psrc_s, rp_s, bias3, cat4 + 512, (float*)d_out);
}

// Round 9
// 158.158 us; speedup vs baseline: 6.2140x; 1.0008x over previous
//
#include <hip/hip_runtime.h>
#include <hip/hip_bf16.h>
#include <cstdint>

constexpr int kNS = 4096;
constexpr int kNG = 20000;
constexpr int kE  = 131072;
constexpr int kNCAT = kNG + kNS;          // 24096
constexpr int kNB = (kNCAT + 255) / 256;  // 95 scan blocks
constexpr float kL2E = 1.4426950408889634f;

typedef __attribute__((ext_vector_type(8))) short short8;
typedef __attribute__((ext_vector_type(4))) float f32x4;
typedef __attribute__((ext_vector_type(2))) float f32x2;

__device__ __forceinline__ float elu_f(float v) { return v > 0.f ? v : expm1f(v); }

__device__ __forceinline__ unsigned short f2bf(float f) {
  union { float f; unsigned u; } v; v.f = f;
  unsigned r = v.u + 0x7FFF + ((v.u >> 16) & 1);
  return (unsigned short)(r >> 16);
}

__device__ __forceinline__ float bf2f(unsigned short u) {
  union { unsigned u; float f; } v; v.u = ((unsigned)u) << 16; return v.f;
}

// unpack 2 bf16 (packed in a dword) -> f32x2 {lo, hi}
__device__ __forceinline__ f32x2 bfp2(unsigned u) {
  union { unsigned u; float f; } lo, hi;
  lo.u = u << 16; hi.u = u & 0xffff0000u;
  return (f32x2){lo.f, hi.f};
}

// ================= tiny zero kernel (replaces hipMemsetAsync: rocclr fill = 41 us!) ====
__global__ __launch_bounds__(256) void zero_int(int* __restrict__ p, int n) {
  int i = blockIdx.x * 256 + threadIdx.x;
  if (i < n) p[i] = 0;
}

// ================= prep: conversions/transposes/bias concat + edge histogram ===========
__global__ __launch_bounds__(256) void prep(
    const float* __restrict__ xs, const float* __restrict__ xg,
    const float* __restrict__ Wl1_sg, const float* __restrict__ Wr1_gs,
    const float* __restrict__ sl1_W, const float* __restrict__ Wr1_sg,
    const float* __restrict__ Wl1_gs, const float* __restrict__ Wl3,
    const float* __restrict__ Wr3, const float* __restrict__ sl3_W,
    const float* __restrict__ bl1_sg, const float* __restrict__ br1_gs,
    const float* __restrict__ sl1_b, const float* __restrict__ br1_sg,
    const float* __restrict__ bl1_gs, const float* __restrict__ br3,
    const float* __restrict__ sl3_b,
    const int* __restrict__ sg_dst, const int* __restrict__ gs_dst,
    int* __restrict__ deg_g, int* __restrict__ deg_s,
    unsigned short* __restrict__ xs_bf, unsigned short* __restrict__ xg_bf,
    unsigned short* __restrict__ Wt1, unsigned short* __restrict__ Wt2,
    unsigned short* __restrict__ Wt3, unsigned short* __restrict__ Wt4,
    float* __restrict__ bc1, float* __restrict__ bc2, float* __restrict__ bc4) {
  int bid = blockIdx.x, tid = threadIdx.x;
  if (bid < 1024) {
    int i = (bid * 256 + tid) * 4;
    float4 v = *(const float4*)&xs[i];
    ushort4 o = {f2bf(v.x), f2bf(v.y), f2bf(v.z), f2bf(v.w)};
    *(ushort4*)&xs_bf[i] = o;
    return;
  }
  bid -= 1024;
  if (bid < 5000) {
    int i = (bid * 256 + tid) * 4;
    float4 v = *(const float4*)&xg[i];
    ushort4 o = {f2bf(v.x), f2bf(v.y), f2bf(v.z), f2bf(v.w)};
    *(ushort4*)&xg_bf[i] = o;
    return;
  }
  bid -= 5000;
  auto wseg = [&](const float* W, unsigned short* Wt, int N) {
    int i = bid * 256 + tid;
    int n = i >> 8, k = i & 255;
    Wt[i] = f2bf(W[(size_t)k * N + n]);
  };
  if (bid < 256) { wseg(Wl1_sg, Wt1, 256); return; } bid -= 256;
  if (bid < 256) { wseg(Wr1_gs, Wt1 + 256 * 256, 256); return; } bid -= 256;
  if (bid < 64)  { wseg(sl1_W,  Wt1 + 512 * 256, 64);  return; } bid -= 64;
  if (bid < 256) { wseg(Wr1_sg, Wt2, 256); return; } bid -= 256;
  if (bid < 256) { wseg(Wl1_gs, Wt2 + 256 * 256, 256); return; } bid -= 256;
  if (bid < 512) { wseg(Wl3,    Wt3, 512); return; } bid -= 512;
  if (bid < 512) { wseg(Wr3,    Wt4, 512); return; } bid -= 512;
  if (bid < 128) { wseg(sl3_W,  Wt4 + 512 * 256, 128); return; } bid -= 128;
  if (bid < 7) {
    int j = bid * 256 + tid;
    if (j < 256) bc1[j] = bl1_sg[j];
    else if (j < 512) bc1[j] = br1_gs[j - 256];
    else if (j < 576) bc1[j] = sl1_b[j - 512];
    else if (j < 832) bc2[j - 576] = br1_sg[j - 576];
    else if (j < 1088) bc2[j - 576] = bl1_gs[j - 832];
    else if (j < 1600) bc4[j - 1088] = br3[j - 1088];
    else if (j < 1728) bc4[j - 1088] = sl3_b[j - 1600];
    return;
  }
  bid -= 7;
  int i = bid * 256 + tid;
  if (i < kE) atomicAdd(&deg_g[sg_dst[i]], 1);
  else atomicAdd(&deg_s[gs_dst[i - kE]], 1);
}

// ================= single-dispatch scan with decoupled lookback =================
__global__ __launch_bounds__(256) void scan_fused(
    int* __restrict__ deg, int* __restrict__ rp_g, int* __restrict__ rp_s,
    int* __restrict__ pval, int* __restrict__ pflag) {
  int b = blockIdx.x, t = threadIdx.x;
  int i = b * 256 + t;
  int v = i < kNCAT ? deg[i] : 0;
  __shared__ int s[256];
  s[t] = v;
  __syncthreads();
  for (int ofs = 1; ofs < 256; ofs <<= 1) {
    int add = t >= ofs ? s[t - ofs] : 0;
    __syncthreads();
    s[t] += add;
    __syncthreads();
  }
  if (t == 255) {
    atomicExch(&pval[b], s[255]);
    __threadfence();
    atomicExch(&pflag[b], 1);
  }
  int pre = 0;
  if (t < b) {
    while (atomicAdd(&pflag[t], 0) == 0) {}
    pre = atomicAdd(&pval[t], 0);
  }
  pre += __shfl_xor(pre, 1);  pre += __shfl_xor(pre, 2);
  pre += __shfl_xor(pre, 4);  pre += __shfl_xor(pre, 8);
  pre += __shfl_xor(pre, 16); pre += __shfl_xor(pre, 32);
  __shared__ int ws4[4];
  if ((t & 63) == 0) ws4[t >> 6] = pre;
  __syncthreads();
  int prefix = ws4[0] + ws4[1] + ws4[2] + ws4[3];
  int ex = prefix + s[t] - v;
  if (i < kNG) { rp_g[i] = ex; deg[i] = 0; }
  else if (i < kNCAT) { rp_s[i - kNG] = ex - kE; deg[i] = 0; }
  if (b == 0 && t == 0) { rp_g[kNG] = kE; rp_s[kNS] = kE; }
}

// ================= MFMA GEMM body (128x64 tile, BK=32, K=256) =================
__device__ __forceinline__ void gemm_body(
    const unsigned short* __restrict__ A, const unsigned short* __restrict__ Bt,
    const float* __restrict__ bias, unsigned short* __restrict__ Cb,
    int M, int N, int bx, int by) {
  __shared__ alignas(16) unsigned short As[128 * 32];
  __shared__ alignas(16) unsigned short Bs[64 * 32];
  const int tid = threadIdx.x;
  const int wave = tid >> 6, lane = tid & 63;
  const int brow = by * 128, bcol = bx * 64;
  const int wrow = (wave >> 1) * 64, wcol = (wave & 1) * 32;
  const int la = lane & 15, lk = (lane >> 4) * 8;
  f32x4 acc[4][2] = {};
  for (int k0 = 0; k0 < 256; k0 += 32) {
#pragma unroll
    for (int c = 0; c < 2; ++c) {
      int seg = wave * 128 + c * 64 + lane;
      int row = seg >> 2, ks = (seg & 3) * 8;
      int grow = brow + row; if (grow > M - 1) grow = M - 1;
      const unsigned short* g = A + (size_t)grow * 256 + k0 + ks;
      __builtin_amdgcn_global_load_lds(
          (const __attribute__((address_space(1))) unsigned*)g,
          (__attribute__((address_space(3))) unsigned*)&As[(wave * 128 + c * 64) * 8],
          16, 0, 0);
    }
    {
      int seg = wave * 64 + lane;
      int row = seg >> 2, ks = (seg & 3) * 8;
      const unsigned short* g = Bt + (size_t)(bcol + row) * 256 + k0 + ks;
      __builtin_amdgcn_global_load_lds(
          (const __attribute__((address_space(1))) unsigned*)g,
          (__attribute__((address_space(3))) unsigned*)&Bs[(wave * 64) * 8],
          16, 0, 0);
    }
    __syncthreads();
    short8 bfr[2];
#pragma unroll
    for (int ni = 0; ni < 2; ++ni)
      bfr[ni] = *(const short8*)&Bs[(wcol + ni * 16 + la) * 32 + lk];
#pragma unroll
    for (int mi = 0; mi < 4; ++mi) {
      short8 af = *(const short8*)&As[(wrow + mi * 16 + la) * 32 + lk];
#pragma unroll
      for (int ni = 0; ni < 2; ++ni)
        acc[mi][ni] = __builtin_amdgcn_mfma_f32_16x16x32_bf16(af, bfr[ni], acc[mi][ni], 0, 0, 0);
    }
    __syncthreads();
  }
  const int r0 = (lane >> 4) * 4;
#pragma unroll
  for (int mi = 0; mi < 4; ++mi) {
#pragma unroll
    for (int r = 0; r < 4; ++r) {
      int row = brow + wrow + mi * 16 + r0 + r;
      if (row >= M) continue;
#pragma unroll
      for (int ni = 0; ni < 2; ++ni) {
        int col = bcol + wcol + ni * 16 + la;
        Cb[(size_t)row * N + col] = f2bf(acc[mi][ni][r] + bias[col]);
      }
    }
  }
}

// two GEMMs + (optionally) CSR perm-build in one dispatch
__global__ __launch_bounds__(256) void gemm_build(
    const unsigned short* __restrict__ A0, const unsigned short* __restrict__ B0,
    const float* __restrict__ b0, unsigned short* __restrict__ C0, int M0, int N0, int nb0,
    const unsigned short* __restrict__ A1, const unsigned short* __restrict__ B1,
    const float* __restrict__ b1, unsigned short* __restrict__ C1, int M1, int N1, int nb1,
    const int* __restrict__ sgd, const int* __restrict__ sgs,
    const int* __restrict__ rpg, int* __restrict__ curg, int* __restrict__ psg,
    const int* __restrict__ gsd, const int* __restrict__ gss,
    const int* __restrict__ rps, int* __restrict__ curs, int* __restrict__ pss) {
  int flat = blockIdx.x;
  if (flat < nb0) {
    int nbx = N0 / 64;
    gemm_body(A0, B0, b0, C0, M0, N0, flat % nbx, flat / nbx);
    return;
  }
  flat -= nb0;
  if (flat < nb1) {
    int nbx = N1 / 64;
    gemm_body(A1, B1, b1, C1, M1, N1, flat % nbx, flat / nbx);
    return;
  }
  flat -= nb1;
  int i = flat * 256 + threadIdx.x;
  if (i < kE) {
    int d = sgd[i];
    psg[rpg[d] + atomicAdd(&curg[d], 1)] = sgs[i];
  } else {
    i -= kE;
    int d = gsd[i];
    pss[rps[d] + atomicAdd(&curs[d], 1)] = gss[i];
  }
}

// ================= fused GATv2, C=64, no-max softmax, pk f32 math ================
template <bool SPLIT, bool ADDSL>
__device__ __forceinline__ void gat64_body(
    const unsigned short* __restrict__ xl, int ldl,
    const unsigned short* __restrict__ xr, int ldr,
    const float* __restrict__ att,
    const int* __restrict__ psrc, const int* __restrict__ rp,
    const float* __restrict__ bias,
    const unsigned short* __restrict__ sl, int ldsl,
    unsigned short* __restrict__ out, int N, int rbid) {
  int tid = threadIdx.x;
  int cl = tid & 31;
  int d, sub;
  if (SPLIT) { d = rbid * 4 + (tid >> 6); sub = (tid >> 5) & 1; }
  else       { d = rbid * 8 + (tid >> 5); sub = 0; }
  if (d >= N) return;
  f32x2 xr2[4], at2[4];
  {
    const uint4 xu = *(const uint4*)&xr[(size_t)d * ldr + cl * 8];
    xr2[0] = bfp2(xu.x); xr2[1] = bfp2(xu.y); xr2[2] = bfp2(xu.z); xr2[3] = bfp2(xu.w);
    float4 a0 = *(const float4*)&att[cl * 8];
    float4 a1 = *(const float4*)&att[cl * 8 + 4];
    at2[0] = (f32x2){a0.x, a0.y} * kL2E; at2[1] = (f32x2){a0.z, a0.w} * kL2E;
    at2[2] = (f32x2){a1.x, a1.y} * kL2E; at2[3] = (f32x2){a1.z, a1.w} * kL2E;
  }
  float l = 0.f;
  f32x2 acc2[4] = {};
  int i0 = rp[d], i1 = rp[d + 1];
  for (int i = SPLIT ? i0 + sub * 4 : i0; i < i1; i += SPLIT ? 8 : 4) {
    int ia = i + 1 < i1 ? i + 1 : i;
    int ib = i + 2 < i1 ? i + 2 : i;
    int ic = i + 3 < i1 ? i + 3 : i;
    int s0 = psrc[i], s1 = psrc[ia], s2 = psrc[ib], s3 = psrc[ic];
    uint4 xu0 = *(const uint4*)&xl[(size_t)s0 * ldl + cl * 8];
    uint4 xu1 = *(const uint4*)&xl[(size_t)s1 * ldl + cl * 8];
    uint4 xu2 = *(const uint4*)&xl[(size_t)s2 * ldl + cl * 8];
    uint4 xu3 = *(const uint4*)&xl[(size_t)s3 * ldl + cl * 8];
    f32x2 xf[4][4];
    xf[0][0] = bfp2(xu0.x); xf[0][1] = bfp2(xu0.y); xf[0][2] = bfp2(xu0.z); xf[0][3] = bfp2(xu0.w);
    xf[1][0] = bfp2(xu1.x); xf[1][1] = bfp2(xu1.y); xf[1][2] = bfp2(xu1.z); xf[1][3] = bfp2(xu1.w);
    xf[2][0] = bfp2(xu2.x); xf[2][1] = bfp2(xu2.y); xf[2][2] = bfp2(xu2.z); xf[2][3] = bfp2(xu2.w);
    xf[3][0] = bfp2(xu3.x); xf[3][1] = bfp2(xu3.y); xf[3][2] = bfp2(xu3.z); xf[3][3] = bfp2(xu3.w);
    float dt[4];
#pragma unroll
    for (int b = 0; b < 4; ++b) {
      f32x2 d2 = {0.f, 0.f};
#pragma unroll
      for (int p = 0; p < 4; ++p) {
        f32x2 v = xf[b][p] + xr2[p];
        f32x2 lk = __builtin_elementwise_max(v, v * 0.2f);
        d2 = __builtin_elementwise_fma(lk, at2[p], d2);
      }
      float dd = d2.x + d2.y;
      dd += __shfl_xor(dd, 1);
      dd += __shfl_xor(dd, 2);
      dd += __shfl_xor(dd, 4);   // 8-lane head reduce
      dt[b] = dd;
    }
    float w0 = exp2f(dt[0]);
    float w1 = (i + 1 < i1) ? exp2f(dt[1]) : 0.f;
    float w2 = (i + 2 < i1) ? exp2f(dt[2]) : 0.f;
    float w3 = (i + 3 < i1) ? exp2f(dt[3]) : 0.f;
    l += (w0 + w1) + (w2 + w3);
#pragma unroll
    for (int p = 0; p < 4; ++p) {
      acc2[p] = __builtin_elementwise_fma(xf[0][p], (f32x2){w0, w0}, acc2[p]);
      acc2[p] = __builtin_elementwise_fma(xf[1][p], (f32x2){w1, w1}, acc2[p]);
      acc2[p] = __builtin_elementwise_fma(xf[2][p], (f32x2){w2, w2}, acc2[p]);
      acc2[p] = __builtin_elementwise_fma(xf[3][p], (f32x2){w3, w3}, acc2[p]);
    }
  }
  if (SPLIT) {
    l += __shfl_xor(l, 32);
#pragma unroll
    for (int p = 0; p < 4; ++p) {
      acc2[p].x += __shfl_xor(acc2[p].x, 32);
      acc2[p].y += __shfl_xor(acc2[p].y, 32);
    }
    if (sub != 0) return;
  }
  float dinv = 1.f / (l + 1e-16f);
  short8 o;
#pragma unroll
  for (int p = 0; p < 4; ++p) {
    int c = cl * 8 + p * 2;
    float v0 = acc2[p].x * dinv + bias[c];
    float v1 = acc2[p].y * dinv + bias[c + 1];
    if (ADDSL) {
      v0 += bf2f(sl[(size_t)d * ldsl + (c & 63)]);
      v1 += bf2f(sl[(size_t)d * ldsl + ((c + 1) & 63)]);
    }
    o[p * 2]     = (short)f2bf(elu_f(v0));
    o[p * 2 + 1] = (short)f2bf(elu_f(v1));
  }
  *(short8*)&out[(size_t)d * 256 + cl * 8] = o;
}

// stage1 (dst per half-wave) + stage2 (split, +SL) in one dispatch
__global__ __launch_bounds__(256) void gat12(
    const unsigned short* __restrict__ xlA, int ldlA,
    const unsigned short* __restrict__ xrA, int ldrA,
    const float* __restrict__ attA, const int* __restrict__ psA,
    const int* __restrict__ rpA, const float* __restrict__ biasA,
    unsigned short* __restrict__ outA, int NA, int nbA,
    const unsigned short* __restrict__ xlB, int ldlB,
    const unsigned short* __restrict__ xrB, int ldrB,
    const float* __restrict__ attB, const int* __restrict__ psB,
    const int* __restrict__ rpB, const float* __restrict__ biasB,
    const unsigned short* __restrict__ slB, int ldslB,
    unsigned short* __restrict__ outB, int NB) {
  int bid = blockIdx.x;
  if (bid < nbA)
    gat64_body<false, false>(xlA, ldlA, xrA, ldrA, attA, psA, rpA, biasA,
                             nullptr, 0, outA, NA, bid);
  else
    gat64_body<true, true>(xlB, ldlB, xrB, ldrB, attB, psB, rpB, biasB,
                           slB, ldslB, outB, NB, bid - nbA);
}

// ================= stage-3 GAT, C=128: 2 waves/dst, LDS add-merge, head-mean ==========
__global__ __launch_bounds__(256) void gat3(
    const unsigned short* __restrict__ xl,   // [NG,512]
    const unsigned short* __restrict__ xr,   // cat4 [NS,640], cols 0..511
    const float* __restrict__ att,
    const int* __restrict__ psrc, const int* __restrict__ rp,
    const float* __restrict__ bias,
    const unsigned short* __restrict__ sl,   // cat4 cols 512..639
    float* __restrict__ out) {
  __shared__ float sm_acc[2][64][8];
  __shared__ float sm_l[2][64];
  int w = threadIdx.x >> 6, lane = threadIdx.x & 63;
  int p = w >> 1, wp = w & 1;
  int d = blockIdx.x * 2 + p;
  f32x2 xr2[4], at2[4];
  {
    const uint4 xu = *(const uint4*)&xr[(size_t)d * 640 + lane * 8];
    xr2[0] = bfp2(xu.x); xr2[1] = bfp2(xu.y); xr2[2] = bfp2(xu.z); xr2[3] = bfp2(xu.w);
    float4 a0 = *(const float4*)&att[lane * 8];
    float4 a1 = *(const float4*)&att[lane * 8 + 4];
    at2[0] = (f32x2){a0.x, a0.y} * kL2E; at2[1] = (f32x2){a0.z, a0.w} * kL2E;
    at2[2] = (f32x2){a1.x, a1.y} * kL2E; at2[3] = (f32x2){a1.z, a1.w} * kL2E;
  }
  float l = 0.f;
  f32x2 acc2[4] = {};
  int i0 = rp[d], i1 = rp[d + 1];
  for (int i = i0 + wp * 4; i < i1; i += 8) {
    int ia = i + 1 < i1 ? i + 1 : i;
    int ib = i + 2 < i1 ? i + 2 : i;
    int ic = i + 3 < i1 ? i + 3 : i;
    int s0 = psrc[i], s1 = psrc[ia], s2 = psrc[ib], s3 = psrc[ic];
    uint4 xu0 = *(const uint4*)&xl[(size_t)s0 * 512 + lane * 8];
    uint4 xu1 = *(const uint4*)&xl[(size_t)s1 * 512 + lane * 8];
    uint4 xu2 = *(const uint4*)&xl[(size_t)s2 * 512 + lane * 8];
    uint4 xu3 = *(const uint4*)&xl[(size_t)s3 * 512 + lane * 8];
    f32x2 xf[4][4];
    xf[0][0] = bfp2(xu0.x); xf[0][1] = bfp2(xu0.y); xf[0][2] = bfp2(xu0.z); xf[0][3] = bfp2(xu0.w);
    xf[1][0] = bfp2(xu1.x); xf[1][1] = bfp2(xu1.y); xf[1][2] = bfp2(xu1.z); xf[1][3] = bfp2(xu1.w);
    xf[2][0] = bfp2(xu2.x); xf[2][1] = bfp2(xu2.y); xf[2][2] = bfp2(xu2.z); xf[2][3] = bfp2(xu2.w);
    xf[3][0] = bfp2(xu3.x); xf[3][1] = bfp2(xu3.y); xf[3][2] = bfp2(xu3.z); xf[3][3] = bfp2(xu3.w);
    float dt[4];
#pragma unroll
    for (int b = 0; b < 4; ++b) {
      f32x2 d2 = {0.f, 0.f};
#pragma unroll
      for (int q = 0; q < 4; ++q) {
        f32x2 v = xf[b][q] + xr2[q];
        f32x2 lk = __builtin_elementwise_max(v, v * 0.2f);
        d2 = __builtin_elementwise_fma(lk, at2[q], d2);
      }
      float dd = d2.x + d2.y;
      dd += __shfl_xor(dd, 1);
      dd += __shfl_xor(dd, 2);
      dd += __shfl_xor(dd, 4);
      dd += __shfl_xor(dd, 8);   // 16-lane head reduce (C=128)
      dt[b] = dd;
    }
    float w0 = exp2f(dt[0]);
    float w1 = (i + 1 < i1) ? exp2f(dt[1]) : 0.f;
    float w2 = (i + 2 < i1) ? exp2f(dt[2]) : 0.f;
    float w3 = (i + 3 < i1) ? exp2f(dt[3]) : 0.f;
    l += (w0 + w1) + (w2 + w3);
#pragma unroll
    for (int q = 0; q < 4; ++q) {
      acc2[q] = __builtin_elementwise_fma(xf[0][q], (f32x2){w0, w0}, acc2[q]);
      acc2[q] = __builtin_elementwise_fma(xf[1][q], (f32x2){w1, w1}, acc2[q]);
      acc2[q] = __builtin_elementwise_fma(xf[2][q], (f32x2){w2, w2}, acc2[q]);
      acc2[q] = __builtin_elementwise_fma(xf[3][q], (f32x2){w3, w3}, acc2[q]);
    }
  }
  if (wp == 1) {
#pragma unroll
    for (int q = 0; q < 4; ++q) {
      sm_acc[p][lane][q * 2]     = acc2[q].x;
      sm_acc[p][lane][q * 2 + 1] = acc2[q].y;
    }
    sm_l[p][lane] = l;
  }
  __syncthreads();
  if (wp == 0) {
    l += sm_l[p][lane];
    float dinv = 1.f / (l + 1e-16f);
    float r[8];
#pragma unroll
    for (int q = 0; q < 4; ++q) {
      r[q * 2]     = (acc2[q].x + sm_acc[p][lane][q * 2]) * dinv;
      r[q * 2 + 1] = (acc2[q].y + sm_acc[p][lane][q * 2 + 1]) * dinv;
    }
#pragma unroll
    for (int j = 0; j < 8; ++j) {
      r[j] += __shfl_xor(r[j], 16);
      r[j] += __shfl_xor(r[j], 32);
    }
    if (lane < 16) {
#pragma unroll
      for (int j = 0; j < 8; ++j) {
        int c = lane * 8 + j;
        out[(size_t)d * 128 + c] =
            elu_f(0.25f * r[j] + bias[c] + bf2f(sl[(size_t)d * 640 + c]));
      }
    }
  }
}

extern "C" void kernel_launch(void* const* d_in, const int* in_sizes, int n_in,
                              void* d_out, int out_size, void* d_ws, size_t ws_size,
                              hipStream_t stream) {
  const float* x_sample = (const float*)d_in[0];
  const float* x_gene   = (const float*)d_in[1];
  const int* sg_src = (const int*)d_in[2];
  const int* sg_dst = (const int*)d_in[3];
  const int* gs_src = (const int*)d_in[4];
  const int* gs_dst = (const int*)d_in[5];
  const float* Wl1_sg = (const float*)d_in[6];
  const float* bl1_sg = (const float*)d_in[7];
  const float* Wr1_sg = (const float*)d_in[8];
  const float* br1_sg = (const float*)d_in[9];
  const float* att1_sg = (const float*)d_in[10];
  const float* bias1_sg = (const float*)d_in[11];
  const float* Wl1_gs = (const float*)d_in[12];
  const float* bl1_gs = (const float*)d_in[13];
  const float* Wr1_gs = (const float*)d_in[14];
  const float* br1_gs = (const float*)d_in[15];
  const float* att1_gs = (const float*)d_in[16];
  const float* bias1_gs = (const float*)d_in[17];
  const float* Wl3 = (const float*)d_in[18];
  const float* bl3 = (const float*)d_in[19];
  const float* Wr3 = (const float*)d_in[20];
  const float* br3 = (const float*)d_in[21];
  const float* att3 = (const float*)d_in[22];
  const float* bias3 = (const float*)d_in[23];
  const float* sl1_W = (const float*)d_in[24];
  const float* sl1_b = (const float*)d_in[25];
  const float* sl3_W = (const float*)d_in[26];
  const float* sl3_b = (const float*)d_in[27];

  float* ws = (float*)d_ws;
  size_t off = 0;
  auto alloc = [&](size_t n) { float* p = ws + off; off += n; return p; };
  float* bc1 = alloc(576);
  float* bc2 = alloc(512);
  float* bc4 = alloc(640);
  unsigned short* cat1 = (unsigned short*)alloc((size_t)kNS * 576 / 2);  // xl_sg|xr_gs|sl1o
  unsigned short* cat2 = (unsigned short*)alloc((size_t)kNG * 512 / 2);  // xr_sg|xl_gs
  unsigned short* xl3  = (unsigned short*)alloc((size_t)kNG * 512 / 2);
  unsigned short* cat4 = (unsigned short*)alloc((size_t)kNS * 640 / 2);  // xr3|sl3o
  unsigned short* xs_bf  = (unsigned short*)alloc((size_t)kNS * 256 / 2);
  unsigned short* xg_bf  = (unsigned short*)alloc((size_t)kNG * 256 / 2);
  unsigned short* xg1_bf = (unsigned short*)alloc((size_t)kNG * 256 / 2);
  unsigned short* xs1_bf = (unsigned short*)alloc((size_t)kNS * 256 / 2);
  unsigned short* Wt1 = (unsigned short*)alloc(576 * 256 / 2);
  unsigned short* Wt2 = (unsigned short*)alloc(512 * 256 / 2);
  unsigned short* Wt3 = (unsigned short*)alloc(512 * 256 / 2);
  unsigned short* Wt4 = (unsigned short*)alloc(640 * 256 / 2);
  int* deg_g  = (int*)alloc(kNG);   // deg_g|deg_s|pval|pflag contiguous for one zero pass
  int* deg_s  = (int*)alloc(kNS);
  int* pval   = (int*)alloc(128);
  int* pflag  = (int*)alloc(128);
  int* rp_g   = (int*)alloc(kNG + 1);
  int* rp_s   = (int*)alloc(kNS + 1);
  int* psrc_g = (int*)alloc(kE);
  int* psrc_s = (int*)alloc(kE);

  // rocclr fillBufferAligned costs ~41 us in-graph for this 97 KB clear; own kernel ~2 us
  zero_int<<<(kNCAT + 256 + 255) / 256, 256, 0, stream>>>(deg_g, kNCAT + 256);

  prep<<<9295, 256, 0, stream>>>(
      x_sample, x_gene, Wl1_sg, Wr1_gs, sl1_W, Wr1_sg, Wl1_gs, Wl3, Wr3, sl3_W,
      bl1_sg, br1_gs, sl1_b, br1_sg, bl1_gs, br3, sl3_b,
      sg_dst, gs_dst, deg_g, deg_s,
      xs_bf, xg_bf, Wt1, Wt2, Wt3, Wt4, bc1, bc2, bc4);

  scan_fused<<<kNB, 256, 0, stream>>>(deg_g, rp_g, rp_s, pval, pflag);

  // layer-1 GEMMs + CSR perm build in one dispatch (independent work)
  gemm_build<<<288 + 1256 + 1024, 256, 0, stream>>>(
      xs_bf, Wt1, bc1, cat1, kNS, 576, 288,
      xg_bf, Wt2, bc2, cat2, kNG, 512, 1256,
      sg_dst, sg_src, rp_g, deg_g, psrc_g,
      gs_dst, gs_src, rp_s, deg_s, psrc_s);

  // stage 1 (2500 blocks, dst-per-half) + stage 2 (1024 blocks, split)
  gat12<<<2500 + 1024, 256, 0, stream>>>(
      cat1, 576, cat2, 512, att1_sg, psrc_g, rp_g, bias1_sg, xg1_bf, kNG, 2500,
      cat2 + 256, 512, cat1 + 256, 576, att1_gs, psrc_s, rp_s, bias1_gs,
      cat1 + 512, 576, xs1_bf, kNS);

  // layer-3 GEMMs (no build blocks)
  gemm_build<<<1256 + 320, 256, 0, stream>>>(
      xg1_bf, Wt3, bl3, xl3, kNG, 512, 1256,
      xs1_bf, Wt4, bc4, cat4, kNS, 640, 320,
      sg_dst, sg_src, rp_g, deg_g, psrc_g,
      gs_dst, gs_src, rp_s, deg_s, psrc_s);

  // stage 3: 2 waves per dst (2048 blocks)
  gat3<<<kNS / 2, 256, 0, stream>>>(
      xl3, cat4, att3, psrc_s, rp_s, bias3, cat4 + 512, (float*)d_out);
}